// Round 1
// baseline (1167.251 us; speedup 1.0000x reference)
//
#include <hip/hip_runtime.h>
#include <math.h>

#define NN 65536
#define SIN 24
#define DD 64
#define HH 4
#define HDIM 16
#define NFRM 256
#define NE 1048576
#define BSZ 256
#define EPSLN 1e-5f
#define SCL 0.25f

// ---- float <-> order-preserving uint encoding for atomic max ----
__device__ __forceinline__ unsigned fenc(float f) {
  unsigned u = __float_as_uint(f);
  return (u & 0x80000000u) ? ~u : (u | 0x80000000u);
}
__device__ __forceinline__ float fdec(unsigned u) {
  return (u & 0x80000000u) ? __uint_as_float(u & 0x7FFFFFFFu) : __uint_as_float(~u);
}

// K1: h = x @ Wi + bi + pe[n % NF]
__global__ void k_input(const float* __restrict__ x, const float* __restrict__ Wi,
                        const float* __restrict__ bi, const float* __restrict__ pe,
                        float* __restrict__ h) {
  int tid = blockIdx.x * blockDim.x + threadIdx.x;
  int n = tid >> 6, j = tid & 63;
  const float* xr = x + (size_t)n * SIN;
  float acc = bi[j] + pe[(n & (NFRM - 1)) * DD + j];
#pragma unroll
  for (int s = 0; s < SIN; ++s) acc += xr[s] * Wi[s * DD + j];
  h[tid] = acc;
}

// K2: q,k,v,skip = einsum('nd,hdk->nhk', h, W*) + b*
__global__ void k_qkvs(const float* __restrict__ h,
                       const float* __restrict__ Wq, const float* __restrict__ Wk,
                       const float* __restrict__ Wv, const float* __restrict__ Ws,
                       const float* __restrict__ bq, const float* __restrict__ bk,
                       const float* __restrict__ bv, const float* __restrict__ bs,
                       float* __restrict__ q, float* __restrict__ k,
                       float* __restrict__ v, float* __restrict__ sk) {
  int tid = blockIdx.x * blockDim.x + threadIdx.x;
  int n = tid >> 6, j = tid & 63;
  int hh = j >> 4, kk = j & 15;
  const float* hr = h + (size_t)n * DD;
  const float* wq = Wq + (size_t)hh * DD * HDIM + kk;
  const float* wk = Wk + (size_t)hh * DD * HDIM + kk;
  const float* wv = Wv + (size_t)hh * DD * HDIM + kk;
  const float* ws = Ws + (size_t)hh * DD * HDIM + kk;
  float aq = bq[j], ak = bk[j], av = bv[j], as_ = bs[j];
#pragma unroll 8
  for (int d = 0; d < DD; ++d) {
    float hd = hr[d];
    aq += hd * wq[d * HDIM];
    ak += hd * wk[d * HDIM];
    av += hd * wv[d * HDIM];
    as_ += hd * ws[d * HDIM];
  }
  q[tid] = aq; k[tid] = ak; v[tid] = av; sk[tid] = as_;
}

// K3: per (edge, head) logits + atomic segment max
__global__ void k_edge_logit(const int* __restrict__ ei, const float* __restrict__ q,
                             const float* __restrict__ k, float* __restrict__ lg,
                             unsigned* __restrict__ menc) {
  int tid = blockIdx.x * blockDim.x + threadIdx.x;
  int e = tid >> 2, hh = tid & 3;
  int src = ei[e], dst = ei[NE + e];
  const float4* qr = (const float4*)(q + (size_t)dst * DD + hh * HDIM);
  const float4* kr = (const float4*)(k + (size_t)src * DD + hh * HDIM);
  float acc = 0.f;
#pragma unroll
  for (int i = 0; i < 4; ++i) {
    float4 a = qr[i], b = kr[i];
    acc += a.x * b.x + a.y * b.y + a.z * b.z + a.w * b.w;
  }
  acc *= SCL;
  lg[tid] = acc;
  atomicMax(&menc[dst * HH + hh], fenc(acc));
}

// K4: ex = exp(logit - m[dst]); denom += ex
__global__ void k_edge_exp(const int* __restrict__ ei, float* __restrict__ lg,
                           const unsigned* __restrict__ menc, float* __restrict__ den) {
  int tid = blockIdx.x * blockDim.x + threadIdx.x;
  int e = tid >> 2, hh = tid & 3;
  int dst = ei[NE + e];
  float m = fdec(menc[dst * HH + hh]);
  float ex = expf(lg[tid] - m);
  lg[tid] = ex;
  atomicAdd(&den[dst * HH + hh], ex);
}

// K5: agg[dst] += (ex/denom[dst]) * v[src]   (thread per edge-feature)
__global__ void k_edge_agg(const int* __restrict__ ei, const float* __restrict__ ex,
                           const float* __restrict__ den, const float* __restrict__ v,
                           float* __restrict__ agg) {
  int tid = blockIdx.x * blockDim.x + threadIdx.x;
  int e = tid >> 6, j = tid & 63;
  int hh = j >> 4;
  int src = ei[e], dst = ei[NE + e];
  float w = ex[(size_t)e * HH + hh] / den[dst * HH + hh];
  atomicAdd(&agg[(size_t)dst * DD + j], w * v[(size_t)src * DD + j]);
}

// Generic: io = LN(io + (in1 [+ in2]) @ Wm + bias)   -- one wave per row
__global__ void k_matln(const float* __restrict__ in1, const float* __restrict__ in2,
                        const float* __restrict__ Wm, const float* __restrict__ bias,
                        const float* __restrict__ g, const float* __restrict__ bb,
                        float* __restrict__ io) {
  __shared__ float t[4][DD];
  int wid = threadIdx.x >> 6, lane = threadIdx.x & 63;
  int n = (blockIdx.x << 2) + wid;
  size_t base = (size_t)n * DD;
  float tv = in1[base + lane];
  if (in2 != nullptr) tv += in2[base + lane];
  t[wid][lane] = tv;
  __syncthreads();
  float o = bias[lane] + io[base + lane];
#pragma unroll 8
  for (int d = 0; d < DD; ++d) o += t[wid][d] * Wm[d * DD + lane];
  float s = o, s2 = o * o;
#pragma unroll
  for (int off = 32; off >= 1; off >>= 1) {
    s += __shfl_xor(s, off);
    s2 += __shfl_xor(s2, off);
  }
  float mean = s * (1.0f / 64.0f);
  float var = s2 * (1.0f / 64.0f) - mean * mean;
  float r = (o - mean) * rsqrtf(var + EPSLN) * g[lane] + bb[lane];
  io[base + lane] = r;
}

// K7: qt, kt, vt projections
__global__ void k_qkvt(const float* __restrict__ xt,
                       const float* __restrict__ Wqt, const float* __restrict__ Wkt,
                       const float* __restrict__ Wvt,
                       const float* __restrict__ bqt, const float* __restrict__ bkt,
                       const float* __restrict__ bvt,
                       float* __restrict__ qt, float* __restrict__ kt, float* __restrict__ vt) {
  int tid = blockIdx.x * blockDim.x + threadIdx.x;
  int n = tid >> 6, j = tid & 63;
  const float* xr = xt + (size_t)n * DD;
  float aq = bqt[j], ak = bkt[j], av = bvt[j];
#pragma unroll 8
  for (int d = 0; d < DD; ++d) {
    float xd = xr[d];
    aq += xd * Wqt[d * DD + j];
    ak += xd * Wkt[d * DD + j];
    av += xd * Wvt[d * DD + j];
  }
  qt[tid] = aq; kt[tid] = ak; vt[tid] = av;
}

// K8: temporal attention, one block per (graph b, head hh)
__global__ void k_tattn(const float* __restrict__ qt, const float* __restrict__ kt,
                        const float* __restrict__ vt, float* __restrict__ attn) {
  int b = blockIdx.x >> 2, hh = blockIdx.x & 3;
  __shared__ float ks[NFRM][HDIM];
  __shared__ float vs[NFRM][HDIM];
  int t = threadIdx.x;
  size_t base = ((size_t)b * NFRM + t) * DD + hh * HDIM;
#pragma unroll
  for (int i = 0; i < 4; ++i) {
    ((float4*)ks[t])[i] = *(const float4*)(kt + base + i * 4);
    ((float4*)vs[t])[i] = *(const float4*)(vt + base + i * 4);
  }
  float qv[HDIM];
#pragma unroll
  for (int i = 0; i < 4; ++i) ((float4*)qv)[i] = *(const float4*)(qt + base + i * 4);
  __syncthreads();
  float m = -INFINITY, l = 0.f;
  float acc[HDIM];
#pragma unroll
  for (int k = 0; k < HDIM; ++k) acc[k] = 0.f;
  for (int j = 0; j < NFRM; ++j) {
    float s = 0.f;
#pragma unroll
    for (int k = 0; k < HDIM; ++k) s += qv[k] * ks[j][k];
    s *= SCL;
    float nm = fmaxf(m, s);
    float c = expf(m - nm);
    float p = expf(s - nm);
    l = l * c + p;
#pragma unroll
    for (int k = 0; k < HDIM; ++k) acc[k] = acc[k] * c + p * vs[j][k];
    m = nm;
  }
  float inv = 1.0f / l;
#pragma unroll
  for (int k = 0; k < HDIM; ++k) attn[base + k] = acc[k] * inv;
}

// K10: u = relu(xt @ W1 + b1)
__global__ void k_ffn1(const float* __restrict__ xt, const float* __restrict__ W1,
                       const float* __restrict__ b1, float* __restrict__ u) {
  int tid = blockIdx.x * blockDim.x + threadIdx.x;
  int n = tid >> 7, j = tid & 127;
  const float* xr = xt + (size_t)n * DD;
  float a = b1[j];
#pragma unroll 8
  for (int d = 0; d < DD; ++d) a += xr[d] * W1[d * 128 + j];
  u[tid] = fmaxf(a, 0.f);
}

// K11: xt = LN(xt + u @ W2 + b2)
__global__ void k_ffn2_ln(const float* __restrict__ u, const float* __restrict__ W2,
                          const float* __restrict__ b2, const float* __restrict__ g,
                          const float* __restrict__ bb, float* __restrict__ xt) {
  __shared__ float t[4][128];
  int wid = threadIdx.x >> 6, lane = threadIdx.x & 63;
  int n = (blockIdx.x << 2) + wid;
  t[wid][lane] = u[(size_t)n * 128 + lane];
  t[wid][64 + lane] = u[(size_t)n * 128 + 64 + lane];
  __syncthreads();
  size_t base = (size_t)n * DD;
  float o = b2[lane] + xt[base + lane];
#pragma unroll 8
  for (int d = 0; d < 128; ++d) o += t[wid][d] * W2[d * DD + lane];
  float s = o, s2 = o * o;
#pragma unroll
  for (int off = 32; off >= 1; off >>= 1) {
    s += __shfl_xor(s, off);
    s2 += __shfl_xor(s2, off);
  }
  float mean = s * (1.0f / 64.0f);
  float var = s2 * (1.0f / 64.0f) - mean * mean;
  float r = (o - mean) * rsqrtf(var + EPSLN) * g[lane] + bb[lane];
  xt[base + lane] = r;
}

// K12: split-K GEMM a1raw[b,j] += sum_i xf[b,i]*Wa1[i,j]
__global__ void k_agg1(const float* __restrict__ xt, const float* __restrict__ Wa1,
                       float* __restrict__ a1) {
  int b = blockIdx.x >> 4;
  int ksp = blockIdx.x & 15;
  int t = threadIdx.x, p = t >> 6, j = t & 63;
  const float* xf = xt + (size_t)b * (NFRM * DD);
  int i0 = ksp * 1024 + p * 256;
  float acc = 0.f;
#pragma unroll 4
  for (int i = i0; i < i0 + 256; ++i) acc += xf[i] * Wa1[(size_t)i * DD + j];
  __shared__ float red[256];
  red[t] = acc;
  __syncthreads();
  if (t < 64) atomicAdd(&a1[b * DD + t], red[t] + red[t + 64] + red[t + 128] + red[t + 192]);
}

// K13: head MLP: relu(a1+ba1) -> a2 -> h1 -> sigmoid
__global__ void k_head(const float* __restrict__ a1, const float* __restrict__ ba1,
                       const float* __restrict__ Wa2, const float* __restrict__ ba2,
                       const float* __restrict__ Wh1, const float* __restrict__ bh1,
                       const float* __restrict__ Wh2, const float* __restrict__ bh2,
                       float* __restrict__ out) {
  int b = blockIdx.x, t = threadIdx.x;
  __shared__ float s1[64], s2[32], s3[16];
  s1[t] = fmaxf(a1[b * DD + t] + ba1[t], 0.f);
  __syncthreads();
  if (t < 32) {
    float a = ba2[t];
#pragma unroll 8
    for (int j = 0; j < 64; ++j) a += s1[j] * Wa2[j * 32 + t];
    s2[t] = fmaxf(a, 0.f);
  }
  __syncthreads();
  if (t < 16) {
    float a = bh1[t];
#pragma unroll
    for (int j = 0; j < 32; ++j) a += s2[j] * Wh1[j * 16 + t];
    s3[t] = fmaxf(a, 0.f);
  }
  __syncthreads();
  if (t == 0) {
    float a = bh2[0];
#pragma unroll
    for (int j = 0; j < 16; ++j) a += s3[j] * Wh2[j];
    out[b] = 1.0f / (1.0f + expf(-a));
  }
}

extern "C" void kernel_launch(void* const* d_in, const int* in_sizes, int n_in,
                              void* d_out, int out_size, void* d_ws, size_t ws_size,
                              hipStream_t stream) {
  const float* x   = (const float*)d_in[0];
  const int*   ei  = (const int*)d_in[1];
  const float* Wi  = (const float*)d_in[2];
  const float* bi  = (const float*)d_in[3];
  const float* pe  = (const float*)d_in[4];
  const float* Wq  = (const float*)d_in[5];
  const float* Wk  = (const float*)d_in[6];
  const float* Wv  = (const float*)d_in[7];
  const float* bq  = (const float*)d_in[8];
  const float* bk  = (const float*)d_in[9];
  const float* bv  = (const float*)d_in[10];
  const float* Ws  = (const float*)d_in[11];
  const float* bs  = (const float*)d_in[12];
  const float* Wo  = (const float*)d_in[13];
  const float* bo  = (const float*)d_in[14];
  const float* gg  = (const float*)d_in[15];
  const float* gb  = (const float*)d_in[16];
  const float* Wqt = (const float*)d_in[17];
  const float* Wkt = (const float*)d_in[18];
  const float* Wvt = (const float*)d_in[19];
  const float* bqt = (const float*)d_in[20];
  const float* bkt = (const float*)d_in[21];
  const float* bvt = (const float*)d_in[22];
  const float* Wot = (const float*)d_in[23];
  const float* bot = (const float*)d_in[24];
  const float* l1g = (const float*)d_in[25];
  const float* l1b = (const float*)d_in[26];
  const float* W1  = (const float*)d_in[27];
  const float* b1  = (const float*)d_in[28];
  const float* W2  = (const float*)d_in[29];
  const float* b2  = (const float*)d_in[30];
  const float* l2g = (const float*)d_in[31];
  const float* l2b = (const float*)d_in[32];
  const float* Wa1 = (const float*)d_in[33];
  const float* ba1 = (const float*)d_in[34];
  const float* Wa2 = (const float*)d_in[35];
  const float* ba2 = (const float*)d_in[36];
  const float* Wh1 = (const float*)d_in[37];
  const float* bh1 = (const float*)d_in[38];
  const float* Wh2 = (const float*)d_in[39];
  const float* bh2 = (const float*)d_in[40];
  float* out = (float*)d_out;

  const size_t ND = (size_t)NN * DD;   // 4,194,304
  const size_t NH = (size_t)NN * HH;   // 262,144
  const size_t EH = (size_t)NE * HH;   // 4,194,304

  float* wsf   = (float*)d_ws;
  float* f_h   = wsf;            // h / xt (reused through pipeline)
  float* f_q   = f_h  + ND;      // q  -> qt
  float* f_k   = f_q  + ND;      // k  -> kt
  float* f_v   = f_k  + ND;      // v  -> vt
  float* f_sk  = f_v  + ND;      // skip -> attn
  float* f_agg = f_sk + ND;      // agg (zeroed)
  float* f_den = f_agg + ND;     // denom (zeroed)
  unsigned* f_menc = (unsigned*)(f_den + NH);  // enc max (zeroed = below all reals)
  float* f_a1  = f_den + 2 * NH; // a1 raw (zeroed)
  float* f_lg  = f_a1 + (size_t)BSZ * DD;  // edge logits / ex
  float* f_u   = f_lg + EH;      // ffn hidden [N,128]

  // zero agg + denom + menc + a1 in one async memset (capture-safe)
  hipMemsetAsync(f_agg, 0, (ND + 2 * NH + (size_t)BSZ * DD) * sizeof(float), stream);

  dim3 B(256);
  // 1. input proj + PE
  k_input<<<dim3((NN * DD) / 256), B, 0, stream>>>(x, Wi, bi, pe, f_h);
  // 2. q,k,v,skip
  k_qkvs<<<dim3((NN * DD) / 256), B, 0, stream>>>(f_h, Wq, Wk, Wv, Ws, bq, bk, bv, bs,
                                                  f_q, f_k, f_v, f_sk);
  // 3-5. edge passes
  k_edge_logit<<<dim3((NE * HH) / 256), B, 0, stream>>>(ei, f_q, f_k, f_lg, f_menc);
  k_edge_exp<<<dim3((NE * HH) / 256), B, 0, stream>>>(ei, f_lg, f_menc, f_den);
  k_edge_agg<<<dim3((NE * 64) / 256), B, 0, stream>>>(ei, f_lg, f_den, f_v, f_agg);
  // 6. (agg+skip)@Wo + bo, residual + LN  -> f_h
  k_matln<<<dim3(NN / 4), B, 0, stream>>>(f_agg, f_sk, Wo, bo, gg, gb, f_h);
  // 7. temporal q,k,v
  k_qkvt<<<dim3((NN * DD) / 256), B, 0, stream>>>(f_h, Wqt, Wkt, Wvt, bqt, bkt, bvt,
                                                  f_q, f_k, f_v);
  // 8. temporal attention -> f_sk
  k_tattn<<<dim3(BSZ * HH), B, 0, stream>>>(f_q, f_k, f_v, f_sk);
  // 9. attn@Wot + bot, residual + LN1 -> f_h
  k_matln<<<dim3(NN / 4), B, 0, stream>>>(f_sk, nullptr, Wot, bot, l1g, l1b, f_h);
  // 10-11. FFN + LN2
  k_ffn1<<<dim3((NN * 128) / 256), B, 0, stream>>>(f_h, W1, b1, f_u);
  k_ffn2_ln<<<dim3(NN / 4), B, 0, stream>>>(f_u, W2, b2, l2g, l2b, f_h);
  // 12. aggregation GEMM (split-K, atomic accumulate)
  k_agg1<<<dim3(BSZ * 16), B, 0, stream>>>(f_h, Wa1, f_a1);
  // 13. head MLP
  k_head<<<dim3(BSZ), dim3(64), 0, stream>>>(f_a1, ba1, Wa2, ba2, Wh1, bh1, Wh2, bh2, out);
}

// Round 2
// 981.919 us; speedup vs baseline: 1.1887x; 1.1887x over previous
//
#include <hip/hip_runtime.h>
#include <math.h>

#define NN 65536
#define SIN 24
#define DD 64
#define HH 4
#define HDIM 16
#define NFRM 256
#define NE 1048576
#define BSZ 256
#define EPSLN 1e-5f
#define SCL 0.25f

#define KSP 128     // K-chunks for agg1 GEMM
#define KROWS 128   // rows of Wa1 per chunk (KSP*KROWS = 16384)

// K1: h = x @ Wi + bi + pe[n % NF]
__global__ void k_input(const float* __restrict__ x, const float* __restrict__ Wi,
                        const float* __restrict__ bi, const float* __restrict__ pe,
                        float* __restrict__ h) {
  int tid = blockIdx.x * blockDim.x + threadIdx.x;
  int n = tid >> 6, j = tid & 63;
  const float* xr = x + (size_t)n * SIN;
  float acc = bi[j] + pe[(n & (NFRM - 1)) * DD + j];
#pragma unroll
  for (int s = 0; s < SIN; ++s) acc += xr[s] * Wi[s * DD + j];
  h[tid] = acc;
}

// K2: q,k,v,skip = einsum('nd,hdk->nhk', h, W*) + b*
__global__ void k_qkvs(const float* __restrict__ h,
                       const float* __restrict__ Wq, const float* __restrict__ Wk,
                       const float* __restrict__ Wv, const float* __restrict__ Ws,
                       const float* __restrict__ bq, const float* __restrict__ bk,
                       const float* __restrict__ bv, const float* __restrict__ bs,
                       float* __restrict__ q, float* __restrict__ k,
                       float* __restrict__ v, float* __restrict__ sk) {
  int tid = blockIdx.x * blockDim.x + threadIdx.x;
  int n = tid >> 6, j = tid & 63;
  int hh = j >> 4, kk = j & 15;
  const float* hr = h + (size_t)n * DD;
  const float* wq = Wq + (size_t)hh * DD * HDIM + kk;
  const float* wk = Wk + (size_t)hh * DD * HDIM + kk;
  const float* wv = Wv + (size_t)hh * DD * HDIM + kk;
  const float* ws = Ws + (size_t)hh * DD * HDIM + kk;
  float aq = bq[j], ak = bk[j], av = bv[j], as_ = bs[j];
#pragma unroll 8
  for (int d = 0; d < DD; ++d) {
    float hd = hr[d];
    aq += hd * wq[d * HDIM];
    ak += hd * wk[d * HDIM];
    av += hd * wv[d * HDIM];
    as_ += hd * ws[d * HDIM];
  }
  q[tid] = aq; k[tid] = ak; v[tid] = av; sk[tid] = as_;
}

// ---- CSR build: count / scan / scatter ----
__global__ void k_count(const int* __restrict__ ei, int* __restrict__ cnt) {
  int e = blockIdx.x * 256 + threadIdx.x;
  atomicAdd(&cnt[ei[NE + e]], 1);
}

__global__ void k_scan1(const int* __restrict__ cnt, int* __restrict__ rowptr,
                        int* __restrict__ bsum) {
  __shared__ int s[256];
  int t = threadIdx.x, base = blockIdx.x << 8;
  int v = cnt[base + t];
  s[t] = v; __syncthreads();
  for (int off = 1; off < 256; off <<= 1) {
    int x = (t >= off) ? s[t - off] : 0;
    __syncthreads();
    s[t] += x;
    __syncthreads();
  }
  rowptr[base + t] = s[t] - v;
  if (t == 255) bsum[blockIdx.x] = s[255];
}

__global__ void k_scan2(const int* __restrict__ bsum, int* __restrict__ boff) {
  __shared__ int s[256];
  int t = threadIdx.x;
  int v = bsum[t];
  s[t] = v; __syncthreads();
  for (int off = 1; off < 256; off <<= 1) {
    int x = (t >= off) ? s[t - off] : 0;
    __syncthreads();
    s[t] += x;
    __syncthreads();
  }
  boff[t] = s[t] - v;
}

__global__ void k_scan3(int* __restrict__ rowptr, const int* __restrict__ boff,
                        int* __restrict__ cursor) {
  int g = blockIdx.x * 256 + threadIdx.x;
  int r = rowptr[g] + boff[g >> 8];
  rowptr[g] = r; cursor[g] = r;
  if (g == 0) rowptr[NN] = NE;
}

__global__ void k_scatter(const int* __restrict__ ei, int* __restrict__ cursor,
                          int* __restrict__ srcs) {
  int e = blockIdx.x * 256 + threadIdx.x;
  int dst = ei[NE + e];
  int pos = atomicAdd(&cursor[dst], 1);
  srcs[pos] = ei[e];
}

// Fused: per-dst online-softmax graph attention + skip + @Wo + residual + LN
// one wave per dst node; lane = h*16+kk
__global__ void k_gattn_ln(const float* __restrict__ q, const float* __restrict__ k,
                           const float* __restrict__ v, const int* __restrict__ rowptr,
                           const int* __restrict__ srcs, const float* __restrict__ sk,
                           const float* __restrict__ Wo, const float* __restrict__ bo,
                           const float* __restrict__ g, const float* __restrict__ bb,
                           float* __restrict__ io) {
  __shared__ float t[4][DD];
  int wid = threadIdx.x >> 6, lane = threadIdx.x & 63;
  int dst = (blockIdx.x << 2) + wid;
  size_t base = (size_t)dst * DD;
  float qv = q[base + lane];
  int beg = rowptr[dst], end = rowptr[dst + 1];
  float m = -INFINITY, l = 0.f, acc = 0.f;
  for (int idx = beg; idx < end; ++idx) {
    int src = srcs[idx];
    size_t sb = (size_t)src * DD;
    float kv = k[sb + lane];
    float vv = v[sb + lane];
    float s = qv * kv;
    s += __shfl_xor(s, 1); s += __shfl_xor(s, 2);
    s += __shfl_xor(s, 4); s += __shfl_xor(s, 8);
    s *= SCL;
    float nm = fmaxf(m, s);
    float c = __expf(m - nm), p = __expf(s - nm);
    l = l * c + p;
    acc = acc * c + p * vv;
    m = nm;
  }
  float aggv = (end > beg) ? acc / l : 0.f;
  t[wid][lane] = aggv + sk[base + lane];
  __syncthreads();
  float o = bo[lane] + io[base + lane];
#pragma unroll 8
  for (int d = 0; d < DD; ++d) o += t[wid][d] * Wo[d * DD + lane];
  float s1 = o, s2 = o * o;
#pragma unroll
  for (int off = 32; off >= 1; off >>= 1) {
    s1 += __shfl_xor(s1, off);
    s2 += __shfl_xor(s2, off);
  }
  float mean = s1 * (1.0f / 64.0f);
  float var = s2 * (1.0f / 64.0f) - mean * mean;
  io[base + lane] = (o - mean) * rsqrtf(var + EPSLN) * g[lane] + bb[lane];
}

// Generic: io = LN(io + in1 @ Wm + bias)   -- one wave per row
__global__ void k_matln(const float* __restrict__ in1,
                        const float* __restrict__ Wm, const float* __restrict__ bias,
                        const float* __restrict__ g, const float* __restrict__ bb,
                        float* __restrict__ io) {
  __shared__ float t[4][DD];
  int wid = threadIdx.x >> 6, lane = threadIdx.x & 63;
  int n = (blockIdx.x << 2) + wid;
  size_t base = (size_t)n * DD;
  t[wid][lane] = in1[base + lane];
  __syncthreads();
  float o = bias[lane] + io[base + lane];
#pragma unroll 8
  for (int d = 0; d < DD; ++d) o += t[wid][d] * Wm[d * DD + lane];
  float s = o, s2 = o * o;
#pragma unroll
  for (int off = 32; off >= 1; off >>= 1) {
    s += __shfl_xor(s, off);
    s2 += __shfl_xor(s2, off);
  }
  float mean = s * (1.0f / 64.0f);
  float var = s2 * (1.0f / 64.0f) - mean * mean;
  float r = (o - mean) * rsqrtf(var + EPSLN) * g[lane] + bb[lane];
  io[base + lane] = r;
}

// K7: qt, kt, vt projections
__global__ void k_qkvt(const float* __restrict__ xt,
                       const float* __restrict__ Wqt, const float* __restrict__ Wkt,
                       const float* __restrict__ Wvt,
                       const float* __restrict__ bqt, const float* __restrict__ bkt,
                       const float* __restrict__ bvt,
                       float* __restrict__ qt, float* __restrict__ kt, float* __restrict__ vt) {
  int tid = blockIdx.x * blockDim.x + threadIdx.x;
  int n = tid >> 6, j = tid & 63;
  const float* xr = xt + (size_t)n * DD;
  float aq = bqt[j], ak = bkt[j], av = bvt[j];
#pragma unroll 8
  for (int d = 0; d < DD; ++d) {
    float xd = xr[d];
    aq += xd * Wqt[d * DD + j];
    ak += xd * Wkt[d * DD + j];
    av += xd * Wvt[d * DD + j];
  }
  qt[tid] = aq; kt[tid] = ak; vt[tid] = av;
}

// K8: temporal attention, one block per (graph b, head hh)
__global__ void k_tattn(const float* __restrict__ qt, const float* __restrict__ kt,
                        const float* __restrict__ vt, float* __restrict__ attn) {
  int b = blockIdx.x >> 2, hh = blockIdx.x & 3;
  __shared__ float ks[NFRM][HDIM];
  __shared__ float vs[NFRM][HDIM];
  int t = threadIdx.x;
  size_t base = ((size_t)b * NFRM + t) * DD + hh * HDIM;
#pragma unroll
  for (int i = 0; i < 4; ++i) {
    ((float4*)ks[t])[i] = *(const float4*)(kt + base + i * 4);
    ((float4*)vs[t])[i] = *(const float4*)(vt + base + i * 4);
  }
  float qv[HDIM];
#pragma unroll
  for (int i = 0; i < 4; ++i) ((float4*)qv)[i] = *(const float4*)(qt + base + i * 4);
  __syncthreads();
  float m = -INFINITY, l = 0.f;
  float acc[HDIM];
#pragma unroll
  for (int k = 0; k < HDIM; ++k) acc[k] = 0.f;
  for (int j = 0; j < NFRM; ++j) {
    float s = 0.f;
#pragma unroll
    for (int k = 0; k < HDIM; ++k) s += qv[k] * ks[j][k];
    s *= SCL;
    float nm = fmaxf(m, s);
    float c = __expf(m - nm);
    float p = __expf(s - nm);
    l = l * c + p;
#pragma unroll
    for (int k = 0; k < HDIM; ++k) acc[k] = acc[k] * c + p * vs[j][k];
    m = nm;
  }
  float inv = 1.0f / l;
#pragma unroll
  for (int k = 0; k < HDIM; ++k) attn[base + k] = acc[k] * inv;
}

// K10: u = relu(xt @ W1 + b1)
__global__ void k_ffn1(const float* __restrict__ xt, const float* __restrict__ W1,
                       const float* __restrict__ b1, float* __restrict__ u) {
  int tid = blockIdx.x * blockDim.x + threadIdx.x;
  int n = tid >> 7, j = tid & 127;
  const float* xr = xt + (size_t)n * DD;
  float a = b1[j];
#pragma unroll 8
  for (int d = 0; d < DD; ++d) a += xr[d] * W1[d * 128 + j];
  u[tid] = fmaxf(a, 0.f);
}

// K11: xt = LN(xt + u @ W2 + b2)
__global__ void k_ffn2_ln(const float* __restrict__ u, const float* __restrict__ W2,
                          const float* __restrict__ b2, const float* __restrict__ g,
                          const float* __restrict__ bb, float* __restrict__ xt) {
  __shared__ float t[4][128];
  int wid = threadIdx.x >> 6, lane = threadIdx.x & 63;
  int n = (blockIdx.x << 2) + wid;
  t[wid][lane] = u[(size_t)n * 128 + lane];
  t[wid][64 + lane] = u[(size_t)n * 128 + 64 + lane];
  __syncthreads();
  size_t base = (size_t)n * DD;
  float o = b2[lane] + xt[base + lane];
#pragma unroll 8
  for (int d = 0; d < 128; ++d) o += t[wid][d] * W2[d * DD + lane];
  float s = o, s2 = o * o;
#pragma unroll
  for (int off = 32; off >= 1; off >>= 1) {
    s += __shfl_xor(s, off);
    s2 += __shfl_xor(s2, off);
  }
  float mean = s * (1.0f / 64.0f);
  float var = s2 * (1.0f / 64.0f) - mean * mean;
  float r = (o - mean) * rsqrtf(var + EPSLN) * g[lane] + bb[lane];
  xt[base + lane] = r;
}

// K12a: agg1 GEMM partials: part[kc][b][j] = sum_{i in chunk kc} xf[b,i]*Wa1[i,j]
__global__ void k_agg1a(const float* __restrict__ xt, const float* __restrict__ Wa1,
                        float* __restrict__ part) {
  __shared__ float ws_s[KROWS * DD];  // 32 KB
  int kc = blockIdx.x >> 3, bt = blockIdx.x & 7;
  int t = threadIdx.x, wid = t >> 6, lane = t & 63;
  const float* wsrc = Wa1 + (size_t)kc * KROWS * DD;
  for (int idx = t; idx < KROWS * DD; idx += 256) ws_s[idx] = wsrc[idx];
  __syncthreads();
  for (int bb_ = 0; bb_ < 8; ++bb_) {
    int b = bt * 32 + wid * 8 + bb_;
    const float* xr = xt + (size_t)b * (NFRM * DD) + kc * KROWS;
    float acc = 0.f;
#pragma unroll 8
    for (int i = 0; i < KROWS; ++i) acc += xr[i] * ws_s[i * DD + lane];
    part[(size_t)kc * (BSZ * DD) + (size_t)b * DD + lane] = acc;
  }
}

// K12b: a1[b,j] = sum_kc part[kc][b][j]
__global__ void k_agg1red(const float* __restrict__ part, float* __restrict__ a1) {
  int g = blockIdx.x * 256 + threadIdx.x;
  float s = 0.f;
#pragma unroll 8
  for (int kc = 0; kc < KSP; ++kc) s += part[(size_t)kc * (BSZ * DD) + g];
  a1[g] = s;
}

// K13: head MLP: relu(a1+ba1) -> a2 -> h1 -> sigmoid
__global__ void k_head(const float* __restrict__ a1, const float* __restrict__ ba1,
                       const float* __restrict__ Wa2, const float* __restrict__ ba2,
                       const float* __restrict__ Wh1, const float* __restrict__ bh1,
                       const float* __restrict__ Wh2, const float* __restrict__ bh2,
                       float* __restrict__ out) {
  int b = blockIdx.x, t = threadIdx.x;
  __shared__ float s1[64], s2[32], s3[16];
  s1[t] = fmaxf(a1[b * DD + t] + ba1[t], 0.f);
  __syncthreads();
  if (t < 32) {
    float a = ba2[t];
#pragma unroll 8
    for (int j = 0; j < 64; ++j) a += s1[j] * Wa2[j * 32 + t];
    s2[t] = fmaxf(a, 0.f);
  }
  __syncthreads();
  if (t < 16) {
    float a = bh1[t];
#pragma unroll
    for (int j = 0; j < 32; ++j) a += s2[j] * Wh1[j * 16 + t];
    s3[t] = fmaxf(a, 0.f);
  }
  __syncthreads();
  if (t == 0) {
    float a = bh2[0];
#pragma unroll
    for (int j = 0; j < 16; ++j) a += s3[j] * Wh2[j];
    out[b] = 1.0f / (1.0f + expf(-a));
  }
}

extern "C" void kernel_launch(void* const* d_in, const int* in_sizes, int n_in,
                              void* d_out, int out_size, void* d_ws, size_t ws_size,
                              hipStream_t stream) {
  const float* x   = (const float*)d_in[0];
  const int*   ei  = (const int*)d_in[1];
  const float* Wi  = (const float*)d_in[2];
  const float* bi  = (const float*)d_in[3];
  const float* pe  = (const float*)d_in[4];
  const float* Wq  = (const float*)d_in[5];
  const float* Wk  = (const float*)d_in[6];
  const float* Wv  = (const float*)d_in[7];
  const float* bq  = (const float*)d_in[8];
  const float* bk  = (const float*)d_in[9];
  const float* bv  = (const float*)d_in[10];
  const float* Ws  = (const float*)d_in[11];
  const float* bs  = (const float*)d_in[12];
  const float* Wo  = (const float*)d_in[13];
  const float* bo  = (const float*)d_in[14];
  const float* gg  = (const float*)d_in[15];
  const float* gb  = (const float*)d_in[16];
  const float* Wqt = (const float*)d_in[17];
  const float* Wkt = (const float*)d_in[18];
  const float* Wvt = (const float*)d_in[19];
  const float* bqt = (const float*)d_in[20];
  const float* bkt = (const float*)d_in[21];
  const float* bvt = (const float*)d_in[22];
  const float* Wot = (const float*)d_in[23];
  const float* bot = (const float*)d_in[24];
  const float* l1g = (const float*)d_in[25];
  const float* l1b = (const float*)d_in[26];
  const float* W1  = (const float*)d_in[27];
  const float* b1  = (const float*)d_in[28];
  const float* W2  = (const float*)d_in[29];
  const float* b2  = (const float*)d_in[30];
  const float* l2g = (const float*)d_in[31];
  const float* l2b = (const float*)d_in[32];
  const float* Wa1 = (const float*)d_in[33];
  const float* ba1 = (const float*)d_in[34];
  const float* Wa2 = (const float*)d_in[35];
  const float* ba2 = (const float*)d_in[36];
  const float* Wh1 = (const float*)d_in[37];
  const float* bh1 = (const float*)d_in[38];
  const float* Wh2 = (const float*)d_in[39];
  const float* bh2 = (const float*)d_in[40];
  float* out = (float*)d_out;

  const size_t ND = (size_t)NN * DD;   // 4,194,304

  float* wsf    = (float*)d_ws;
  float* f_h    = wsf;                 // h / xt
  float* f_q    = f_h  + ND;           // q  -> qt
  float* f_k    = f_q  + ND;           // k  -> kt
  float* f_v    = f_k  + ND;           // v  -> vt
  float* f_sk   = f_v  + ND;           // skip -> attn
  float* f_u    = f_sk + ND;           // ffn hidden [N,128]
  float* f_part = f_u  + 2 * ND;       // agg1 partials [KSP][BSZ][DD] = 8 MB
  float* f_a1   = f_part + (size_t)KSP * BSZ * DD;
  int* i_srcs   = (int*)(f_a1 + BSZ * DD);  // CSR src list [NE]
  int* i_rowptr = i_srcs + NE;              // [NN+1]
  int* i_cursor = i_rowptr + NN + 1;        // [NN]
  int* i_cnt    = i_cursor + NN;            // [NN]
  int* i_bsum   = i_cnt + NN;               // [256]
  int* i_boff   = i_bsum + 256;             // [256]

  hipMemsetAsync(i_cnt, 0, NN * sizeof(int), stream);

  dim3 B(256);
  // 1. input proj + PE
  k_input<<<dim3((NN * DD) / 256), B, 0, stream>>>(x, Wi, bi, pe, f_h);
  // 2. q,k,v,skip
  k_qkvs<<<dim3((NN * DD) / 256), B, 0, stream>>>(f_h, Wq, Wk, Wv, Ws, bq, bk, bv, bs,
                                                  f_q, f_k, f_v, f_sk);
  // 3. CSR build
  k_count<<<dim3(NE / 256), B, 0, stream>>>(ei, i_cnt);
  k_scan1<<<dim3(NN / 256), B, 0, stream>>>(i_cnt, i_rowptr, i_bsum);
  k_scan2<<<dim3(1), B, 0, stream>>>(i_bsum, i_boff);
  k_scan3<<<dim3(NN / 256), B, 0, stream>>>(i_rowptr, i_boff, i_cursor);
  k_scatter<<<dim3(NE / 256), B, 0, stream>>>(ei, i_cursor, i_srcs);
  // 4. fused graph attention + skip + Wo + residual LN -> f_h
  k_gattn_ln<<<dim3(NN / 4), B, 0, stream>>>(f_q, f_k, f_v, i_rowptr, i_srcs, f_sk,
                                             Wo, bo, gg, gb, f_h);
  // 5. temporal q,k,v
  k_qkvt<<<dim3((NN * DD) / 256), B, 0, stream>>>(f_h, Wqt, Wkt, Wvt, bqt, bkt, bvt,
                                                  f_q, f_k, f_v);
  // 6. temporal attention -> f_sk
  k_tattn<<<dim3(BSZ * HH), B, 0, stream>>>(f_q, f_k, f_v, f_sk);
  // 7. attn@Wot + bot, residual + LN1 -> f_h
  k_matln<<<dim3(NN / 4), B, 0, stream>>>(f_sk, Wot, bot, l1g, l1b, f_h);
  // 8-9. FFN + LN2
  k_ffn1<<<dim3((NN * 128) / 256), B, 0, stream>>>(f_h, W1, b1, f_u);
  k_ffn2_ln<<<dim3(NN / 4), B, 0, stream>>>(f_u, W2, b2, l2g, l2b, f_h);
  // 10. aggregation GEMM (LDS-tiled split-K + reduce)
  k_agg1a<<<dim3(KSP * 8), B, 0, stream>>>(f_h, Wa1, f_part);
  k_agg1red<<<dim3(BSZ * DD / 256), B, 0, stream>>>(f_part, f_a1);
  // 11. head MLP
  k_head<<<dim3(BSZ), dim3(64), 0, stream>>>(f_a1, ba1, Wa2, ba2, Wh1, bh1, Wh2, bh2, out);
}

// Round 3
// 901.737 us; speedup vs baseline: 1.2944x; 1.0889x over previous
//
#include <hip/hip_runtime.h>
#include <math.h>

#define NN 65536
#define SIN 24
#define DD 64
#define HH 4
#define HDIM 16
#define NFRM 256
#define NE 1048576
#define BSZ 256
#define EPSLN 1e-5f
#define SCL 0.25f

#define KSP 128     // K-chunks for agg1 GEMM
#define KROWS 128   // rows of Wa1 per chunk (KSP*KROWS = 16384)

__device__ __forceinline__ unsigned short f2bf(float f) {
  unsigned u = __float_as_uint(f);
  return (unsigned short)((u + 0x7FFFu + ((u >> 16) & 1u)) >> 16);
}
__device__ __forceinline__ float bf2f(unsigned short b) {
  return __uint_as_float(((unsigned)b) << 16);
}

// K1: h = x @ Wi + bi + pe[n % NF]
__global__ void k_input(const float* __restrict__ x, const float* __restrict__ Wi,
                        const float* __restrict__ bi, const float* __restrict__ pe,
                        float* __restrict__ h) {
  int tid = blockIdx.x * blockDim.x + threadIdx.x;
  int n = tid >> 6, j = tid & 63;
  const float* xr = x + (size_t)n * SIN;
  float acc = bi[j] + pe[(n & (NFRM - 1)) * DD + j];
#pragma unroll
  for (int s = 0; s < SIN; ++s) acc += xr[s] * Wi[s * DD + j];
  h[tid] = acc;
}

// K2: q (fp32), kv (packed bf16 {k,v}), skip (fp32)
__global__ void k_qkvs(const float* __restrict__ h,
                       const float* __restrict__ Wq, const float* __restrict__ Wk,
                       const float* __restrict__ Wv, const float* __restrict__ Ws,
                       const float* __restrict__ bq, const float* __restrict__ bk,
                       const float* __restrict__ bv, const float* __restrict__ bs,
                       float* __restrict__ q, ushort2* __restrict__ kv,
                       float* __restrict__ sk) {
  int tid = blockIdx.x * blockDim.x + threadIdx.x;
  int n = tid >> 6, j = tid & 63;
  int hh = j >> 4, kk = j & 15;
  const float* hr = h + (size_t)n * DD;
  const float* wq = Wq + (size_t)hh * DD * HDIM + kk;
  const float* wk = Wk + (size_t)hh * DD * HDIM + kk;
  const float* wv = Wv + (size_t)hh * DD * HDIM + kk;
  const float* ws = Ws + (size_t)hh * DD * HDIM + kk;
  float aq = bq[j], ak = bk[j], av = bv[j], as_ = bs[j];
#pragma unroll 8
  for (int d = 0; d < DD; ++d) {
    float hd = hr[d];
    aq += hd * wq[d * HDIM];
    ak += hd * wk[d * HDIM];
    av += hd * wv[d * HDIM];
    as_ += hd * ws[d * HDIM];
  }
  q[tid] = aq;
  kv[tid] = make_ushort2(f2bf(ak), f2bf(av));
  sk[tid] = as_;
}

// ---- CSR build ----
__global__ void k_count(const int* __restrict__ ei, int* __restrict__ cnt) {
  int e = blockIdx.x * 256 + threadIdx.x;
  atomicAdd(&cnt[ei[NE + e]], 1);
}

__global__ void k_scan1(const int* __restrict__ cnt, int* __restrict__ rowptr,
                        int* __restrict__ bsum) {
  __shared__ int s[256];
  int t = threadIdx.x, base = blockIdx.x << 8;
  int v = cnt[base + t];
  s[t] = v; __syncthreads();
  for (int off = 1; off < 256; off <<= 1) {
    int x = (t >= off) ? s[t - off] : 0;
    __syncthreads();
    s[t] += x;
    __syncthreads();
  }
  rowptr[base + t] = s[t] - v;
  if (t == 255) bsum[blockIdx.x] = s[255];
}

__global__ void k_scan2(const int* __restrict__ bsum, int* __restrict__ boff) {
  __shared__ int s[256];
  int t = threadIdx.x;
  int v = bsum[t];
  s[t] = v; __syncthreads();
  for (int off = 1; off < 256; off <<= 1) {
    int x = (t >= off) ? s[t - off] : 0;
    __syncthreads();
    s[t] += x;
    __syncthreads();
  }
  boff[t] = s[t] - v;
}

__global__ void k_scan3(int* __restrict__ rowptr, const int* __restrict__ boff,
                        int* __restrict__ cursor) {
  int g = blockIdx.x * 256 + threadIdx.x;
  int r = rowptr[g] + boff[g >> 8];
  rowptr[g] = r; cursor[g] = r;
  if (g == 0) rowptr[NN] = NE;
}

__global__ void k_scatter(const int* __restrict__ ei, int* __restrict__ cursor,
                          int* __restrict__ srcs) {
  int e = blockIdx.x * 256 + threadIdx.x;
  int dst = ei[NE + e];
  int pos = atomicAdd(&cursor[dst], 1);
  srcs[pos] = ei[e];
}

// Fused graph attention (bf16 kv gather, 4-way unrolled online softmax)
// + skip + @Wo + residual + LN.  One wave per dst; lane = h*16+kk.
__global__ void k_gattn_ln(const float* __restrict__ q, const ushort2* __restrict__ kv,
                           const int* __restrict__ rowptr,
                           const int* __restrict__ srcs, const float* __restrict__ sk,
                           const float* __restrict__ Wo, const float* __restrict__ bo,
                           const float* __restrict__ g, const float* __restrict__ bb,
                           float* __restrict__ io) {
  __shared__ float t[4][DD];
  int wid = threadIdx.x >> 6, lane = threadIdx.x & 63;
  int dst = (blockIdx.x << 2) + wid;
  size_t base = (size_t)dst * DD;
  float qv = q[base + lane];
  int beg = rowptr[dst], end = rowptr[dst + 1];
  float m = -INFINITY, l = 0.f, acc = 0.f;
  int idx = beg;
  for (; idx + 4 <= end; idx += 4) {
    int s0 = srcs[idx], s1 = srcs[idx + 1], s2 = srcs[idx + 2], s3 = srcs[idx + 3];
    ushort2 a0 = kv[(size_t)s0 * DD + lane];
    ushort2 a1 = kv[(size_t)s1 * DD + lane];
    ushort2 a2 = kv[(size_t)s2 * DD + lane];
    ushort2 a3 = kv[(size_t)s3 * DD + lane];
    float t0 = qv * bf2f(a0.x), t1 = qv * bf2f(a1.x);
    float t2 = qv * bf2f(a2.x), t3 = qv * bf2f(a3.x);
#pragma unroll
    for (int off = 1; off <= 8; off <<= 1) {
      t0 += __shfl_xor(t0, off);
      t1 += __shfl_xor(t1, off);
      t2 += __shfl_xor(t2, off);
      t3 += __shfl_xor(t3, off);
    }
    t0 *= SCL; t1 *= SCL; t2 *= SCL; t3 *= SCL;
    float nm = fmaxf(fmaxf(m, fmaxf(t0, t1)), fmaxf(t2, t3));
    float c = __expf(m - nm);
    float p0 = __expf(t0 - nm), p1 = __expf(t1 - nm);
    float p2 = __expf(t2 - nm), p3 = __expf(t3 - nm);
    l = l * c + ((p0 + p1) + (p2 + p3));
    acc = acc * c + ((p0 * bf2f(a0.y) + p1 * bf2f(a1.y)) +
                     (p2 * bf2f(a2.y) + p3 * bf2f(a3.y)));
    m = nm;
  }
  for (; idx < end; ++idx) {
    int s0 = srcs[idx];
    ushort2 a0 = kv[(size_t)s0 * DD + lane];
    float t0 = qv * bf2f(a0.x);
#pragma unroll
    for (int off = 1; off <= 8; off <<= 1) t0 += __shfl_xor(t0, off);
    t0 *= SCL;
    float nm = fmaxf(m, t0);
    float c = __expf(m - nm), p = __expf(t0 - nm);
    l = l * c + p;
    acc = acc * c + p * bf2f(a0.y);
    m = nm;
  }
  float aggv = (end > beg) ? acc / l : 0.f;
  t[wid][lane] = aggv + sk[base + lane];
  __syncthreads();
  float o = bo[lane] + io[base + lane];
#pragma unroll 8
  for (int d = 0; d < DD; ++d) o += t[wid][d] * Wo[d * DD + lane];
  float s1v = o, s2v = o * o;
#pragma unroll
  for (int off = 32; off >= 1; off >>= 1) {
    s1v += __shfl_xor(s1v, off);
    s2v += __shfl_xor(s2v, off);
  }
  float mean = s1v * (1.0f / 64.0f);
  float var = s2v * (1.0f / 64.0f) - mean * mean;
  io[base + lane] = (o - mean) * rsqrtf(var + EPSLN) * g[lane] + bb[lane];
}

// Generic: io = LN(io + in1 @ Wm + bias)
__global__ void k_matln(const float* __restrict__ in1,
                        const float* __restrict__ Wm, const float* __restrict__ bias,
                        const float* __restrict__ g, const float* __restrict__ bb,
                        float* __restrict__ io) {
  __shared__ float t[4][DD];
  int wid = threadIdx.x >> 6, lane = threadIdx.x & 63;
  int n = (blockIdx.x << 2) + wid;
  size_t base = (size_t)n * DD;
  t[wid][lane] = in1[base + lane];
  __syncthreads();
  float o = bias[lane] + io[base + lane];
#pragma unroll 8
  for (int d = 0; d < DD; ++d) o += t[wid][d] * Wm[d * DD + lane];
  float s = o, s2 = o * o;
#pragma unroll
  for (int off = 32; off >= 1; off >>= 1) {
    s += __shfl_xor(s, off);
    s2 += __shfl_xor(s2, off);
  }
  float mean = s * (1.0f / 64.0f);
  float var = s2 * (1.0f / 64.0f) - mean * mean;
  float r = (o - mean) * rsqrtf(var + EPSLN) * g[lane] + bb[lane];
  io[base + lane] = r;
}

// K7: qt, kt, vt projections
__global__ void k_qkvt(const float* __restrict__ xt,
                       const float* __restrict__ Wqt, const float* __restrict__ Wkt,
                       const float* __restrict__ Wvt,
                       const float* __restrict__ bqt, const float* __restrict__ bkt,
                       const float* __restrict__ bvt,
                       float* __restrict__ qt, float* __restrict__ kt, float* __restrict__ vt) {
  int tid = blockIdx.x * blockDim.x + threadIdx.x;
  int n = tid >> 6, j = tid & 63;
  const float* xr = xt + (size_t)n * DD;
  float aq = bqt[j], ak = bkt[j], av = bvt[j];
#pragma unroll 8
  for (int d = 0; d < DD; ++d) {
    float xd = xr[d];
    aq += xd * Wqt[d * DD + j];
    ak += xd * Wkt[d * DD + j];
    av += xd * Wvt[d * DD + j];
  }
  qt[tid] = aq; kt[tid] = ak; vt[tid] = av;
}

// K8: temporal attention, one block per (graph b, head hh)
__global__ void k_tattn(const float* __restrict__ qt, const float* __restrict__ kt,
                        const float* __restrict__ vt, float* __restrict__ attn) {
  int b = blockIdx.x >> 2, hh = blockIdx.x & 3;
  __shared__ float ks[NFRM][HDIM];
  __shared__ float vs[NFRM][HDIM];
  int t = threadIdx.x;
  size_t base = ((size_t)b * NFRM + t) * DD + hh * HDIM;
#pragma unroll
  for (int i = 0; i < 4; ++i) {
    ((float4*)ks[t])[i] = *(const float4*)(kt + base + i * 4);
    ((float4*)vs[t])[i] = *(const float4*)(vt + base + i * 4);
  }
  float qv[HDIM];
#pragma unroll
  for (int i = 0; i < 4; ++i) ((float4*)qv)[i] = *(const float4*)(qt + base + i * 4);
  __syncthreads();
  float m = -INFINITY, l = 0.f;
  float acc[HDIM];
#pragma unroll
  for (int k = 0; k < HDIM; ++k) acc[k] = 0.f;
  for (int j = 0; j < NFRM; ++j) {
    float s = 0.f;
#pragma unroll
    for (int k = 0; k < HDIM; ++k) s += qv[k] * ks[j][k];
    s *= SCL;
    float nm = fmaxf(m, s);
    float c = __expf(m - nm);
    float p = __expf(s - nm);
    l = l * c + p;
#pragma unroll
    for (int k = 0; k < HDIM; ++k) acc[k] = acc[k] * c + p * vs[j][k];
    m = nm;
  }
  float inv = 1.0f / l;
#pragma unroll
  for (int k = 0; k < HDIM; ++k) attn[base + k] = acc[k] * inv;
}

// K10: u = relu(xt @ W1 + b1)
__global__ void k_ffn1(const float* __restrict__ xt, const float* __restrict__ W1,
                       const float* __restrict__ b1, float* __restrict__ u) {
  int tid = blockIdx.x * blockDim.x + threadIdx.x;
  int n = tid >> 7, j = tid & 127;
  const float* xr = xt + (size_t)n * DD;
  float a = b1[j];
#pragma unroll 8
  for (int d = 0; d < DD; ++d) a += xr[d] * W1[d * 128 + j];
  u[tid] = fmaxf(a, 0.f);
}

// K11: xt = LN(xt + u @ W2 + b2)
__global__ void k_ffn2_ln(const float* __restrict__ u, const float* __restrict__ W2,
                          const float* __restrict__ b2, const float* __restrict__ g,
                          const float* __restrict__ bb, float* __restrict__ xt) {
  __shared__ float t[4][128];
  int wid = threadIdx.x >> 6, lane = threadIdx.x & 63;
  int n = (blockIdx.x << 2) + wid;
  t[wid][lane] = u[(size_t)n * 128 + lane];
  t[wid][64 + lane] = u[(size_t)n * 128 + 64 + lane];
  __syncthreads();
  size_t base = (size_t)n * DD;
  float o = b2[lane] + xt[base + lane];
#pragma unroll 8
  for (int d = 0; d < 128; ++d) o += t[wid][d] * W2[d * DD + lane];
  float s = o, s2 = o * o;
#pragma unroll
  for (int off = 32; off >= 1; off >>= 1) {
    s += __shfl_xor(s, off);
    s2 += __shfl_xor(s2, off);
  }
  float mean = s * (1.0f / 64.0f);
  float var = s2 * (1.0f / 64.0f) - mean * mean;
  float r = (o - mean) * rsqrtf(var + EPSLN) * g[lane] + bb[lane];
  xt[base + lane] = r;
}

// K12a: agg1 GEMM partials
__global__ void k_agg1a(const float* __restrict__ xt, const float* __restrict__ Wa1,
                        float* __restrict__ part) {
  __shared__ float ws_s[KROWS * DD];  // 32 KB
  int kc = blockIdx.x >> 3, bt = blockIdx.x & 7;
  int t = threadIdx.x, wid = t >> 6, lane = t & 63;
  const float* wsrc = Wa1 + (size_t)kc * KROWS * DD;
  for (int idx = t; idx < KROWS * DD; idx += 256) ws_s[idx] = wsrc[idx];
  __syncthreads();
  for (int bb_ = 0; bb_ < 8; ++bb_) {
    int b = bt * 32 + wid * 8 + bb_;
    const float* xr = xt + (size_t)b * (NFRM * DD) + kc * KROWS;
    float acc = 0.f;
#pragma unroll 8
    for (int i = 0; i < KROWS; ++i) acc += xr[i] * ws_s[i * DD + lane];
    part[(size_t)kc * (BSZ * DD) + (size_t)b * DD + lane] = acc;
  }
}

// K12b: reduce partials
__global__ void k_agg1red(const float* __restrict__ part, float* __restrict__ a1) {
  int g = blockIdx.x * 256 + threadIdx.x;
  float s = 0.f;
#pragma unroll 8
  for (int kc = 0; kc < KSP; ++kc) s += part[(size_t)kc * (BSZ * DD) + g];
  a1[g] = s;
}

// K13: head MLP
__global__ void k_head(const float* __restrict__ a1, const float* __restrict__ ba1,
                       const float* __restrict__ Wa2, const float* __restrict__ ba2,
                       const float* __restrict__ Wh1, const float* __restrict__ bh1,
                       const float* __restrict__ Wh2, const float* __restrict__ bh2,
                       float* __restrict__ out) {
  int b = blockIdx.x, t = threadIdx.x;
  __shared__ float s1[64], s2[32], s3[16];
  s1[t] = fmaxf(a1[b * DD + t] + ba1[t], 0.f);
  __syncthreads();
  if (t < 32) {
    float a = ba2[t];
#pragma unroll 8
    for (int j = 0; j < 64; ++j) a += s1[j] * Wa2[j * 32 + t];
    s2[t] = fmaxf(a, 0.f);
  }
  __syncthreads();
  if (t < 16) {
    float a = bh1[t];
#pragma unroll
    for (int j = 0; j < 32; ++j) a += s2[j] * Wh1[j * 16 + t];
    s3[t] = fmaxf(a, 0.f);
  }
  __syncthreads();
  if (t == 0) {
    float a = bh2[0];
#pragma unroll
    for (int j = 0; j < 16; ++j) a += s3[j] * Wh2[j];
    out[b] = 1.0f / (1.0f + expf(-a));
  }
}

extern "C" void kernel_launch(void* const* d_in, const int* in_sizes, int n_in,
                              void* d_out, int out_size, void* d_ws, size_t ws_size,
                              hipStream_t stream) {
  const float* x   = (const float*)d_in[0];
  const int*   ei  = (const int*)d_in[1];
  const float* Wi  = (const float*)d_in[2];
  const float* bi  = (const float*)d_in[3];
  const float* pe  = (const float*)d_in[4];
  const float* Wq  = (const float*)d_in[5];
  const float* Wk  = (const float*)d_in[6];
  const float* Wv  = (const float*)d_in[7];
  const float* bq  = (const float*)d_in[8];
  const float* bk  = (const float*)d_in[9];
  const float* bv  = (const float*)d_in[10];
  const float* Ws  = (const float*)d_in[11];
  const float* bs  = (const float*)d_in[12];
  const float* Wo  = (const float*)d_in[13];
  const float* bo  = (const float*)d_in[14];
  const float* gg  = (const float*)d_in[15];
  const float* gb  = (const float*)d_in[16];
  const float* Wqt = (const float*)d_in[17];
  const float* Wkt = (const float*)d_in[18];
  const float* Wvt = (const float*)d_in[19];
  const float* bqt = (const float*)d_in[20];
  const float* bkt = (const float*)d_in[21];
  const float* bvt = (const float*)d_in[22];
  const float* Wot = (const float*)d_in[23];
  const float* bot = (const float*)d_in[24];
  const float* l1g = (const float*)d_in[25];
  const float* l1b = (const float*)d_in[26];
  const float* W1  = (const float*)d_in[27];
  const float* b1  = (const float*)d_in[28];
  const float* W2  = (const float*)d_in[29];
  const float* b2  = (const float*)d_in[30];
  const float* l2g = (const float*)d_in[31];
  const float* l2b = (const float*)d_in[32];
  const float* Wa1 = (const float*)d_in[33];
  const float* ba1 = (const float*)d_in[34];
  const float* Wa2 = (const float*)d_in[35];
  const float* ba2 = (const float*)d_in[36];
  const float* Wh1 = (const float*)d_in[37];
  const float* bh1 = (const float*)d_in[38];
  const float* Wh2 = (const float*)d_in[39];
  const float* bh2 = (const float*)d_in[40];
  float* out = (float*)d_out;

  const size_t ND = (size_t)NN * DD;   // 4,194,304

  float* wsf    = (float*)d_ws;
  float* f_h    = wsf;                 // h / xt
  float* f_q    = f_h  + ND;           // q  -> qt
  float* f_k    = f_q  + ND;           // kv (bf16 packed) -> kt
  float* f_v    = f_k  + ND;           // v  -> vt
  float* f_sk   = f_v  + ND;           // skip -> attn
  float* f_u    = f_sk + ND;           // ffn hidden [N,128]
  float* f_part = f_u  + 2 * ND;       // agg1 partials [KSP][BSZ][DD] = 8 MB
  float* f_a1   = f_part + (size_t)KSP * BSZ * DD;
  int* i_srcs   = (int*)(f_a1 + BSZ * DD);  // CSR src list [NE]
  int* i_rowptr = i_srcs + NE;              // [NN+1]
  int* i_cursor = i_rowptr + NN + 1;        // [NN]
  int* i_cnt    = i_cursor + NN;            // [NN]
  int* i_bsum   = i_cnt + NN;               // [256]
  int* i_boff   = i_bsum + 256;             // [256]

  ushort2* f_kv = (ushort2*)f_k;

  hipMemsetAsync(i_cnt, 0, NN * sizeof(int), stream);

  dim3 B(256);
  // 1. input proj + PE
  k_input<<<dim3((NN * DD) / 256), B, 0, stream>>>(x, Wi, bi, pe, f_h);
  // 2. q, kv(bf16), skip
  k_qkvs<<<dim3((NN * DD) / 256), B, 0, stream>>>(f_h, Wq, Wk, Wv, Ws, bq, bk, bv, bs,
                                                  f_q, f_kv, f_sk);
  // 3. CSR build
  k_count<<<dim3(NE / 256), B, 0, stream>>>(ei, i_cnt);
  k_scan1<<<dim3(NN / 256), B, 0, stream>>>(i_cnt, i_rowptr, i_bsum);
  k_scan2<<<dim3(1), B, 0, stream>>>(i_bsum, i_boff);
  k_scan3<<<dim3(NN / 256), B, 0, stream>>>(i_rowptr, i_boff, i_cursor);
  k_scatter<<<dim3(NE / 256), B, 0, stream>>>(ei, i_cursor, i_srcs);
  // 4. fused graph attention + skip + Wo + residual LN -> f_h
  k_gattn_ln<<<dim3(NN / 4), B, 0, stream>>>(f_q, f_kv, i_rowptr, i_srcs, f_sk,
                                             Wo, bo, gg, gb, f_h);
  // 5. temporal q,k,v
  k_qkvt<<<dim3((NN * DD) / 256), B, 0, stream>>>(f_h, Wqt, Wkt, Wvt, bqt, bkt, bvt,
                                                  f_q, f_k, f_v);
  // 6. temporal attention -> f_sk
  k_tattn<<<dim3(BSZ * HH), B, 0, stream>>>(f_q, f_k, f_v, f_sk);
  // 7. attn@Wot + bot, residual + LN1 -> f_h
  k_matln<<<dim3(NN / 4), B, 0, stream>>>(f_sk, Wot, bot, l1g, l1b, f_h);
  // 8-9. FFN + LN2
  k_ffn1<<<dim3((NN * 128) / 256), B, 0, stream>>>(f_h, W1, b1, f_u);
  k_ffn2_ln<<<dim3(NN / 4), B, 0, stream>>>(f_u, W2, b2, l2g, l2b, f_h);
  // 10. aggregation GEMM
  k_agg1a<<<dim3(KSP * 8), B, 0, stream>>>(f_h, Wa1, f_part);
  k_agg1red<<<dim3(BSZ * DD / 256), B, 0, stream>>>(f_part, f_a1);
  // 11. head MLP
  k_head<<<dim3(BSZ), dim3(64), 0, stream>>>(f_a1, ba1, Wa2, ba2, Wh1, bh1, Wh2, bh2, out);
}

// Round 4
// 620.529 us; speedup vs baseline: 1.8811x; 1.4532x over previous
//
#include <hip/hip_runtime.h>
#include <math.h>

#define NN 65536
#define SIN 24
#define DD 64
#define HH 4
#define HDIM 16
#define NFRM 256
#define NE 1048576
#define BSZ 256
#define EPSLN 1e-5f
#define SCL 0.25f
#define RB 8        // rows per wave in row-blocked dense kernels

#define KSP 128     // K-chunks for agg1 GEMM
#define KROWS 128   // rows of Wa1 per chunk (KSP*KROWS = 16384)

__device__ __forceinline__ unsigned short f2bf(float f) {
  unsigned u = __float_as_uint(f);
  return (unsigned short)((u + 0x7FFFu + ((u >> 16) & 1u)) >> 16);
}
__device__ __forceinline__ float bf2f(unsigned short b) {
  return __uint_as_float(((unsigned)b) << 16);
}

// K1: h = x @ Wi + bi + pe[n % NF]   (8 rows/wave)
__global__ void k_input(const float* __restrict__ x, const float* __restrict__ Wi,
                        const float* __restrict__ bi, const float* __restrict__ pe,
                        float* __restrict__ h) {
  int lane = threadIdx.x & 63;
  int wid = __builtin_amdgcn_readfirstlane(threadIdx.x >> 6);
  int n0 = (blockIdx.x * 4 + wid) * RB;
  float b = bi[lane];
  float acc[RB];
#pragma unroll
  for (int r = 0; r < RB; ++r) acc[r] = b + pe[((n0 + r) & (NFRM - 1)) * DD + lane];
  for (int s = 0; s < SIN; ++s) {
    float w = Wi[s * DD + lane];
#pragma unroll
    for (int r = 0; r < RB; ++r) acc[r] += x[(size_t)(n0 + r) * SIN + s] * w;
  }
#pragma unroll
  for (int r = 0; r < RB; ++r) h[(size_t)(n0 + r) * DD + lane] = acc[r];
}

// K2: q (fp32), kv (packed bf16 {k,v}), skip (fp32)   (8 rows/wave)
__global__ void k_qkvs(const float* __restrict__ h,
                       const float* __restrict__ Wq, const float* __restrict__ Wk,
                       const float* __restrict__ Wv, const float* __restrict__ Ws,
                       const float* __restrict__ bq, const float* __restrict__ bk,
                       const float* __restrict__ bv, const float* __restrict__ bs,
                       float* __restrict__ q, ushort2* __restrict__ kv,
                       float* __restrict__ sk) {
  int lane = threadIdx.x & 63;
  int wid = __builtin_amdgcn_readfirstlane(threadIdx.x >> 6);
  int n0 = (blockIdx.x * 4 + wid) * RB;
  int hh = lane >> 4, kk = lane & 15;
  const float* wqp = Wq + (size_t)hh * DD * HDIM + kk;
  const float* wkp = Wk + (size_t)hh * DD * HDIM + kk;
  const float* wvp = Wv + (size_t)hh * DD * HDIM + kk;
  const float* wsp = Ws + (size_t)hh * DD * HDIM + kk;
  float aq[RB], ak[RB], av[RB], as_[RB];
  float bq_ = bq[lane], bk_ = bk[lane], bv_ = bv[lane], bs_ = bs[lane];
#pragma unroll
  for (int r = 0; r < RB; ++r) { aq[r] = bq_; ak[r] = bk_; av[r] = bv_; as_[r] = bs_; }
#pragma unroll 2
  for (int d = 0; d < DD; ++d) {
    float wq = wqp[d * HDIM], wk = wkp[d * HDIM];
    float wv = wvp[d * HDIM], ws = wsp[d * HDIM];
#pragma unroll
    for (int r = 0; r < RB; ++r) {
      float hd = h[(size_t)(n0 + r) * DD + d];
      aq[r] += hd * wq; ak[r] += hd * wk; av[r] += hd * wv; as_[r] += hd * ws;
    }
  }
#pragma unroll
  for (int r = 0; r < RB; ++r) {
    size_t o = (size_t)(n0 + r) * DD + lane;
    q[o] = aq[r];
    kv[o] = make_ushort2(f2bf(ak[r]), f2bf(av[r]));
    sk[o] = as_[r];
  }
}

// ---- CSR build ----
__global__ void k_count(const int* __restrict__ ei, int* __restrict__ cnt) {
  int e = blockIdx.x * 256 + threadIdx.x;
  atomicAdd(&cnt[ei[NE + e]], 1);
}

__global__ void k_scan1(const int* __restrict__ cnt, int* __restrict__ rowptr,
                        int* __restrict__ bsum) {
  __shared__ int s[256];
  int t = threadIdx.x, base = blockIdx.x << 8;
  int v = cnt[base + t];
  s[t] = v; __syncthreads();
  for (int off = 1; off < 256; off <<= 1) {
    int x = (t >= off) ? s[t - off] : 0;
    __syncthreads();
    s[t] += x;
    __syncthreads();
  }
  rowptr[base + t] = s[t] - v;
  if (t == 255) bsum[blockIdx.x] = s[255];
}

__global__ void k_scan2(const int* __restrict__ bsum, int* __restrict__ boff) {
  __shared__ int s[256];
  int t = threadIdx.x;
  int v = bsum[t];
  s[t] = v; __syncthreads();
  for (int off = 1; off < 256; off <<= 1) {
    int x = (t >= off) ? s[t - off] : 0;
    __syncthreads();
    s[t] += x;
    __syncthreads();
  }
  boff[t] = s[t] - v;
}

__global__ void k_scan3(int* __restrict__ rowptr, const int* __restrict__ boff,
                        int* __restrict__ cursor) {
  int g = blockIdx.x * 256 + threadIdx.x;
  int r = rowptr[g] + boff[g >> 8];
  rowptr[g] = r; cursor[g] = r;
  if (g == 0) rowptr[NN] = NE;
}

__global__ void k_scatter(const int* __restrict__ ei, int* __restrict__ cursor,
                          int* __restrict__ srcs) {
  int e = blockIdx.x * 256 + threadIdx.x;
  int dst = ei[NE + e];
  int pos = atomicAdd(&cursor[dst], 1);
  srcs[pos] = ei[e];
}

// Graph attention (bf16 kv gather, 4-way unrolled online softmax) + skip -> tmp
__global__ void k_gattn(const float* __restrict__ q, const ushort2* __restrict__ kv,
                        const int* __restrict__ rowptr,
                        const int* __restrict__ srcs, const float* __restrict__ sk,
                        float* __restrict__ tmp) {
  int wid = threadIdx.x >> 6, lane = threadIdx.x & 63;
  int dst = (blockIdx.x << 2) + wid;
  size_t base = (size_t)dst * DD;
  float qv = q[base + lane];
  int beg = rowptr[dst], end = rowptr[dst + 1];
  float m = -INFINITY, l = 0.f, acc = 0.f;
  int idx = beg;
  for (; idx + 4 <= end; idx += 4) {
    int s0 = srcs[idx], s1 = srcs[idx + 1], s2 = srcs[idx + 2], s3 = srcs[idx + 3];
    ushort2 a0 = kv[(size_t)s0 * DD + lane];
    ushort2 a1 = kv[(size_t)s1 * DD + lane];
    ushort2 a2 = kv[(size_t)s2 * DD + lane];
    ushort2 a3 = kv[(size_t)s3 * DD + lane];
    float t0 = qv * bf2f(a0.x), t1 = qv * bf2f(a1.x);
    float t2 = qv * bf2f(a2.x), t3 = qv * bf2f(a3.x);
#pragma unroll
    for (int off = 1; off <= 8; off <<= 1) {
      t0 += __shfl_xor(t0, off);
      t1 += __shfl_xor(t1, off);
      t2 += __shfl_xor(t2, off);
      t3 += __shfl_xor(t3, off);
    }
    t0 *= SCL; t1 *= SCL; t2 *= SCL; t3 *= SCL;
    float nm = fmaxf(fmaxf(m, fmaxf(t0, t1)), fmaxf(t2, t3));
    float c = __expf(m - nm);
    float p0 = __expf(t0 - nm), p1 = __expf(t1 - nm);
    float p2 = __expf(t2 - nm), p3 = __expf(t3 - nm);
    l = l * c + ((p0 + p1) + (p2 + p3));
    acc = acc * c + ((p0 * bf2f(a0.y) + p1 * bf2f(a1.y)) +
                     (p2 * bf2f(a2.y) + p3 * bf2f(a3.y)));
    m = nm;
  }
  for (; idx < end; ++idx) {
    int s0 = srcs[idx];
    ushort2 a0 = kv[(size_t)s0 * DD + lane];
    float t0 = qv * bf2f(a0.x);
#pragma unroll
    for (int off = 1; off <= 8; off <<= 1) t0 += __shfl_xor(t0, off);
    t0 *= SCL;
    float nm = fmaxf(m, t0);
    float c = __expf(m - nm), p = __expf(t0 - nm);
    l = l * c + p;
    acc = acc * c + p * bf2f(a0.y);
    m = nm;
  }
  float aggv = (end > beg) ? acc / l : 0.f;
  tmp[base + lane] = aggv + sk[base + lane];
}

// io = LN(io + in1 @ Wm + bias)   (8 rows/wave, weights amortized)
__global__ void k_matln(const float* __restrict__ in1,
                        const float* __restrict__ Wm, const float* __restrict__ bias,
                        const float* __restrict__ g, const float* __restrict__ bb,
                        float* __restrict__ io) {
  int lane = threadIdx.x & 63;
  int wid = __builtin_amdgcn_readfirstlane(threadIdx.x >> 6);
  int n0 = (blockIdx.x * 4 + wid) * RB;
  float acc[RB];
#pragma unroll
  for (int r = 0; r < RB; ++r) acc[r] = 0.f;
#pragma unroll 2
  for (int d = 0; d < DD; ++d) {
    float w = Wm[d * DD + lane];
#pragma unroll
    for (int r = 0; r < RB; ++r) acc[r] += in1[(size_t)(n0 + r) * DD + d] * w;
  }
  float bi_ = bias[lane], g_ = g[lane], bb_ = bb[lane];
#pragma unroll
  for (int r = 0; r < RB; ++r) {
    size_t o_idx = (size_t)(n0 + r) * DD + lane;
    float o = acc[r] + bi_ + io[o_idx];
    float s = o, s2 = o * o;
#pragma unroll
    for (int off = 32; off >= 1; off >>= 1) {
      s += __shfl_xor(s, off);
      s2 += __shfl_xor(s2, off);
    }
    float mean = s * (1.0f / 64.0f);
    float var = s2 * (1.0f / 64.0f) - mean * mean;
    io[o_idx] = (o - mean) * rsqrtf(var + EPSLN) * g_ + bb_;
  }
}

// K7: qt, kt, vt projections   (8 rows/wave)
__global__ void k_qkvt(const float* __restrict__ xt,
                       const float* __restrict__ Wqt, const float* __restrict__ Wkt,
                       const float* __restrict__ Wvt,
                       const float* __restrict__ bqt, const float* __restrict__ bkt,
                       const float* __restrict__ bvt,
                       float* __restrict__ qt, float* __restrict__ kt, float* __restrict__ vt) {
  int lane = threadIdx.x & 63;
  int wid = __builtin_amdgcn_readfirstlane(threadIdx.x >> 6);
  int n0 = (blockIdx.x * 4 + wid) * RB;
  float aq[RB], ak[RB], av[RB];
  float bq_ = bqt[lane], bk_ = bkt[lane], bv_ = bvt[lane];
#pragma unroll
  for (int r = 0; r < RB; ++r) { aq[r] = bq_; ak[r] = bk_; av[r] = bv_; }
#pragma unroll 2
  for (int d = 0; d < DD; ++d) {
    float wq = Wqt[d * DD + lane], wk = Wkt[d * DD + lane], wv = Wvt[d * DD + lane];
#pragma unroll
    for (int r = 0; r < RB; ++r) {
      float xd = xt[(size_t)(n0 + r) * DD + d];
      aq[r] += xd * wq; ak[r] += xd * wk; av[r] += xd * wv;
    }
  }
#pragma unroll
  for (int r = 0; r < RB; ++r) {
    size_t o = (size_t)(n0 + r) * DD + lane;
    qt[o] = aq[r]; kt[o] = ak[r]; vt[o] = av[r];
  }
}

// K8: temporal attention, one block per (graph b, head hh)
__global__ void k_tattn(const float* __restrict__ qt, const float* __restrict__ kt,
                        const float* __restrict__ vt, float* __restrict__ attn) {
  int b = blockIdx.x >> 2, hh = blockIdx.x & 3;
  __shared__ float ks[NFRM][HDIM];
  __shared__ float vs[NFRM][HDIM];
  int t = threadIdx.x;
  size_t base = ((size_t)b * NFRM + t) * DD + hh * HDIM;
#pragma unroll
  for (int i = 0; i < 4; ++i) {
    ((float4*)ks[t])[i] = *(const float4*)(kt + base + i * 4);
    ((float4*)vs[t])[i] = *(const float4*)(vt + base + i * 4);
  }
  float qv[HDIM];
#pragma unroll
  for (int i = 0; i < 4; ++i) ((float4*)qv)[i] = *(const float4*)(qt + base + i * 4);
  __syncthreads();
  float m = -INFINITY, l = 0.f;
  float acc[HDIM];
#pragma unroll
  for (int k = 0; k < HDIM; ++k) acc[k] = 0.f;
  for (int j = 0; j < NFRM; ++j) {
    float s = 0.f;
#pragma unroll
    for (int k = 0; k < HDIM; ++k) s += qv[k] * ks[j][k];
    s *= SCL;
    float nm = fmaxf(m, s);
    float c = __expf(m - nm);
    float p = __expf(s - nm);
    l = l * c + p;
#pragma unroll
    for (int k = 0; k < HDIM; ++k) acc[k] = acc[k] * c + p * vs[j][k];
    m = nm;
  }
  float inv = 1.0f / l;
#pragma unroll
  for (int k = 0; k < HDIM; ++k) attn[base + k] = acc[k] * inv;
}

// K10: u = relu(xt @ W1 + b1)   (8 rows/wave, 2 waves per 128-col row)
__global__ void k_ffn1(const float* __restrict__ xt, const float* __restrict__ W1,
                       const float* __restrict__ b1, float* __restrict__ u) {
  int lane = threadIdx.x & 63;
  int wid = __builtin_amdgcn_readfirstlane(threadIdx.x >> 6);
  int j = (wid & 1) * 64 + lane;
  int n0 = (blockIdx.x * 2 + (wid >> 1)) * RB;
  float acc[RB];
  float b_ = b1[j];
#pragma unroll
  for (int r = 0; r < RB; ++r) acc[r] = b_;
#pragma unroll 2
  for (int d = 0; d < DD; ++d) {
    float w = W1[d * 128 + j];
#pragma unroll
    for (int r = 0; r < RB; ++r) acc[r] += xt[(size_t)(n0 + r) * DD + d] * w;
  }
#pragma unroll
  for (int r = 0; r < RB; ++r) u[(size_t)(n0 + r) * 128 + j] = fmaxf(acc[r], 0.f);
}

// K11: xt = LN(xt + u @ W2 + b2)   (8 rows/wave)
__global__ void k_ffn2_ln(const float* __restrict__ u, const float* __restrict__ W2,
                          const float* __restrict__ b2, const float* __restrict__ g,
                          const float* __restrict__ bb, float* __restrict__ xt) {
  int lane = threadIdx.x & 63;
  int wid = __builtin_amdgcn_readfirstlane(threadIdx.x >> 6);
  int n0 = (blockIdx.x * 4 + wid) * RB;
  float acc[RB];
#pragma unroll
  for (int r = 0; r < RB; ++r) acc[r] = 0.f;
#pragma unroll 2
  for (int d = 0; d < 128; ++d) {
    float w = W2[d * DD + lane];
#pragma unroll
    for (int r = 0; r < RB; ++r) acc[r] += u[(size_t)(n0 + r) * 128 + d] * w;
  }
  float bi_ = b2[lane], g_ = g[lane], bb_ = bb[lane];
#pragma unroll
  for (int r = 0; r < RB; ++r) {
    size_t o_idx = (size_t)(n0 + r) * DD + lane;
    float o = acc[r] + bi_ + xt[o_idx];
    float s = o, s2 = o * o;
#pragma unroll
    for (int off = 32; off >= 1; off >>= 1) {
      s += __shfl_xor(s, off);
      s2 += __shfl_xor(s2, off);
    }
    float mean = s * (1.0f / 64.0f);
    float var = s2 * (1.0f / 64.0f) - mean * mean;
    xt[o_idx] = (o - mean) * rsqrtf(var + EPSLN) * g_ + bb_;
  }
}

// K12a: agg1 GEMM partials
__global__ void k_agg1a(const float* __restrict__ xt, const float* __restrict__ Wa1,
                        float* __restrict__ part) {
  __shared__ float ws_s[KROWS * DD];  // 32 KB
  int kc = blockIdx.x >> 3, bt = blockIdx.x & 7;
  int t = threadIdx.x, wid = t >> 6, lane = t & 63;
  const float* wsrc = Wa1 + (size_t)kc * KROWS * DD;
  for (int idx = t; idx < KROWS * DD; idx += 256) ws_s[idx] = wsrc[idx];
  __syncthreads();
  for (int bb_ = 0; bb_ < 8; ++bb_) {
    int b = bt * 32 + wid * 8 + bb_;
    const float* xr = xt + (size_t)b * (NFRM * DD) + kc * KROWS;
    float acc = 0.f;
#pragma unroll 8
    for (int i = 0; i < KROWS; ++i) acc += xr[i] * ws_s[i * DD + lane];
    part[(size_t)kc * (BSZ * DD) + (size_t)b * DD + lane] = acc;
  }
}

// K12b: reduce partials
__global__ void k_agg1red(const float* __restrict__ part, float* __restrict__ a1) {
  int g = blockIdx.x * 256 + threadIdx.x;
  float s = 0.f;
#pragma unroll 8
  for (int kc = 0; kc < KSP; ++kc) s += part[(size_t)kc * (BSZ * DD) + g];
  a1[g] = s;
}

// K13: head MLP
__global__ void k_head(const float* __restrict__ a1, const float* __restrict__ ba1,
                       const float* __restrict__ Wa2, const float* __restrict__ ba2,
                       const float* __restrict__ Wh1, const float* __restrict__ bh1,
                       const float* __restrict__ Wh2, const float* __restrict__ bh2,
                       float* __restrict__ out) {
  int b = blockIdx.x, t = threadIdx.x;
  __shared__ float s1[64], s2[32], s3[16];
  s1[t] = fmaxf(a1[b * DD + t] + ba1[t], 0.f);
  __syncthreads();
  if (t < 32) {
    float a = ba2[t];
#pragma unroll 8
    for (int j = 0; j < 64; ++j) a += s1[j] * Wa2[j * 32 + t];
    s2[t] = fmaxf(a, 0.f);
  }
  __syncthreads();
  if (t < 16) {
    float a = bh1[t];
#pragma unroll
    for (int j = 0; j < 32; ++j) a += s2[j] * Wh1[j * 16 + t];
    s3[t] = fmaxf(a, 0.f);
  }
  __syncthreads();
  if (t == 0) {
    float a = bh2[0];
#pragma unroll
    for (int j = 0; j < 16; ++j) a += s3[j] * Wh2[j];
    out[b] = 1.0f / (1.0f + expf(-a));
  }
}

extern "C" void kernel_launch(void* const* d_in, const int* in_sizes, int n_in,
                              void* d_out, int out_size, void* d_ws, size_t ws_size,
                              hipStream_t stream) {
  const float* x   = (const float*)d_in[0];
  const int*   ei  = (const int*)d_in[1];
  const float* Wi  = (const float*)d_in[2];
  const float* bi  = (const float*)d_in[3];
  const float* pe  = (const float*)d_in[4];
  const float* Wq  = (const float*)d_in[5];
  const float* Wk  = (const float*)d_in[6];
  const float* Wv  = (const float*)d_in[7];
  const float* bq  = (const float*)d_in[8];
  const float* bk  = (const float*)d_in[9];
  const float* bv  = (const float*)d_in[10];
  const float* Ws  = (const float*)d_in[11];
  const float* bs  = (const float*)d_in[12];
  const float* Wo  = (const float*)d_in[13];
  const float* bo  = (const float*)d_in[14];
  const float* gg  = (const float*)d_in[15];
  const float* gb  = (const float*)d_in[16];
  const float* Wqt = (const float*)d_in[17];
  const float* Wkt = (const float*)d_in[18];
  const float* Wvt = (const float*)d_in[19];
  const float* bqt = (const float*)d_in[20];
  const float* bkt = (const float*)d_in[21];
  const float* bvt = (const float*)d_in[22];
  const float* Wot = (const float*)d_in[23];
  const float* bot = (const float*)d_in[24];
  const float* l1g = (const float*)d_in[25];
  const float* l1b = (const float*)d_in[26];
  const float* W1  = (const float*)d_in[27];
  const float* b1  = (const float*)d_in[28];
  const float* W2  = (const float*)d_in[29];
  const float* b2  = (const float*)d_in[30];
  const float* l2g = (const float*)d_in[31];
  const float* l2b = (const float*)d_in[32];
  const float* Wa1 = (const float*)d_in[33];
  const float* ba1 = (const float*)d_in[34];
  const float* Wa2 = (const float*)d_in[35];
  const float* ba2 = (const float*)d_in[36];
  const float* Wh1 = (const float*)d_in[37];
  const float* bh1 = (const float*)d_in[38];
  const float* Wh2 = (const float*)d_in[39];
  const float* bh2 = (const float*)d_in[40];
  float* out = (float*)d_out;

  const size_t ND = (size_t)NN * DD;   // 4,194,304

  float* wsf    = (float*)d_ws;
  float* f_h    = wsf;                 // h / xt
  float* f_q    = f_h  + ND;           // q  -> qt
  float* f_k    = f_q  + ND;           // kv (bf16 packed) -> kt
  float* f_v    = f_k  + ND;           // v  -> vt
  float* f_sk   = f_v  + ND;           // skip -> attn
  float* f_u    = f_sk + ND;           // gattn tmp, then ffn hidden [N,128]
  float* f_part = f_u  + 2 * ND;       // agg1 partials [KSP][BSZ][DD] = 8 MB
  float* f_a1   = f_part + (size_t)KSP * BSZ * DD;
  int* i_srcs   = (int*)(f_a1 + BSZ * DD);  // CSR src list [NE]
  int* i_rowptr = i_srcs + NE;              // [NN+1]
  int* i_cursor = i_rowptr + NN + 1;        // [NN]
  int* i_cnt    = i_cursor + NN;            // [NN]
  int* i_bsum   = i_cnt + NN;               // [256]
  int* i_boff   = i_bsum + 256;             // [256]

  ushort2* f_kv = (ushort2*)f_k;
  float* f_tmp  = f_u;                 // gattn output (free until ffn1)

  hipMemsetAsync(i_cnt, 0, NN * sizeof(int), stream);

  dim3 B(256);
  // 1. input proj + PE
  k_input<<<dim3(NN / (4 * RB)), B, 0, stream>>>(x, Wi, bi, pe, f_h);
  // 2. q, kv(bf16), skip
  k_qkvs<<<dim3(NN / (4 * RB)), B, 0, stream>>>(f_h, Wq, Wk, Wv, Ws, bq, bk, bv, bs,
                                                f_q, f_kv, f_sk);
  // 3. CSR build
  k_count<<<dim3(NE / 256), B, 0, stream>>>(ei, i_cnt);
  k_scan1<<<dim3(NN / 256), B, 0, stream>>>(i_cnt, i_rowptr, i_bsum);
  k_scan2<<<dim3(1), B, 0, stream>>>(i_bsum, i_boff);
  k_scan3<<<dim3(NN / 256), B, 0, stream>>>(i_rowptr, i_boff, i_cursor);
  k_scatter<<<dim3(NE / 256), B, 0, stream>>>(ei, i_cursor, i_srcs);
  // 4. graph attention + skip -> f_tmp; then Wo matmul + residual LN -> f_h
  k_gattn<<<dim3(NN / 4), B, 0, stream>>>(f_q, f_kv, i_rowptr, i_srcs, f_sk, f_tmp);
  k_matln<<<dim3(NN / (4 * RB)), B, 0, stream>>>(f_tmp, Wo, bo, gg, gb, f_h);
  // 5. temporal q,k,v
  k_qkvt<<<dim3(NN / (4 * RB)), B, 0, stream>>>(f_h, Wqt, Wkt, Wvt, bqt, bkt, bvt,
                                                f_q, f_k, f_v);
  // 6. temporal attention -> f_sk
  k_tattn<<<dim3(BSZ * HH), B, 0, stream>>>(f_q, f_k, f_v, f_sk);
  // 7. attn@Wot + bot, residual + LN1 -> f_h
  k_matln<<<dim3(NN / (4 * RB)), B, 0, stream>>>(f_sk, Wot, bot, l1g, l1b, f_h);
  // 8-9. FFN + LN2
  k_ffn1<<<dim3(NN / (2 * RB)), B, 0, stream>>>(f_h, W1, b1, f_u);
  k_ffn2_ln<<<dim3(NN / (4 * RB)), B, 0, stream>>>(f_u, W2, b2, l2g, l2b, f_h);
  // 10. aggregation GEMM
  k_agg1a<<<dim3(KSP * 8), B, 0, stream>>>(f_h, Wa1, f_part);
  k_agg1red<<<dim3(BSZ * DD / 256), B, 0, stream>>>(f_part, f_a1);
  // 11. head MLP
  k_head<<<dim3(BSZ), dim3(64), 0, stream>>>(f_a1, ba1, Wa2, ba2, Wh1, bh1, Wh2, bh2, out);
}

// Round 5
// 550.124 us; speedup vs baseline: 2.1218x; 1.1280x over previous
//
#include <hip/hip_runtime.h>
#include <math.h>

#define NN 65536
#define SIN 24
#define DD 64
#define HH 4
#define HDIM 16
#define NFRM 256
#define NE 1048576
#define BSZ 256
#define EPSLN 1e-5f
#define SCL 0.25f
#define RB 8        // rows per wave in row-blocked dense kernels

#define KSP 128     // K-chunks for agg1 GEMM
#define KROWS 128   // rows of Wa1 per chunk (KSP*KROWS = 16384)

typedef __attribute__((ext_vector_type(8))) short bf16x8;
typedef __attribute__((ext_vector_type(4))) float f32x4;

__device__ __forceinline__ unsigned short f2bf(float f) {
  unsigned u = __float_as_uint(f);
  return (unsigned short)((u + 0x7FFFu + ((u >> 16) & 1u)) >> 16);
}
__device__ __forceinline__ float bf2f(unsigned short b) {
  return __uint_as_float(((unsigned)b) << 16);
}

// K1: h = x @ Wi + bi + pe[n % NF]   (8 rows/wave)
__global__ void k_input(const float* __restrict__ x, const float* __restrict__ Wi,
                        const float* __restrict__ bi, const float* __restrict__ pe,
                        float* __restrict__ h) {
  int lane = threadIdx.x & 63;
  int wid = __builtin_amdgcn_readfirstlane(threadIdx.x >> 6);
  int n0 = (blockIdx.x * 4 + wid) * RB;
  float b = bi[lane];
  float acc[RB];
#pragma unroll
  for (int r = 0; r < RB; ++r) acc[r] = b + pe[((n0 + r) & (NFRM - 1)) * DD + lane];
  for (int s = 0; s < SIN; ++s) {
    float w = Wi[s * DD + lane];
#pragma unroll
    for (int r = 0; r < RB; ++r) acc[r] += x[(size_t)(n0 + r) * SIN + s] * w;
  }
#pragma unroll
  for (int r = 0; r < RB; ++r) h[(size_t)(n0 + r) * DD + lane] = acc[r];
}

// K2: q (fp32), kv (packed bf16 {k,v}), skip (fp32)   (8 rows/wave)
__global__ void k_qkvs(const float* __restrict__ h,
                       const float* __restrict__ Wq, const float* __restrict__ Wk,
                       const float* __restrict__ Wv, const float* __restrict__ Ws,
                       const float* __restrict__ bq, const float* __restrict__ bk,
                       const float* __restrict__ bv, const float* __restrict__ bs,
                       float* __restrict__ q, ushort2* __restrict__ kv,
                       float* __restrict__ sk) {
  int lane = threadIdx.x & 63;
  int wid = __builtin_amdgcn_readfirstlane(threadIdx.x >> 6);
  int n0 = (blockIdx.x * 4 + wid) * RB;
  int hh = lane >> 4, kk = lane & 15;
  const float* wqp = Wq + (size_t)hh * DD * HDIM + kk;
  const float* wkp = Wk + (size_t)hh * DD * HDIM + kk;
  const float* wvp = Wv + (size_t)hh * DD * HDIM + kk;
  const float* wsp = Ws + (size_t)hh * DD * HDIM + kk;
  float aq[RB], ak[RB], av[RB], as_[RB];
  float bq_ = bq[lane], bk_ = bk[lane], bv_ = bv[lane], bs_ = bs[lane];
#pragma unroll
  for (int r = 0; r < RB; ++r) { aq[r] = bq_; ak[r] = bk_; av[r] = bv_; as_[r] = bs_; }
#pragma unroll 2
  for (int d = 0; d < DD; ++d) {
    float wq = wqp[d * HDIM], wk = wkp[d * HDIM];
    float wv = wvp[d * HDIM], ws = wsp[d * HDIM];
#pragma unroll
    for (int r = 0; r < RB; ++r) {
      float hd = h[(size_t)(n0 + r) * DD + d];
      aq[r] += hd * wq; ak[r] += hd * wk; av[r] += hd * wv; as_[r] += hd * ws;
    }
  }
#pragma unroll
  for (int r = 0; r < RB; ++r) {
    size_t o = (size_t)(n0 + r) * DD + lane;
    q[o] = aq[r];
    kv[o] = make_ushort2(f2bf(ak[r]), f2bf(av[r]));
    sk[o] = as_[r];
  }
}

// ---- CSR build ----
__global__ void k_count(const int* __restrict__ ei, int* __restrict__ cnt) {
  int e = blockIdx.x * 256 + threadIdx.x;
  atomicAdd(&cnt[ei[NE + e]], 1);
}

__global__ void k_scan1(const int* __restrict__ cnt, int* __restrict__ rowptr,
                        int* __restrict__ bsum) {
  __shared__ int s[256];
  int t = threadIdx.x, base = blockIdx.x << 8;
  int v = cnt[base + t];
  s[t] = v; __syncthreads();
  for (int off = 1; off < 256; off <<= 1) {
    int x = (t >= off) ? s[t - off] : 0;
    __syncthreads();
    s[t] += x;
    __syncthreads();
  }
  rowptr[base + t] = s[t] - v;
  if (t == 255) bsum[blockIdx.x] = s[255];
}

__global__ void k_scan2(const int* __restrict__ bsum, int* __restrict__ boff) {
  __shared__ int s[256];
  int t = threadIdx.x;
  int v = bsum[t];
  s[t] = v; __syncthreads();
  for (int off = 1; off < 256; off <<= 1) {
    int x = (t >= off) ? s[t - off] : 0;
    __syncthreads();
    s[t] += x;
    __syncthreads();
  }
  boff[t] = s[t] - v;
}

__global__ void k_scan3(int* __restrict__ rowptr, const int* __restrict__ boff,
                        int* __restrict__ cursor) {
  int g = blockIdx.x * 256 + threadIdx.x;
  int r = rowptr[g] + boff[g >> 8];
  rowptr[g] = r; cursor[g] = r;
  if (g == 0) rowptr[NN] = NE;
}

__global__ void k_scatter(const int* __restrict__ ei, int* __restrict__ cursor,
                          int* __restrict__ srcs) {
  int e = blockIdx.x * 256 + threadIdx.x;
  int dst = ei[NE + e];
  int pos = atomicAdd(&cursor[dst], 1);
  srcs[pos] = ei[e];
}

// Graph attention (bf16 kv gather, 4-way unrolled online softmax) + skip -> tmp
__global__ void k_gattn(const float* __restrict__ q, const ushort2* __restrict__ kv,
                        const int* __restrict__ rowptr,
                        const int* __restrict__ srcs, const float* __restrict__ sk,
                        float* __restrict__ tmp) {
  int wid = threadIdx.x >> 6, lane = threadIdx.x & 63;
  int dst = (blockIdx.x << 2) + wid;
  size_t base = (size_t)dst * DD;
  float qv = q[base + lane];
  int beg = rowptr[dst], end = rowptr[dst + 1];
  float m = -INFINITY, l = 0.f, acc = 0.f;
  int idx = beg;
  for (; idx + 4 <= end; idx += 4) {
    int s0 = srcs[idx], s1 = srcs[idx + 1], s2 = srcs[idx + 2], s3 = srcs[idx + 3];
    ushort2 a0 = kv[(size_t)s0 * DD + lane];
    ushort2 a1 = kv[(size_t)s1 * DD + lane];
    ushort2 a2 = kv[(size_t)s2 * DD + lane];
    ushort2 a3 = kv[(size_t)s3 * DD + lane];
    float t0 = qv * bf2f(a0.x), t1 = qv * bf2f(a1.x);
    float t2 = qv * bf2f(a2.x), t3 = qv * bf2f(a3.x);
#pragma unroll
    for (int off = 1; off <= 8; off <<= 1) {
      t0 += __shfl_xor(t0, off);
      t1 += __shfl_xor(t1, off);
      t2 += __shfl_xor(t2, off);
      t3 += __shfl_xor(t3, off);
    }
    t0 *= SCL; t1 *= SCL; t2 *= SCL; t3 *= SCL;
    float nm = fmaxf(fmaxf(m, fmaxf(t0, t1)), fmaxf(t2, t3));
    float c = __expf(m - nm);
    float p0 = __expf(t0 - nm), p1 = __expf(t1 - nm);
    float p2 = __expf(t2 - nm), p3 = __expf(t3 - nm);
    l = l * c + ((p0 + p1) + (p2 + p3));
    acc = acc * c + ((p0 * bf2f(a0.y) + p1 * bf2f(a1.y)) +
                     (p2 * bf2f(a2.y) + p3 * bf2f(a3.y)));
    m = nm;
  }
  for (; idx < end; ++idx) {
    int s0 = srcs[idx];
    ushort2 a0 = kv[(size_t)s0 * DD + lane];
    float t0 = qv * bf2f(a0.x);
#pragma unroll
    for (int off = 1; off <= 8; off <<= 1) t0 += __shfl_xor(t0, off);
    t0 *= SCL;
    float nm = fmaxf(m, t0);
    float c = __expf(m - nm), p = __expf(t0 - nm);
    l = l * c + p;
    acc = acc * c + p * bf2f(a0.y);
    m = nm;
  }
  float aggv = (end > beg) ? acc / l : 0.f;
  tmp[base + lane] = aggv + sk[base + lane];
}

// io = LN(io + in1 @ Wm + bias)   (8 rows/wave, weights amortized)
__global__ void k_matln(const float* __restrict__ in1,
                        const float* __restrict__ Wm, const float* __restrict__ bias,
                        const float* __restrict__ g, const float* __restrict__ bb,
                        float* __restrict__ io) {
  int lane = threadIdx.x & 63;
  int wid = __builtin_amdgcn_readfirstlane(threadIdx.x >> 6);
  int n0 = (blockIdx.x * 4 + wid) * RB;
  float acc[RB];
#pragma unroll
  for (int r = 0; r < RB; ++r) acc[r] = 0.f;
#pragma unroll 2
  for (int d = 0; d < DD; ++d) {
    float w = Wm[d * DD + lane];
#pragma unroll
    for (int r = 0; r < RB; ++r) acc[r] += in1[(size_t)(n0 + r) * DD + d] * w;
  }
  float bi_ = bias[lane], g_ = g[lane], bb_ = bb[lane];
#pragma unroll
  for (int r = 0; r < RB; ++r) {
    size_t o_idx = (size_t)(n0 + r) * DD + lane;
    float o = acc[r] + bi_ + io[o_idx];
    float s = o, s2 = o * o;
#pragma unroll
    for (int off = 32; off >= 1; off >>= 1) {
      s += __shfl_xor(s, off);
      s2 += __shfl_xor(s2, off);
    }
    float mean = s * (1.0f / 64.0f);
    float var = s2 * (1.0f / 64.0f) - mean * mean;
    io[o_idx] = (o - mean) * rsqrtf(var + EPSLN) * g_ + bb_;
  }
}

// K7: qt, kt, vt projections -> bf16   (8 rows/wave)
__global__ void k_qkvt(const float* __restrict__ xt,
                       const float* __restrict__ Wqt, const float* __restrict__ Wkt,
                       const float* __restrict__ Wvt,
                       const float* __restrict__ bqt, const float* __restrict__ bkt,
                       const float* __restrict__ bvt,
                       unsigned short* __restrict__ qt, unsigned short* __restrict__ kt,
                       unsigned short* __restrict__ vt) {
  int lane = threadIdx.x & 63;
  int wid = __builtin_amdgcn_readfirstlane(threadIdx.x >> 6);
  int n0 = (blockIdx.x * 4 + wid) * RB;
  float aq[RB], ak[RB], av[RB];
  float bq_ = bqt[lane], bk_ = bkt[lane], bv_ = bvt[lane];
#pragma unroll
  for (int r = 0; r < RB; ++r) { aq[r] = bq_; ak[r] = bk_; av[r] = bv_; }
#pragma unroll 2
  for (int d = 0; d < DD; ++d) {
    float wq = Wqt[d * DD + lane], wk = Wkt[d * DD + lane], wv = Wvt[d * DD + lane];
#pragma unroll
    for (int r = 0; r < RB; ++r) {
      float xd = xt[(size_t)(n0 + r) * DD + d];
      aq[r] += xd * wq; ak[r] += xd * wk; av[r] += xd * wv;
    }
  }
#pragma unroll
  for (int r = 0; r < RB; ++r) {
    size_t o = (size_t)(n0 + r) * DD + lane;
    qt[o] = f2bf(aq[r]); kt[o] = f2bf(ak[r]); vt[o] = f2bf(av[r]);
  }
}

// K8: temporal attention via MFMA, one block per (graph b, head hh).
// No-max softmax (scores bounded, mathematically identical to max-subtracted).
#define VST 20   // V LDS row stride (ushorts)
#define PST 40   // P LDS row stride (ushorts)
__global__ void __launch_bounds__(256)
k_tattn(const unsigned short* __restrict__ qtb, const unsigned short* __restrict__ ktb,
        const unsigned short* __restrict__ vtb, float* __restrict__ attn) {
  int b = blockIdx.x >> 2, hh = blockIdx.x & 3;
  __shared__ unsigned short Qs[NFRM][16];
  __shared__ unsigned short Ks[NFRM][16];
  __shared__ unsigned short Vs[NFRM][VST];
  __shared__ unsigned short Ps[4][16][PST];
  int t = threadIdx.x;
  int wv = t >> 6, lane = t & 63;
  int g = lane >> 4, c = lane & 15;
  {
    size_t src = ((size_t)b * NFRM + t) * DD + hh * 16;
    const uint4* qsrc = (const uint4*)(qtb + src);
    const uint4* ksrc = (const uint4*)(ktb + src);
    const uint2* vsrc = (const uint2*)(vtb + src);
    ((uint4*)Qs[t])[0] = qsrc[0]; ((uint4*)Qs[t])[1] = qsrc[1];
    ((uint4*)Ks[t])[0] = ksrc[0]; ((uint4*)Ks[t])[1] = ksrc[1];
    uint2* vdst = (uint2*)Vs[t];
    vdst[0] = vsrc[0]; vdst[1] = vsrc[1]; vdst[2] = vsrc[2]; vdst[3] = vsrc[3];
  }
  __syncthreads();
  const bf16x8 zf = {0, 0, 0, 0, 0, 0, 0, 0};
  unsigned short (*P)[PST] = Ps[wv];
  for (int qt0 = wv; qt0 < 16; qt0 += 4) {
    bf16x8 qf = zf;
    if (g < 2) qf = *(const bf16x8*)&Qs[qt0 * 16 + c][g * 8];
    f32x4 O = {0.f, 0.f, 0.f, 0.f};
    float lacc[4] = {0.f, 0.f, 0.f, 0.f};
    for (int jp = 0; jp < 8; ++jp) {
#pragma unroll
      for (int half = 0; half < 2; ++half) {
        int jt = jp * 2 + half;
        bf16x8 kf = zf;
        if (g < 2) kf = *(const bf16x8*)&Ks[jt * 16 + c][g * 8];
        f32x4 S = __builtin_amdgcn_mfma_f32_16x16x32_bf16(qf, kf,
                    (f32x4){0.f, 0.f, 0.f, 0.f}, 0, 0, 0);
#pragma unroll
        for (int r = 0; r < 4; ++r) {
          float p = __expf(S[r] * SCL);
          lacc[r] += p;
          P[4 * g + r][half * 16 + c] = f2bf(p);
        }
      }
      bf16x8 pf = *(const bf16x8*)&P[c][g * 8];
      bf16x8 vf;
#pragma unroll
      for (int i = 0; i < 8; ++i) vf[i] = (short)Vs[jp * 32 + g * 8 + i][c];
      O = __builtin_amdgcn_mfma_f32_16x16x32_bf16(pf, vf, O, 0, 0, 0);
    }
#pragma unroll
    for (int r = 0; r < 4; ++r) {
      float s = lacc[r];
      s += __shfl_xor(s, 1); s += __shfl_xor(s, 2);
      s += __shfl_xor(s, 4); s += __shfl_xor(s, 8);
      lacc[r] = 1.0f / s;
    }
    size_t obase = ((size_t)b * NFRM + qt0 * 16) * DD + hh * 16;
#pragma unroll
    for (int r = 0; r < 4; ++r)
      attn[obase + (size_t)(4 * g + r) * DD + c] = O[r] * lacc[r];
  }
}

// K10: u = relu(xt @ W1 + b1)   (8 rows/wave, 2 waves per 128-col row)
__global__ void k_ffn1(const float* __restrict__ xt, const float* __restrict__ W1,
                       const float* __restrict__ b1, float* __restrict__ u) {
  int lane = threadIdx.x & 63;
  int wid = __builtin_amdgcn_readfirstlane(threadIdx.x >> 6);
  int j = (wid & 1) * 64 + lane;
  int n0 = (blockIdx.x * 2 + (wid >> 1)) * RB;
  float acc[RB];
  float b_ = b1[j];
#pragma unroll
  for (int r = 0; r < RB; ++r) acc[r] = b_;
#pragma unroll 2
  for (int d = 0; d < DD; ++d) {
    float w = W1[d * 128 + j];
#pragma unroll
    for (int r = 0; r < RB; ++r) acc[r] += xt[(size_t)(n0 + r) * DD + d] * w;
  }
#pragma unroll
  for (int r = 0; r < RB; ++r) u[(size_t)(n0 + r) * 128 + j] = fmaxf(acc[r], 0.f);
}

// K11: xt = LN(xt + u @ W2 + b2)   (8 rows/wave)
__global__ void k_ffn2_ln(const float* __restrict__ u, const float* __restrict__ W2,
                          const float* __restrict__ b2, const float* __restrict__ g,
                          const float* __restrict__ bb, float* __restrict__ xt) {
  int lane = threadIdx.x & 63;
  int wid = __builtin_amdgcn_readfirstlane(threadIdx.x >> 6);
  int n0 = (blockIdx.x * 4 + wid) * RB;
  float acc[RB];
#pragma unroll
  for (int r = 0; r < RB; ++r) acc[r] = 0.f;
#pragma unroll 2
  for (int d = 0; d < 128; ++d) {
    float w = W2[d * DD + lane];
#pragma unroll
    for (int r = 0; r < RB; ++r) acc[r] += u[(size_t)(n0 + r) * 128 + d] * w;
  }
  float bi_ = b2[lane], g_ = g[lane], bb_ = bb[lane];
#pragma unroll
  for (int r = 0; r < RB; ++r) {
    size_t o_idx = (size_t)(n0 + r) * DD + lane;
    float o = acc[r] + bi_ + xt[o_idx];
    float s = o, s2 = o * o;
#pragma unroll
    for (int off = 32; off >= 1; off >>= 1) {
      s += __shfl_xor(s, off);
      s2 += __shfl_xor(s2, off);
    }
    float mean = s * (1.0f / 64.0f);
    float var = s2 * (1.0f / 64.0f) - mean * mean;
    xt[o_idx] = (o - mean) * rsqrtf(var + EPSLN) * g_ + bb_;
  }
}

// K12a: agg1 GEMM partials
__global__ void k_agg1a(const float* __restrict__ xt, const float* __restrict__ Wa1,
                        float* __restrict__ part) {
  __shared__ float ws_s[KROWS * DD];  // 32 KB
  int kc = blockIdx.x >> 3, bt = blockIdx.x & 7;
  int t = threadIdx.x, wid = t >> 6, lane = t & 63;
  const float* wsrc = Wa1 + (size_t)kc * KROWS * DD;
  for (int idx = t; idx < KROWS * DD; idx += 256) ws_s[idx] = wsrc[idx];
  __syncthreads();
  for (int bb_ = 0; bb_ < 8; ++bb_) {
    int b = bt * 32 + wid * 8 + bb_;
    const float* xr = xt + (size_t)b * (NFRM * DD) + kc * KROWS;
    float acc = 0.f;
#pragma unroll 8
    for (int i = 0; i < KROWS; ++i) acc += xr[i] * ws_s[i * DD + lane];
    part[(size_t)kc * (BSZ * DD) + (size_t)b * DD + lane] = acc;
  }
}

// K12b: reduce partials
__global__ void k_agg1red(const float* __restrict__ part, float* __restrict__ a1) {
  int g = blockIdx.x * 256 + threadIdx.x;
  float s = 0.f;
#pragma unroll 8
  for (int kc = 0; kc < KSP; ++kc) s += part[(size_t)kc * (BSZ * DD) + g];
  a1[g] = s;
}

// K13: head MLP
__global__ void k_head(const float* __restrict__ a1, const float* __restrict__ ba1,
                       const float* __restrict__ Wa2, const float* __restrict__ ba2,
                       const float* __restrict__ Wh1, const float* __restrict__ bh1,
                       const float* __restrict__ Wh2, const float* __restrict__ bh2,
                       float* __restrict__ out) {
  int b = blockIdx.x, t = threadIdx.x;
  __shared__ float s1[64], s2[32], s3[16];
  s1[t] = fmaxf(a1[b * DD + t] + ba1[t], 0.f);
  __syncthreads();
  if (t < 32) {
    float a = ba2[t];
#pragma unroll 8
    for (int j = 0; j < 64; ++j) a += s1[j] * Wa2[j * 32 + t];
    s2[t] = fmaxf(a, 0.f);
  }
  __syncthreads();
  if (t < 16) {
    float a = bh1[t];
#pragma unroll
    for (int j = 0; j < 32; ++j) a += s2[j] * Wh1[j * 16 + t];
    s3[t] = fmaxf(a, 0.f);
  }
  __syncthreads();
  if (t == 0) {
    float a = bh2[0];
#pragma unroll
    for (int j = 0; j < 16; ++j) a += s3[j] * Wh2[j];
    out[b] = 1.0f / (1.0f + expf(-a));
  }
}

extern "C" void kernel_launch(void* const* d_in, const int* in_sizes, int n_in,
                              void* d_out, int out_size, void* d_ws, size_t ws_size,
                              hipStream_t stream) {
  const float* x   = (const float*)d_in[0];
  const int*   ei  = (const int*)d_in[1];
  const float* Wi  = (const float*)d_in[2];
  const float* bi  = (const float*)d_in[3];
  const float* pe  = (const float*)d_in[4];
  const float* Wq  = (const float*)d_in[5];
  const float* Wk  = (const float*)d_in[6];
  const float* Wv  = (const float*)d_in[7];
  const float* bq  = (const float*)d_in[8];
  const float* bk  = (const float*)d_in[9];
  const float* bv  = (const float*)d_in[10];
  const float* Ws  = (const float*)d_in[11];
  const float* bs  = (const float*)d_in[12];
  const float* Wo  = (const float*)d_in[13];
  const float* bo  = (const float*)d_in[14];
  const float* gg  = (const float*)d_in[15];
  const float* gb  = (const float*)d_in[16];
  const float* Wqt = (const float*)d_in[17];
  const float* Wkt = (const float*)d_in[18];
  const float* Wvt = (const float*)d_in[19];
  const float* bqt = (const float*)d_in[20];
  const float* bkt = (const float*)d_in[21];
  const float* bvt = (const float*)d_in[22];
  const float* Wot = (const float*)d_in[23];
  const float* bot = (const float*)d_in[24];
  const float* l1g = (const float*)d_in[25];
  const float* l1b = (const float*)d_in[26];
  const float* W1  = (const float*)d_in[27];
  const float* b1  = (const float*)d_in[28];
  const float* W2  = (const float*)d_in[29];
  const float* b2  = (const float*)d_in[30];
  const float* l2g = (const float*)d_in[31];
  const float* l2b = (const float*)d_in[32];
  const float* Wa1 = (const float*)d_in[33];
  const float* ba1 = (const float*)d_in[34];
  const float* Wa2 = (const float*)d_in[35];
  const float* ba2 = (const float*)d_in[36];
  const float* Wh1 = (const float*)d_in[37];
  const float* bh1 = (const float*)d_in[38];
  const float* Wh2 = (const float*)d_in[39];
  const float* bh2 = (const float*)d_in[40];
  float* out = (float*)d_out;

  const size_t ND = (size_t)NN * DD;   // 4,194,304

  float* wsf    = (float*)d_ws;
  float* f_h    = wsf;                 // h / xt
  float* f_q    = f_h  + ND;           // q  -> qt/kt (bf16)
  float* f_k    = f_q  + ND;           // kv (bf16 packed) -> vt (bf16)
  float* f_v    = f_k  + ND;           // (spare)
  float* f_sk   = f_v  + ND;           // skip -> attn
  float* f_u    = f_sk + ND;           // gattn tmp, then ffn hidden [N,128]
  float* f_part = f_u  + 2 * ND;       // agg1 partials [KSP][BSZ][DD] = 8 MB
  float* f_a1   = f_part + (size_t)KSP * BSZ * DD;
  int* i_srcs   = (int*)(f_a1 + BSZ * DD);  // CSR src list [NE]
  int* i_rowptr = i_srcs + NE;              // [NN+1]
  int* i_cursor = i_rowptr + NN + 1;        // [NN]
  int* i_cnt    = i_cursor + NN;            // [NN]
  int* i_bsum   = i_cnt + NN;               // [256]
  int* i_boff   = i_bsum + 256;             // [256]

  ushort2* f_kv = (ushort2*)f_k;
  float* f_tmp  = f_u;                 // gattn output (free until ffn1)
  unsigned short* us_qt = (unsigned short*)f_q;        // [N][64] bf16
  unsigned short* us_kt = us_qt + ND;                  // [N][64] bf16
  unsigned short* us_vt = (unsigned short*)f_k;        // [N][64] bf16

  hipMemsetAsync(i_cnt, 0, NN * sizeof(int), stream);

  dim3 B(256);
  // 1. input proj + PE
  k_input<<<dim3(NN / (4 * RB)), B, 0, stream>>>(x, Wi, bi, pe, f_h);
  // 2. q, kv(bf16), skip
  k_qkvs<<<dim3(NN / (4 * RB)), B, 0, stream>>>(f_h, Wq, Wk, Wv, Ws, bq, bk, bv, bs,
                                                f_q, f_kv, f_sk);
  // 3. CSR build
  k_count<<<dim3(NE / 256), B, 0, stream>>>(ei, i_cnt);
  k_scan1<<<dim3(NN / 256), B, 0, stream>>>(i_cnt, i_rowptr, i_bsum);
  k_scan2<<<dim3(1), B, 0, stream>>>(i_bsum, i_boff);
  k_scan3<<<dim3(NN / 256), B, 0, stream>>>(i_rowptr, i_boff, i_cursor);
  k_scatter<<<dim3(NE / 256), B, 0, stream>>>(ei, i_cursor, i_srcs);
  // 4. graph attention + skip -> f_tmp; then Wo matmul + residual LN -> f_h
  k_gattn<<<dim3(NN / 4), B, 0, stream>>>(f_q, f_kv, i_rowptr, i_srcs, f_sk, f_tmp);
  k_matln<<<dim3(NN / (4 * RB)), B, 0, stream>>>(f_tmp, Wo, bo, gg, gb, f_h);
  // 5. temporal q,k,v (bf16)
  k_qkvt<<<dim3(NN / (4 * RB)), B, 0, stream>>>(f_h, Wqt, Wkt, Wvt, bqt, bkt, bvt,
                                                us_qt, us_kt, us_vt);
  // 6. temporal attention (MFMA) -> f_sk
  k_tattn<<<dim3(BSZ * HH), B, 0, stream>>>(us_qt, us_kt, us_vt, f_sk);
  // 7. attn@Wot + bot, residual + LN1 -> f_h
  k_matln<<<dim3(NN / (4 * RB)), B, 0, stream>>>(f_sk, Wot, bot, l1g, l1b, f_h);
  // 8-9. FFN + LN2
  k_ffn1<<<dim3(NN / (2 * RB)), B, 0, stream>>>(f_h, W1, b1, f_u);
  k_ffn2_ln<<<dim3(NN / (4 * RB)), B, 0, stream>>>(f_u, W2, b2, l2g, l2b, f_h);
  // 10. aggregation GEMM
  k_agg1a<<<dim3(KSP * 8), B, 0, stream>>>(f_h, Wa1, f_part);
  k_agg1red<<<dim3(BSZ * DD / 256), B, 0, stream>>>(f_part, f_a1);
  // 11. head MLP
  k_head<<<dim3(BSZ), dim3(64), 0, stream>>>(f_a1, ba1, Wa2, ba2, Wh1, bh1, Wh2, bh2, out);
}

// Round 6
// 379.240 us; speedup vs baseline: 3.0779x; 1.4506x over previous
//
#include <hip/hip_runtime.h>
#include <math.h>

#define NN 65536
#define SIN 24
#define DD 64
#define HH 4
#define HDIM 16
#define NFRM 256
#define NE 1048576
#define BSZ 256
#define EPSLN 1e-5f
#define SCL 0.25f
#define RB 8

#define KSP 128
#define KROWS 128

typedef __attribute__((ext_vector_type(8))) short bf16x8;
typedef __attribute__((ext_vector_type(4))) float f32x4;

__device__ __forceinline__ unsigned short f2bf(float f) {
  unsigned u = __float_as_uint(f);
  return (unsigned short)((u + 0x7FFFu + ((u >> 16) & 1u)) >> 16);
}
__device__ __forceinline__ float bf2f(unsigned short b) {
  return __uint_as_float(((unsigned)b) << 16);
}

// stage fp32 [rows][DK] -> bf16 LDS [rows][ST]
__device__ __forceinline__ void stage_f32(const float* __restrict__ src,
                                          unsigned short* dst, int n4, int DK, int ST, int tid) {
  int dk4 = DK >> 2;
  for (int idx = tid; idx < n4; idx += 256) {
    int row = idx / dk4, c = (idx % dk4) * 4;
    float4 v = *(const float4*)(src + (size_t)row * DK + c);
    uint2 p;
    p.x = (unsigned)f2bf(v.x) | ((unsigned)f2bf(v.y) << 16);
    p.y = (unsigned)f2bf(v.z) | ((unsigned)f2bf(v.w) << 16);
    *(uint2*)(dst + row * ST + c) = p;
  }
}

// stage bf16 [rows][DK] -> LDS [rows][ST]
__device__ __forceinline__ void stage_bf(const unsigned short* __restrict__ src,
                                         unsigned short* dst, int n8, int DK, int ST, int tid) {
  int dk8 = DK >> 3;
  for (int idx = tid; idx < n8; idx += 256) {
    int row = idx / dk8, c = (idx % dk8) * 8;
    *(uint4*)(dst + row * ST + c) = *(const uint4*)(src + (size_t)row * DK + c);
  }
}

// K1: h = x @ Wi + bi + pe[n % NF]
__global__ void k_input(const float* __restrict__ x, const float* __restrict__ Wi,
                        const float* __restrict__ bi, const float* __restrict__ pe,
                        float* __restrict__ h) {
  int lane = threadIdx.x & 63;
  int wid = __builtin_amdgcn_readfirstlane(threadIdx.x >> 6);
  int n0 = (blockIdx.x * 4 + wid) * RB;
  float b = bi[lane];
  float acc[RB];
#pragma unroll
  for (int r = 0; r < RB; ++r) acc[r] = b + pe[((n0 + r) & (NFRM - 1)) * DD + lane];
  for (int s = 0; s < SIN; ++s) {
    float w = Wi[s * DD + lane];
#pragma unroll
    for (int r = 0; r < RB; ++r) acc[r] += x[(size_t)(n0 + r) * SIN + s] * w;
  }
#pragma unroll
  for (int r = 0; r < RB; ++r) h[(size_t)(n0 + r) * DD + lane] = acc[r];
}

// Weight prep: transpose all dense weights to bf16 Wt[Nout][Dk]
// segments (ushort offsets): 0 o | 4096 ot | 8192 qt | 12288 kt | 16384 vt |
// 20480 W1t[128][64] | 28672 W2t[64][128] | 36864 sq | 40960 sk | 45056 sv | 49152 ss
__global__ void k_wprep(const float* __restrict__ Wo, const float* __restrict__ Wot,
                        const float* __restrict__ Wqt, const float* __restrict__ Wkt,
                        const float* __restrict__ Wvt, const float* __restrict__ W1,
                        const float* __restrict__ W2, const float* __restrict__ Wq,
                        const float* __restrict__ Wk, const float* __restrict__ Wv,
                        const float* __restrict__ Wsk, unsigned short* __restrict__ wt) {
  int i = blockIdx.x * 256 + threadIdx.x;
  if (i >= 53248) return;
  float v;
  if (i < 4096)       { int t = i;         int j = t >> 6, d = t & 63; v = Wo[d * 64 + j]; }
  else if (i < 8192)  { int t = i - 4096;  int j = t >> 6, d = t & 63; v = Wot[d * 64 + j]; }
  else if (i < 12288) { int t = i - 8192;  int j = t >> 6, d = t & 63; v = Wqt[d * 64 + j]; }
  else if (i < 16384) { int t = i - 12288; int j = t >> 6, d = t & 63; v = Wkt[d * 64 + j]; }
  else if (i < 20480) { int t = i - 16384; int j = t >> 6, d = t & 63; v = Wvt[d * 64 + j]; }
  else if (i < 28672) { int t = i - 20480; int j = t >> 6, d = t & 63; v = W1[d * 128 + j]; }
  else if (i < 36864) { int t = i - 28672; int j = t >> 7, d = t & 127; v = W2[d * 64 + j]; }
  else if (i < 40960) { int t = i - 36864; int j = t >> 6, d = t & 63; v = Wq[(j >> 4) * 1024 + d * 16 + (j & 15)]; }
  else if (i < 45056) { int t = i - 40960; int j = t >> 6, d = t & 63; v = Wk[(j >> 4) * 1024 + d * 16 + (j & 15)]; }
  else if (i < 49152) { int t = i - 45056; int j = t >> 6, d = t & 63; v = Wv[(j >> 4) * 1024 + d * 16 + (j & 15)]; }
  else                { int t = i - 49152; int j = t >> 6, d = t & 63; v = Wsk[(j >> 4) * 1024 + d * 16 + (j & 15)]; }
  wt[i] = f2bf(v);
}

// K2 (MFMA): q fp32, kv packed bf16, sk fp32
__global__ void __launch_bounds__(256)
k_qkvs_m(const float* __restrict__ h, const unsigned short* __restrict__ wt,
         const float* __restrict__ bq, const float* __restrict__ bk,
         const float* __restrict__ bv, const float* __restrict__ bs,
         float* __restrict__ q, ushort2* __restrict__ kv, float* __restrict__ sk) {
  __shared__ unsigned short Xs[64 * 72];
  __shared__ unsigned short Ws4[4 * 64 * 72];
  int tid = threadIdx.x;
  int n0 = blockIdx.x * 64;
  stage_f32(h + (size_t)n0 * 64, Xs, 64 * 16, 64, 72, tid);
  stage_bf(wt + 36864, Ws4, 64 * 8, 64, 72, tid);                 // q
  stage_bf(wt + 40960, Ws4 + 4608, 64 * 8, 64, 72, tid);          // k
  stage_bf(wt + 45056, Ws4 + 9216, 64 * 8, 64, 72, tid);          // v
  stage_bf(wt + 49152, Ws4 + 13824, 64 * 8, 64, 72, tid);         // s
  __syncthreads();
  int lane = tid & 63, w = tid >> 6;
  int c = lane & 15, g = lane >> 4;
  f32x4 aq[4], ak[4], av[4], as_[4];
#pragma unroll
  for (int j = 0; j < 4; ++j) {
#pragma unroll
    for (int r = 0; r < 4; ++r) { aq[j][r] = 0.f; ak[j][r] = 0.f; av[j][r] = 0.f; as_[j][r] = 0.f; }
  }
  const unsigned short* xrow = Xs + (w * 16 + c) * 72 + g * 8;
#pragma unroll
  for (int kk = 0; kk < 2; ++kk) {
    bf16x8 af = *(const bf16x8*)(xrow + kk * 32);
#pragma unroll
    for (int j = 0; j < 4; ++j) {
      int boff = (j * 16 + c) * 72 + kk * 32 + g * 8;
      aq[j] = __builtin_amdgcn_mfma_f32_16x16x32_bf16(af, *(const bf16x8*)(Ws4 + boff), aq[j], 0, 0, 0);
      ak[j] = __builtin_amdgcn_mfma_f32_16x16x32_bf16(af, *(const bf16x8*)(Ws4 + 4608 + boff), ak[j], 0, 0, 0);
      av[j] = __builtin_amdgcn_mfma_f32_16x16x32_bf16(af, *(const bf16x8*)(Ws4 + 9216 + boff), av[j], 0, 0, 0);
      as_[j] = __builtin_amdgcn_mfma_f32_16x16x32_bf16(af, *(const bf16x8*)(Ws4 + 13824 + boff), as_[j], 0, 0, 0);
    }
  }
  int rowb = n0 + w * 16 + 4 * g;
#pragma unroll
  for (int j = 0; j < 4; ++j) {
    int col = j * 16 + c;
    float bqj = bq[col], bkj = bk[col], bvj = bv[col], bsj = bs[col];
#pragma unroll
    for (int r = 0; r < 4; ++r) {
      size_t o = (size_t)(rowb + r) * 64 + col;
      q[o] = aq[j][r] + bqj;
      kv[o] = make_ushort2(f2bf(ak[j][r] + bkj), f2bf(av[j][r] + bvj));
      sk[o] = as_[j][r] + bsj;
    }
  }
}

// ---- CSR build ----
__global__ void k_count(const int* __restrict__ ei, int* __restrict__ cnt) {
  int e = blockIdx.x * 256 + threadIdx.x;
  atomicAdd(&cnt[ei[NE + e]], 1);
}

__global__ void k_scan1(const int* __restrict__ cnt, int* __restrict__ rowptr,
                        int* __restrict__ bsum) {
  __shared__ int s[256];
  int t = threadIdx.x, base = blockIdx.x << 8;
  int v = cnt[base + t];
  s[t] = v; __syncthreads();
  for (int off = 1; off < 256; off <<= 1) {
    int x = (t >= off) ? s[t - off] : 0;
    __syncthreads();
    s[t] += x;
    __syncthreads();
  }
  rowptr[base + t] = s[t] - v;
  if (t == 255) bsum[blockIdx.x] = s[255];
}

__global__ void k_scan2(const int* __restrict__ bsum, int* __restrict__ boff) {
  __shared__ int s[256];
  int t = threadIdx.x;
  int v = bsum[t];
  s[t] = v; __syncthreads();
  for (int off = 1; off < 256; off <<= 1) {
    int x = (t >= off) ? s[t - off] : 0;
    __syncthreads();
    s[t] += x;
    __syncthreads();
  }
  boff[t] = s[t] - v;
}

__global__ void k_scan3(int* __restrict__ rowptr, const int* __restrict__ boff,
                        int* __restrict__ cursor) {
  int g = blockIdx.x * 256 + threadIdx.x;
  int r = rowptr[g] + boff[g >> 8];
  rowptr[g] = r; cursor[g] = r;
  if (g == 0) rowptr[NN] = NE;
}

__global__ void k_scatter(const int* __restrict__ ei, int* __restrict__ cursor,
                          int* __restrict__ srcs) {
  int e = blockIdx.x * 256 + threadIdx.x;
  int dst = ei[NE + e];
  int pos = atomicAdd(&cursor[dst], 1);
  srcs[pos] = ei[e];
}

// Graph attention + skip -> tmp
__global__ void k_gattn(const float* __restrict__ q, const ushort2* __restrict__ kv,
                        const int* __restrict__ rowptr,
                        const int* __restrict__ srcs, const float* __restrict__ sk,
                        float* __restrict__ tmp) {
  int wid = threadIdx.x >> 6, lane = threadIdx.x & 63;
  int dst = (blockIdx.x << 2) + wid;
  size_t base = (size_t)dst * DD;
  float qv = q[base + lane];
  int beg = rowptr[dst], end = rowptr[dst + 1];
  float m = -INFINITY, l = 0.f, acc = 0.f;
  int idx = beg;
  for (; idx + 4 <= end; idx += 4) {
    int s0 = srcs[idx], s1 = srcs[idx + 1], s2 = srcs[idx + 2], s3 = srcs[idx + 3];
    ushort2 a0 = kv[(size_t)s0 * DD + lane];
    ushort2 a1 = kv[(size_t)s1 * DD + lane];
    ushort2 a2 = kv[(size_t)s2 * DD + lane];
    ushort2 a3 = kv[(size_t)s3 * DD + lane];
    float t0 = qv * bf2f(a0.x), t1 = qv * bf2f(a1.x);
    float t2 = qv * bf2f(a2.x), t3 = qv * bf2f(a3.x);
#pragma unroll
    for (int off = 1; off <= 8; off <<= 1) {
      t0 += __shfl_xor(t0, off);
      t1 += __shfl_xor(t1, off);
      t2 += __shfl_xor(t2, off);
      t3 += __shfl_xor(t3, off);
    }
    t0 *= SCL; t1 *= SCL; t2 *= SCL; t3 *= SCL;
    float nm = fmaxf(fmaxf(m, fmaxf(t0, t1)), fmaxf(t2, t3));
    float cc = __expf(m - nm);
    float p0 = __expf(t0 - nm), p1 = __expf(t1 - nm);
    float p2 = __expf(t2 - nm), p3 = __expf(t3 - nm);
    l = l * cc + ((p0 + p1) + (p2 + p3));
    acc = acc * cc + ((p0 * bf2f(a0.y) + p1 * bf2f(a1.y)) +
                      (p2 * bf2f(a2.y) + p3 * bf2f(a3.y)));
    m = nm;
  }
  for (; idx < end; ++idx) {
    int s0 = srcs[idx];
    ushort2 a0 = kv[(size_t)s0 * DD + lane];
    float t0 = qv * bf2f(a0.x);
#pragma unroll
    for (int off = 1; off <= 8; off <<= 1) t0 += __shfl_xor(t0, off);
    t0 *= SCL;
    float nm = fmaxf(m, t0);
    float cc = __expf(m - nm), p = __expf(t0 - nm);
    l = l * cc + p;
    acc = acc * cc + p * bf2f(a0.y);
    m = nm;
  }
  float aggv = (end > beg) ? acc / l : 0.f;
  tmp[base + lane] = aggv + sk[base + lane];
}

// MFMA: io = LN(io + in1 @ W + bias)
__global__ void __launch_bounds__(256)
k_matln_m(const float* __restrict__ in1, const unsigned short* __restrict__ Wt,
          const float* __restrict__ bias, const float* __restrict__ gam,
          const float* __restrict__ bet, float* __restrict__ io) {
  __shared__ unsigned short Xs[64 * 72];
  __shared__ unsigned short Ws[64 * 72];
  int tid = threadIdx.x;
  int n0 = blockIdx.x * 64;
  stage_f32(in1 + (size_t)n0 * 64, Xs, 64 * 16, 64, 72, tid);
  stage_bf(Wt, Ws, 64 * 8, 64, 72, tid);
  __syncthreads();
  int lane = tid & 63, w = tid >> 6;
  int c = lane & 15, g = lane >> 4;
  f32x4 acc[4];
#pragma unroll
  for (int j = 0; j < 4; ++j) { acc[j][0] = 0.f; acc[j][1] = 0.f; acc[j][2] = 0.f; acc[j][3] = 0.f; }
  const unsigned short* xrow = Xs + (w * 16 + c) * 72 + g * 8;
#pragma unroll
  for (int kk = 0; kk < 2; ++kk) {
    bf16x8 af = *(const bf16x8*)(xrow + kk * 32);
#pragma unroll
    for (int j = 0; j < 4; ++j)
      acc[j] = __builtin_amdgcn_mfma_f32_16x16x32_bf16(af,
                 *(const bf16x8*)(Ws + (j * 16 + c) * 72 + kk * 32 + g * 8), acc[j], 0, 0, 0);
  }
  int rowb = n0 + w * 16 + 4 * g;
  float o[4][4], gj[4], bj[4];
#pragma unroll
  for (int j = 0; j < 4; ++j) {
    int col = j * 16 + c;
    float bb = bias[col];
    gj[j] = gam[col]; bj[j] = bet[col];
#pragma unroll
    for (int r = 0; r < 4; ++r)
      o[j][r] = acc[j][r] + bb + io[(size_t)(rowb + r) * 64 + col];
  }
#pragma unroll
  for (int r = 0; r < 4; ++r) {
    float s = (o[0][r] + o[1][r]) + (o[2][r] + o[3][r]);
    float s2 = (o[0][r] * o[0][r] + o[1][r] * o[1][r]) + (o[2][r] * o[2][r] + o[3][r] * o[3][r]);
#pragma unroll
    for (int off = 1; off <= 8; off <<= 1) {
      s += __shfl_xor(s, off);
      s2 += __shfl_xor(s2, off);
    }
    float mean = s * (1.0f / 64.0f);
    float var = s2 * (1.0f / 64.0f) - mean * mean;
    float rs = rsqrtf(var + EPSLN);
#pragma unroll
    for (int j = 0; j < 4; ++j)
      io[(size_t)(rowb + r) * 64 + j * 16 + c] = (o[j][r] - mean) * rs * gj[j] + bj[j];
  }
}

// MFMA: qt,kt,vt (bf16 out)
__global__ void __launch_bounds__(256)
k_qkvt_m(const float* __restrict__ xt, const unsigned short* __restrict__ wt,
         const float* __restrict__ bqt, const float* __restrict__ bkt,
         const float* __restrict__ bvt,
         unsigned short* __restrict__ qt, unsigned short* __restrict__ kt,
         unsigned short* __restrict__ vt) {
  __shared__ unsigned short Xs[64 * 72];
  __shared__ unsigned short Ws3[3 * 64 * 72];
  int tid = threadIdx.x;
  int n0 = blockIdx.x * 64;
  stage_f32(xt + (size_t)n0 * 64, Xs, 64 * 16, 64, 72, tid);
  stage_bf(wt + 8192, Ws3, 64 * 8, 64, 72, tid);
  stage_bf(wt + 12288, Ws3 + 4608, 64 * 8, 64, 72, tid);
  stage_bf(wt + 16384, Ws3 + 9216, 64 * 8, 64, 72, tid);
  __syncthreads();
  int lane = tid & 63, w = tid >> 6;
  int c = lane & 15, g = lane >> 4;
  f32x4 aq[4], ak[4], av[4];
#pragma unroll
  for (int j = 0; j < 4; ++j) {
#pragma unroll
    for (int r = 0; r < 4; ++r) { aq[j][r] = 0.f; ak[j][r] = 0.f; av[j][r] = 0.f; }
  }
  const unsigned short* xrow = Xs + (w * 16 + c) * 72 + g * 8;
#pragma unroll
  for (int kk = 0; kk < 2; ++kk) {
    bf16x8 af = *(const bf16x8*)(xrow + kk * 32);
#pragma unroll
    for (int j = 0; j < 4; ++j) {
      int boff = (j * 16 + c) * 72 + kk * 32 + g * 8;
      aq[j] = __builtin_amdgcn_mfma_f32_16x16x32_bf16(af, *(const bf16x8*)(Ws3 + boff), aq[j], 0, 0, 0);
      ak[j] = __builtin_amdgcn_mfma_f32_16x16x32_bf16(af, *(const bf16x8*)(Ws3 + 4608 + boff), ak[j], 0, 0, 0);
      av[j] = __builtin_amdgcn_mfma_f32_16x16x32_bf16(af, *(const bf16x8*)(Ws3 + 9216 + boff), av[j], 0, 0, 0);
    }
  }
  int rowb = n0 + w * 16 + 4 * g;
#pragma unroll
  for (int j = 0; j < 4; ++j) {
    int col = j * 16 + c;
    float bqj = bqt[col], bkj = bkt[col], bvj = bvt[col];
#pragma unroll
    for (int r = 0; r < 4; ++r) {
      size_t o = (size_t)(rowb + r) * 64 + col;
      qt[o] = f2bf(aq[j][r] + bqj);
      kt[o] = f2bf(ak[j][r] + bkj);
      vt[o] = f2bf(av[j][r] + bvj);
    }
  }
}

// K8: temporal attention via MFMA (unchanged)
#define VST 20
#define PST 40
__global__ void __launch_bounds__(256)
k_tattn(const unsigned short* __restrict__ qtb, const unsigned short* __restrict__ ktb,
        const unsigned short* __restrict__ vtb, float* __restrict__ attn) {
  int b = blockIdx.x >> 2, hh = blockIdx.x & 3;
  __shared__ unsigned short Qs[NFRM][16];
  __shared__ unsigned short Ks[NFRM][16];
  __shared__ unsigned short Vs[NFRM][VST];
  __shared__ unsigned short Ps[4][16][PST];
  int t = threadIdx.x;
  int wv = t >> 6, lane = t & 63;
  int g = lane >> 4, c = lane & 15;
  {
    size_t src = ((size_t)b * NFRM + t) * DD + hh * 16;
    const uint4* qsrc = (const uint4*)(qtb + src);
    const uint4* ksrc = (const uint4*)(ktb + src);
    const uint2* vsrc = (const uint2*)(vtb + src);
    ((uint4*)Qs[t])[0] = qsrc[0]; ((uint4*)Qs[t])[1] = qsrc[1];
    ((uint4*)Ks[t])[0] = ksrc[0]; ((uint4*)Ks[t])[1] = ksrc[1];
    uint2* vdst = (uint2*)Vs[t];
    vdst[0] = vsrc[0]; vdst[1] = vsrc[1]; vdst[2] = vsrc[2]; vdst[3] = vsrc[3];
  }
  __syncthreads();
  const bf16x8 zf = {0, 0, 0, 0, 0, 0, 0, 0};
  unsigned short (*P)[PST] = Ps[wv];
  for (int qt0 = wv; qt0 < 16; qt0 += 4) {
    bf16x8 qf = zf;
    if (g < 2) qf = *(const bf16x8*)&Qs[qt0 * 16 + c][g * 8];
    f32x4 O = {0.f, 0.f, 0.f, 0.f};
    float lacc[4] = {0.f, 0.f, 0.f, 0.f};
    for (int jp = 0; jp < 8; ++jp) {
#pragma unroll
      for (int half = 0; half < 2; ++half) {
        int jt = jp * 2 + half;
        bf16x8 kf = zf;
        if (g < 2) kf = *(const bf16x8*)&Ks[jt * 16 + c][g * 8];
        f32x4 S = __builtin_amdgcn_mfma_f32_16x16x32_bf16(qf, kf,
                    (f32x4){0.f, 0.f, 0.f, 0.f}, 0, 0, 0);
#pragma unroll
        for (int r = 0; r < 4; ++r) {
          float p = __expf(S[r] * SCL);
          lacc[r] += p;
          P[4 * g + r][half * 16 + c] = f2bf(p);
        }
      }
      bf16x8 pf = *(const bf16x8*)&P[c][g * 8];
      bf16x8 vf;
#pragma unroll
      for (int i = 0; i < 8; ++i) vf[i] = (short)Vs[jp * 32 + g * 8 + i][c];
      O = __builtin_amdgcn_mfma_f32_16x16x32_bf16(pf, vf, O, 0, 0, 0);
    }
#pragma unroll
    for (int r = 0; r < 4; ++r) {
      float s = lacc[r];
      s += __shfl_xor(s, 1); s += __shfl_xor(s, 2);
      s += __shfl_xor(s, 4); s += __shfl_xor(s, 8);
      lacc[r] = 1.0f / s;
    }
    size_t obase = ((size_t)b * NFRM + qt0 * 16) * DD + hh * 16;
#pragma unroll
    for (int r = 0; r < 4; ++r)
      attn[obase + (size_t)(4 * g + r) * DD + c] = O[r] * lacc[r];
  }
}

// MFMA: u = relu(xt @ W1 + b1), bf16 out [N][128]
__global__ void __launch_bounds__(256)
k_ffn1_m(const float* __restrict__ xt, const unsigned short* __restrict__ wt,
         const float* __restrict__ b1, unsigned short* __restrict__ u) {
  __shared__ unsigned short Xs[64 * 72];
  __shared__ unsigned short Ws[128 * 72];
  int tid = threadIdx.x;
  int n0 = blockIdx.x * 64;
  stage_f32(xt + (size_t)n0 * 64, Xs, 64 * 16, 64, 72, tid);
  stage_bf(wt + 20480, Ws, 128 * 8, 64, 72, tid);
  __syncthreads();
  int lane = tid & 63, w = tid >> 6;
  int c = lane & 15, g = lane >> 4;
  f32x4 acc[8];
#pragma unroll
  for (int j = 0; j < 8; ++j) { acc[j][0] = 0.f; acc[j][1] = 0.f; acc[j][2] = 0.f; acc[j][3] = 0.f; }
  const unsigned short* xrow = Xs + (w * 16 + c) * 72 + g * 8;
#pragma unroll
  for (int kk = 0; kk < 2; ++kk) {
    bf16x8 af = *(const bf16x8*)(xrow + kk * 32);
#pragma unroll
    for (int j = 0; j < 8; ++j)
      acc[j] = __builtin_amdgcn_mfma_f32_16x16x32_bf16(af,
                 *(const bf16x8*)(Ws + (j * 16 + c) * 72 + kk * 32 + g * 8), acc[j], 0, 0, 0);
  }
  int rowb = n0 + w * 16 + 4 * g;
#pragma unroll
  for (int j = 0; j < 8; ++j) {
    int col = j * 16 + c;
    float bb = b1[col];
#pragma unroll
    for (int r = 0; r < 4; ++r)
      u[(size_t)(rowb + r) * 128 + col] = f2bf(fmaxf(acc[j][r] + bb, 0.f));
  }
}

// MFMA: xt = LN(xt + u @ W2 + b2)
__global__ void __launch_bounds__(256)
k_ffn2_m(const unsigned short* __restrict__ u, const unsigned short* __restrict__ wt,
         const float* __restrict__ b2, const float* __restrict__ gam,
         const float* __restrict__ bet, float* __restrict__ xt) {
  __shared__ unsigned short Xs[64 * 136];
  __shared__ unsigned short Ws[64 * 136];
  int tid = threadIdx.x;
  int n0 = blockIdx.x * 64;
  stage_bf(u + (size_t)n0 * 128, Xs, 64 * 16, 128, 136, tid);
  stage_bf(wt + 28672, Ws, 64 * 16, 128, 136, tid);
  __syncthreads();
  int lane = tid & 63, w = tid >> 6;
  int c = lane & 15, g = lane >> 4;
  f32x4 acc[4];
#pragma unroll
  for (int j = 0; j < 4; ++j) { acc[j][0] = 0.f; acc[j][1] = 0.f; acc[j][2] = 0.f; acc[j][3] = 0.f; }
  const unsigned short* xrow = Xs + (w * 16 + c) * 136 + g * 8;
#pragma unroll
  for (int kk = 0; kk < 4; ++kk) {
    bf16x8 af = *(const bf16x8*)(xrow + kk * 32);
#pragma unroll
    for (int j = 0; j < 4; ++j)
      acc[j] = __builtin_amdgcn_mfma_f32_16x16x32_bf16(af,
                 *(const bf16x8*)(Ws + (j * 16 + c) * 136 + kk * 32 + g * 8), acc[j], 0, 0, 0);
  }
  int rowb = n0 + w * 16 + 4 * g;
  float o[4][4], gj[4], bj[4];
#pragma unroll
  for (int j = 0; j < 4; ++j) {
    int col = j * 16 + c;
    float bb = b2[col];
    gj[j] = gam[col]; bj[j] = bet[col];
#pragma unroll
    for (int r = 0; r < 4; ++r)
      o[j][r] = acc[j][r] + bb + xt[(size_t)(rowb + r) * 64 + col];
  }
#pragma unroll
  for (int r = 0; r < 4; ++r) {
    float s = (o[0][r] + o[1][r]) + (o[2][r] + o[3][r]);
    float s2 = (o[0][r] * o[0][r] + o[1][r] * o[1][r]) + (o[2][r] * o[2][r] + o[3][r] * o[3][r]);
#pragma unroll
    for (int off = 1; off <= 8; off <<= 1) {
      s += __shfl_xor(s, off);
      s2 += __shfl_xor(s2, off);
    }
    float mean = s * (1.0f / 64.0f);
    float var = s2 * (1.0f / 64.0f) - mean * mean;
    float rs = rsqrtf(var + EPSLN);
#pragma unroll
    for (int j = 0; j < 4; ++j)
      xt[(size_t)(rowb + r) * 64 + j * 16 + c] = (o[j][r] - mean) * rs * gj[j] + bj[j];
  }
}

// K12a: agg1 GEMM partials
__global__ void k_agg1a(const float* __restrict__ xt, const float* __restrict__ Wa1,
                        float* __restrict__ part) {
  __shared__ float ws_s[KROWS * DD];
  int kc = blockIdx.x >> 3, bt = blockIdx.x & 7;
  int t = threadIdx.x, wid = t >> 6, lane = t & 63;
  const float* wsrc = Wa1 + (size_t)kc * KROWS * DD;
  for (int idx = t; idx < KROWS * DD; idx += 256) ws_s[idx] = wsrc[idx];
  __syncthreads();
  for (int bb_ = 0; bb_ < 8; ++bb_) {
    int b = bt * 32 + wid * 8 + bb_;
    const float* xr = xt + (size_t)b * (NFRM * DD) + kc * KROWS;
    float acc = 0.f;
#pragma unroll 8
    for (int i = 0; i < KROWS; ++i) acc += xr[i] * ws_s[i * DD + lane];
    part[(size_t)kc * (BSZ * DD) + (size_t)b * DD + lane] = acc;
  }
}

__global__ void k_agg1red(const float* __restrict__ part, float* __restrict__ a1) {
  int g = blockIdx.x * 256 + threadIdx.x;
  float s = 0.f;
#pragma unroll 8
  for (int kc = 0; kc < KSP; ++kc) s += part[(size_t)kc * (BSZ * DD) + g];
  a1[g] = s;
}

// K13: head MLP
__global__ void k_head(const float* __restrict__ a1, const float* __restrict__ ba1,
                       const float* __restrict__ Wa2, const float* __restrict__ ba2,
                       const float* __restrict__ Wh1, const float* __restrict__ bh1,
                       const float* __restrict__ Wh2, const float* __restrict__ bh2,
                       float* __restrict__ out) {
  int b = blockIdx.x, t = threadIdx.x;
  __shared__ float s1[64], s2[32], s3[16];
  s1[t] = fmaxf(a1[b * DD + t] + ba1[t], 0.f);
  __syncthreads();
  if (t < 32) {
    float a = ba2[t];
#pragma unroll 8
    for (int j = 0; j < 64; ++j) a += s1[j] * Wa2[j * 32 + t];
    s2[t] = fmaxf(a, 0.f);
  }
  __syncthreads();
  if (t < 16) {
    float a = bh1[t];
#pragma unroll
    for (int j = 0; j < 32; ++j) a += s2[j] * Wh1[j * 16 + t];
    s3[t] = fmaxf(a, 0.f);
  }
  __syncthreads();
  if (t == 0) {
    float a = bh2[0];
#pragma unroll
    for (int j = 0; j < 16; ++j) a += s3[j] * Wh2[j];
    out[b] = 1.0f / (1.0f + expf(-a));
  }
}

extern "C" void kernel_launch(void* const* d_in, const int* in_sizes, int n_in,
                              void* d_out, int out_size, void* d_ws, size_t ws_size,
                              hipStream_t stream) {
  const float* x   = (const float*)d_in[0];
  const int*   ei  = (const int*)d_in[1];
  const float* Wi  = (const float*)d_in[2];
  const float* bi  = (const float*)d_in[3];
  const float* pe  = (const float*)d_in[4];
  const float* Wq  = (const float*)d_in[5];
  const float* Wk  = (const float*)d_in[6];
  const float* Wv  = (const float*)d_in[7];
  const float* bq  = (const float*)d_in[8];
  const float* bk  = (const float*)d_in[9];
  const float* bv  = (const float*)d_in[10];
  const float* Ws  = (const float*)d_in[11];
  const float* bs  = (const float*)d_in[12];
  const float* Wo  = (const float*)d_in[13];
  const float* bo  = (const float*)d_in[14];
  const float* gg  = (const float*)d_in[15];
  const float* gb  = (const float*)d_in[16];
  const float* Wqt = (const float*)d_in[17];
  const float* Wkt = (const float*)d_in[18];
  const float* Wvt = (const float*)d_in[19];
  const float* bqt = (const float*)d_in[20];
  const float* bkt = (const float*)d_in[21];
  const float* bvt = (const float*)d_in[22];
  const float* Wot = (const float*)d_in[23];
  const float* bot = (const float*)d_in[24];
  const float* l1g = (const float*)d_in[25];
  const float* l1b = (const float*)d_in[26];
  const float* W1  = (const float*)d_in[27];
  const float* b1  = (const float*)d_in[28];
  const float* W2  = (const float*)d_in[29];
  const float* b2  = (const float*)d_in[30];
  const float* l2g = (const float*)d_in[31];
  const float* l2b = (const float*)d_in[32];
  const float* Wa1 = (const float*)d_in[33];
  const float* ba1 = (const float*)d_in[34];
  const float* Wa2 = (const float*)d_in[35];
  const float* ba2 = (const float*)d_in[36];
  const float* Wh1 = (const float*)d_in[37];
  const float* bh1 = (const float*)d_in[38];
  const float* Wh2 = (const float*)d_in[39];
  const float* bh2 = (const float*)d_in[40];
  float* out = (float*)d_out;

  const size_t ND = (size_t)NN * DD;

  float* wsf    = (float*)d_ws;
  float* f_h    = wsf;                 // h / xt (fp32)
  float* f_q    = f_h  + ND;           // q fp32 -> qt/kt bf16
  float* f_k    = f_q  + ND;           // kv packed -> vt bf16
  float* f_v    = f_k  + ND;           // spare
  float* f_sk   = f_v  + ND;           // skip -> attn
  float* f_u    = f_sk + ND;           // gattn tmp fp32, then u bf16 [N][128]
  float* f_part = f_u  + 2 * ND;
  float* f_a1   = f_part + (size_t)KSP * BSZ * DD;
  int* i_srcs   = (int*)(f_a1 + BSZ * DD);
  int* i_rowptr = i_srcs + NE;
  int* i_cursor = i_rowptr + NN + 1;
  int* i_cnt    = i_cursor + NN;
  int* i_bsum   = i_cnt + NN;
  int* i_boff   = i_bsum + 256;
  unsigned short* wt = (unsigned short*)(i_boff + 256);  // 53248 ushorts

  ushort2* f_kv = (ushort2*)f_k;
  float* f_tmp  = f_u;
  unsigned short* us_qt = (unsigned short*)f_q;
  unsigned short* us_kt = us_qt + ND;
  unsigned short* us_vt = (unsigned short*)f_k;
  unsigned short* us_u  = (unsigned short*)f_u;

  hipMemsetAsync(i_cnt, 0, NN * sizeof(int), stream);

  dim3 B(256);
  // 0. weight prep (bf16 transposed)
  k_wprep<<<dim3(208), B, 0, stream>>>(Wo, Wot, Wqt, Wkt, Wvt, W1, W2, Wq, Wk, Wv, Ws, wt);
  // 1. input proj + PE
  k_input<<<dim3(NN / (4 * RB)), B, 0, stream>>>(x, Wi, bi, pe, f_h);
  // 2. q, kv(bf16), skip  (MFMA)
  k_qkvs_m<<<dim3(NN / 64), B, 0, stream>>>(f_h, wt, bq, bk, bv, bs, f_q, f_kv, f_sk);
  // 3. CSR build
  k_count<<<dim3(NE / 256), B, 0, stream>>>(ei, i_cnt);
  k_scan1<<<dim3(NN / 256), B, 0, stream>>>(i_cnt, i_rowptr, i_bsum);
  k_scan2<<<dim3(1), B, 0, stream>>>(i_bsum, i_boff);
  k_scan3<<<dim3(NN / 256), B, 0, stream>>>(i_rowptr, i_boff, i_cursor);
  k_scatter<<<dim3(NE / 256), B, 0, stream>>>(ei, i_cursor, i_srcs);
  // 4. graph attention + skip -> f_tmp; Wo matmul + residual LN -> f_h
  k_gattn<<<dim3(NN / 4), B, 0, stream>>>(f_q, f_kv, i_rowptr, i_srcs, f_sk, f_tmp);
  k_matln_m<<<dim3(NN / 64), B, 0, stream>>>(f_tmp, wt + 0, bo, gg, gb, f_h);
  // 5. temporal q,k,v (bf16, MFMA)
  k_qkvt_m<<<dim3(NN / 64), B, 0, stream>>>(f_h, wt, bqt, bkt, bvt, us_qt, us_kt, us_vt);
  // 6. temporal attention (MFMA) -> f_sk
  k_tattn<<<dim3(BSZ * HH), B, 0, stream>>>(us_qt, us_kt, us_vt, f_sk);
  // 7. attn@Wot + residual + LN1 -> f_h
  k_matln_m<<<dim3(NN / 64), B, 0, stream>>>(f_sk, wt + 4096, bot, l1g, l1b, f_h);
  // 8-9. FFN (MFMA) + LN2
  k_ffn1_m<<<dim3(NN / 64), B, 0, stream>>>(f_h, wt, b1, us_u);
  k_ffn2_m<<<dim3(NN / 64), B, 0, stream>>>(us_u, wt, b2, l2g, l2b, f_h);
  // 10. aggregation GEMM
  k_agg1a<<<dim3(KSP * 8), B, 0, stream>>>(f_h, Wa1, f_part);
  k_agg1red<<<dim3(BSZ * DD / 256), B, 0, stream>>>(f_part, f_a1);
  // 11. head MLP
  k_head<<<dim3(BSZ), dim3(64), 0, stream>>>(f_a1, ba1, Wa2, ba2, Wh1, bh1, Wh2, bh2, out);
}

// Round 7
// 286.187 us; speedup vs baseline: 4.0786x; 1.3251x over previous
//
#include <hip/hip_runtime.h>
#include <math.h>

#define NN 65536
#define SIN 24
#define DD 64
#define HH 4
#define HDIM 16
#define NFRM 256
#define NE 1048576
#define BSZ 256
#define EPSLN 1e-5f
#define SCL 0.25f
#define RB 8

#define KSP 128
#define KROWS 128

typedef __attribute__((ext_vector_type(8))) short bf16x8;
typedef __attribute__((ext_vector_type(4))) float f32x4;

__device__ __forceinline__ unsigned short f2bf(float f) {
  unsigned u = __float_as_uint(f);
  return (unsigned short)((u + 0x7FFFu + ((u >> 16) & 1u)) >> 16);
}
__device__ __forceinline__ float bf2f(unsigned short b) {
  return __uint_as_float(((unsigned)b) << 16);
}

// stage fp32 [rows][DK] -> bf16 LDS [rows][ST]
__device__ __forceinline__ void stage_f32(const float* __restrict__ src,
                                          unsigned short* dst, int n4, int DK, int ST, int tid) {
  int dk4 = DK >> 2;
  for (int idx = tid; idx < n4; idx += 256) {
    int row = idx / dk4, c = (idx % dk4) * 4;
    float4 v = *(const float4*)(src + (size_t)row * DK + c);
    uint2 p;
    p.x = (unsigned)f2bf(v.x) | ((unsigned)f2bf(v.y) << 16);
    p.y = (unsigned)f2bf(v.z) | ((unsigned)f2bf(v.w) << 16);
    *(uint2*)(dst + row * ST + c) = p;
  }
}

// stage bf16 [rows][DK] -> LDS [rows][ST]
__device__ __forceinline__ void stage_bf(const unsigned short* __restrict__ src,
                                         unsigned short* dst, int n8, int DK, int ST, int tid) {
  int dk8 = DK >> 3;
  for (int idx = tid; idx < n8; idx += 256) {
    int row = idx / dk8, c = (idx % dk8) * 8;
    *(uint4*)(dst + row * ST + c) = *(const uint4*)(src + (size_t)row * DK + c);
  }
}

// K1: h = x @ Wi + bi + pe[n % NF]
__global__ void k_input(const float* __restrict__ x, const float* __restrict__ Wi,
                        const float* __restrict__ bi, const float* __restrict__ pe,
                        float* __restrict__ h) {
  int lane = threadIdx.x & 63;
  int wid = __builtin_amdgcn_readfirstlane(threadIdx.x >> 6);
  int n0 = (blockIdx.x * 4 + wid) * RB;
  float b = bi[lane];
  float acc[RB];
#pragma unroll
  for (int r = 0; r < RB; ++r) acc[r] = b + pe[((n0 + r) & (NFRM - 1)) * DD + lane];
  for (int s = 0; s < SIN; ++s) {
    float w = Wi[s * DD + lane];
#pragma unroll
    for (int r = 0; r < RB; ++r) acc[r] += x[(size_t)(n0 + r) * SIN + s] * w;
  }
#pragma unroll
  for (int r = 0; r < RB; ++r) h[(size_t)(n0 + r) * DD + lane] = acc[r];
}

// Weight prep: transpose all dense weights to bf16 Wt[Nout][Dk]
__global__ void k_wprep(const float* __restrict__ Wo, const float* __restrict__ Wot,
                        const float* __restrict__ Wqt, const float* __restrict__ Wkt,
                        const float* __restrict__ Wvt, const float* __restrict__ W1,
                        const float* __restrict__ W2, const float* __restrict__ Wq,
                        const float* __restrict__ Wk, const float* __restrict__ Wv,
                        const float* __restrict__ Wsk, unsigned short* __restrict__ wt) {
  int i = blockIdx.x * 256 + threadIdx.x;
  if (i >= 53248) return;
  float v;
  if (i < 4096)       { int t = i;         int j = t >> 6, d = t & 63; v = Wo[d * 64 + j]; }
  else if (i < 8192)  { int t = i - 4096;  int j = t >> 6, d = t & 63; v = Wot[d * 64 + j]; }
  else if (i < 12288) { int t = i - 8192;  int j = t >> 6, d = t & 63; v = Wqt[d * 64 + j]; }
  else if (i < 16384) { int t = i - 12288; int j = t >> 6, d = t & 63; v = Wkt[d * 64 + j]; }
  else if (i < 20480) { int t = i - 16384; int j = t >> 6, d = t & 63; v = Wvt[d * 64 + j]; }
  else if (i < 28672) { int t = i - 20480; int j = t >> 6, d = t & 63; v = W1[d * 128 + j]; }
  else if (i < 36864) { int t = i - 28672; int j = t >> 7, d = t & 127; v = W2[d * 64 + j]; }
  else if (i < 40960) { int t = i - 36864; int j = t >> 6, d = t & 63; v = Wq[(j >> 4) * 1024 + d * 16 + (j & 15)]; }
  else if (i < 45056) { int t = i - 40960; int j = t >> 6, d = t & 63; v = Wk[(j >> 4) * 1024 + d * 16 + (j & 15)]; }
  else if (i < 49152) { int t = i - 45056; int j = t >> 6, d = t & 63; v = Wv[(j >> 4) * 1024 + d * 16 + (j & 15)]; }
  else                { int t = i - 49152; int j = t >> 6, d = t & 63; v = Wsk[(j >> 4) * 1024 + d * 16 + (j & 15)]; }
  wt[i] = f2bf(v);
}

// K2 (MFMA): q fp32, kv packed bf16, sk fp32
__global__ void __launch_bounds__(256)
k_qkvs_m(const float* __restrict__ h, const unsigned short* __restrict__ wt,
         const float* __restrict__ bq, const float* __restrict__ bk,
         const float* __restrict__ bv, const float* __restrict__ bs,
         float* __restrict__ q, ushort2* __restrict__ kv, float* __restrict__ sk) {
  __shared__ unsigned short Xs[64 * 72];
  __shared__ unsigned short Ws4[4 * 64 * 72];
  int tid = threadIdx.x;
  int n0 = blockIdx.x * 64;
  stage_f32(h + (size_t)n0 * 64, Xs, 64 * 16, 64, 72, tid);
  stage_bf(wt + 36864, Ws4, 64 * 8, 64, 72, tid);
  stage_bf(wt + 40960, Ws4 + 4608, 64 * 8, 64, 72, tid);
  stage_bf(wt + 45056, Ws4 + 9216, 64 * 8, 64, 72, tid);
  stage_bf(wt + 49152, Ws4 + 13824, 64 * 8, 64, 72, tid);
  __syncthreads();
  int lane = tid & 63, w = tid >> 6;
  int c = lane & 15, g = lane >> 4;
  f32x4 aq[4], ak[4], av[4], as_[4];
#pragma unroll
  for (int j = 0; j < 4; ++j) {
#pragma unroll
    for (int r = 0; r < 4; ++r) { aq[j][r] = 0.f; ak[j][r] = 0.f; av[j][r] = 0.f; as_[j][r] = 0.f; }
  }
  const unsigned short* xrow = Xs + (w * 16 + c) * 72 + g * 8;
#pragma unroll
  for (int kk = 0; kk < 2; ++kk) {
    bf16x8 af = *(const bf16x8*)(xrow + kk * 32);
#pragma unroll
    for (int j = 0; j < 4; ++j) {
      int boff = (j * 16 + c) * 72 + kk * 32 + g * 8;
      aq[j] = __builtin_amdgcn_mfma_f32_16x16x32_bf16(af, *(const bf16x8*)(Ws4 + boff), aq[j], 0, 0, 0);
      ak[j] = __builtin_amdgcn_mfma_f32_16x16x32_bf16(af, *(const bf16x8*)(Ws4 + 4608 + boff), ak[j], 0, 0, 0);
      av[j] = __builtin_amdgcn_mfma_f32_16x16x32_bf16(af, *(const bf16x8*)(Ws4 + 9216 + boff), av[j], 0, 0, 0);
      as_[j] = __builtin_amdgcn_mfma_f32_16x16x32_bf16(af, *(const bf16x8*)(Ws4 + 13824 + boff), as_[j], 0, 0, 0);
    }
  }
  int rowb = n0 + w * 16 + 4 * g;
#pragma unroll
  for (int j = 0; j < 4; ++j) {
    int col = j * 16 + c;
    float bqj = bq[col], bkj = bk[col], bvj = bv[col], bsj = bs[col];
#pragma unroll
    for (int r = 0; r < 4; ++r) {
      size_t o = (size_t)(rowb + r) * 64 + col;
      q[o] = aq[j][r] + bqj;
      kv[o] = make_ushort2(f2bf(ak[j][r] + bkj), f2bf(av[j][r] + bvj));
      sk[o] = as_[j][r] + bsj;
    }
  }
}

// ---- Bucketed CSR build (bucket = dst >> 8) ----
// K3a: per-block histogram over buckets
__global__ void k_hist(const int* __restrict__ ei, int* __restrict__ hist) {
  __shared__ int h[256];
  int t = threadIdx.x;
  h[t] = 0;
  __syncthreads();
  int base = blockIdx.x * 4096;
#pragma unroll
  for (int r = 0; r < 16; ++r)
    atomicAdd(&h[ei[NE + base + r * 256 + t] >> 8], 1);
  __syncthreads();
  hist[t * 256 + blockIdx.x] = h[t];   // hist[bucket][block]
}

// K3b: per-bucket exclusive scan over blocks; emit bucket totals
__global__ void k_hscan(int* __restrict__ hist, int* __restrict__ btot) {
  __shared__ int s[256];
  int t = threadIdx.x, bkt = blockIdx.x;
  int v = hist[bkt * 256 + t];
  s[t] = v; __syncthreads();
  for (int off = 1; off < 256; off <<= 1) {
    int x = (t >= off) ? s[t - off] : 0;
    __syncthreads();
    s[t] += x;
    __syncthreads();
  }
  hist[bkt * 256 + t] = s[t] - v;
  if (t == 255) btot[bkt] = s[255];
}

// K3c: exclusive scan of bucket totals -> bucket bases
__global__ void k_bscan(const int* __restrict__ btot, int* __restrict__ bbase) {
  __shared__ int s[256];
  int t = threadIdx.x;
  int v = btot[t];
  s[t] = v; __syncthreads();
  for (int off = 1; off < 256; off <<= 1) {
    int x = (t >= off) ? s[t - off] : 0;
    __syncthreads();
    s[t] += x;
    __syncthreads();
  }
  bbase[t] = s[t] - v;
}

// K3d: partition edges into bucket-major pairs (dstlow<<16 | src)
__global__ void k_passB(const int* __restrict__ ei, const int* __restrict__ hist,
                        const int* __restrict__ bbase, int* __restrict__ pairs) {
  __shared__ int cur[256];
  int t = threadIdx.x;
  cur[t] = bbase[t] + hist[t * 256 + blockIdx.x];
  __syncthreads();
  int base = blockIdx.x * 4096;
#pragma unroll
  for (int r = 0; r < 16; ++r) {
    int e = base + r * 256 + t;
    int src = ei[e], dst = ei[NE + e];
    int pos = atomicAdd(&cur[dst >> 8], 1);
    pairs[pos] = ((dst & 255) << 16) | src;
  }
}

// K3e: per-bucket local CSR: counts -> rowptr, place srcs (L2-local writes)
__global__ void k_passC(const int* __restrict__ pairs, const int* __restrict__ bbase,
                        const int* __restrict__ btot, int* __restrict__ rowptr,
                        int* __restrict__ srcs) {
  __shared__ int cnt[256];
  __shared__ int s[256];
  int t = threadIdx.x, bkt = blockIdx.x;
  cnt[t] = 0;
  __syncthreads();
  int base = bbase[bkt], n = btot[bkt];
  for (int i = t; i < n; i += 256) atomicAdd(&cnt[pairs[base + i] >> 16], 1);
  __syncthreads();
  int v = cnt[t];
  s[t] = v; __syncthreads();
  for (int off = 1; off < 256; off <<= 1) {
    int x = (t >= off) ? s[t - off] : 0;
    __syncthreads();
    s[t] += x;
    __syncthreads();
  }
  int rp = base + s[t] - v;
  rowptr[bkt * 256 + t] = rp;
  if (bkt == 0 && t == 0) rowptr[NN] = NE;
  __syncthreads();
  cnt[t] = rp;   // reuse as cursor
  __syncthreads();
  for (int i = t; i < n; i += 256) {
    int p = pairs[base + i];
    int pos = atomicAdd(&cnt[p >> 16], 1);
    srcs[pos] = p & 0xFFFF;
  }
}

// Graph attention + skip -> tmp
__global__ void k_gattn(const float* __restrict__ q, const ushort2* __restrict__ kv,
                        const int* __restrict__ rowptr,
                        const int* __restrict__ srcs, const float* __restrict__ sk,
                        float* __restrict__ tmp) {
  int wid = threadIdx.x >> 6, lane = threadIdx.x & 63;
  int dst = (blockIdx.x << 2) + wid;
  size_t base = (size_t)dst * DD;
  float qv = q[base + lane];
  int beg = rowptr[dst], end = rowptr[dst + 1];
  float m = -INFINITY, l = 0.f, acc = 0.f;
  int idx = beg;
  for (; idx + 4 <= end; idx += 4) {
    int s0 = srcs[idx], s1 = srcs[idx + 1], s2 = srcs[idx + 2], s3 = srcs[idx + 3];
    ushort2 a0 = kv[(size_t)s0 * DD + lane];
    ushort2 a1 = kv[(size_t)s1 * DD + lane];
    ushort2 a2 = kv[(size_t)s2 * DD + lane];
    ushort2 a3 = kv[(size_t)s3 * DD + lane];
    float t0 = qv * bf2f(a0.x), t1 = qv * bf2f(a1.x);
    float t2 = qv * bf2f(a2.x), t3 = qv * bf2f(a3.x);
#pragma unroll
    for (int off = 1; off <= 8; off <<= 1) {
      t0 += __shfl_xor(t0, off);
      t1 += __shfl_xor(t1, off);
      t2 += __shfl_xor(t2, off);
      t3 += __shfl_xor(t3, off);
    }
    t0 *= SCL; t1 *= SCL; t2 *= SCL; t3 *= SCL;
    float nm = fmaxf(fmaxf(m, fmaxf(t0, t1)), fmaxf(t2, t3));
    float cc = __expf(m - nm);
    float p0 = __expf(t0 - nm), p1 = __expf(t1 - nm);
    float p2 = __expf(t2 - nm), p3 = __expf(t3 - nm);
    l = l * cc + ((p0 + p1) + (p2 + p3));
    acc = acc * cc + ((p0 * bf2f(a0.y) + p1 * bf2f(a1.y)) +
                      (p2 * bf2f(a2.y) + p3 * bf2f(a3.y)));
    m = nm;
  }
  for (; idx < end; ++idx) {
    int s0 = srcs[idx];
    ushort2 a0 = kv[(size_t)s0 * DD + lane];
    float t0 = qv * bf2f(a0.x);
#pragma unroll
    for (int off = 1; off <= 8; off <<= 1) t0 += __shfl_xor(t0, off);
    t0 *= SCL;
    float nm = fmaxf(m, t0);
    float cc = __expf(m - nm), p = __expf(t0 - nm);
    l = l * cc + p;
    acc = acc * cc + p * bf2f(a0.y);
    m = nm;
  }
  float aggv = (end > beg) ? acc / l : 0.f;
  tmp[base + lane] = aggv + sk[base + lane];
}

// MFMA: io = LN(io + in1 @ W + bias)
__global__ void __launch_bounds__(256)
k_matln_m(const float* __restrict__ in1, const unsigned short* __restrict__ Wt,
          const float* __restrict__ bias, const float* __restrict__ gam,
          const float* __restrict__ bet, float* __restrict__ io) {
  __shared__ unsigned short Xs[64 * 72];
  __shared__ unsigned short Ws[64 * 72];
  int tid = threadIdx.x;
  int n0 = blockIdx.x * 64;
  stage_f32(in1 + (size_t)n0 * 64, Xs, 64 * 16, 64, 72, tid);
  stage_bf(Wt, Ws, 64 * 8, 64, 72, tid);
  __syncthreads();
  int lane = tid & 63, w = tid >> 6;
  int c = lane & 15, g = lane >> 4;
  f32x4 acc[4];
#pragma unroll
  for (int j = 0; j < 4; ++j) { acc[j][0] = 0.f; acc[j][1] = 0.f; acc[j][2] = 0.f; acc[j][3] = 0.f; }
  const unsigned short* xrow = Xs + (w * 16 + c) * 72 + g * 8;
#pragma unroll
  for (int kk = 0; kk < 2; ++kk) {
    bf16x8 af = *(const bf16x8*)(xrow + kk * 32);
#pragma unroll
    for (int j = 0; j < 4; ++j)
      acc[j] = __builtin_amdgcn_mfma_f32_16x16x32_bf16(af,
                 *(const bf16x8*)(Ws + (j * 16 + c) * 72 + kk * 32 + g * 8), acc[j], 0, 0, 0);
  }
  int rowb = n0 + w * 16 + 4 * g;
  float o[4][4], gj[4], bj[4];
#pragma unroll
  for (int j = 0; j < 4; ++j) {
    int col = j * 16 + c;
    float bb = bias[col];
    gj[j] = gam[col]; bj[j] = bet[col];
#pragma unroll
    for (int r = 0; r < 4; ++r)
      o[j][r] = acc[j][r] + bb + io[(size_t)(rowb + r) * 64 + col];
  }
#pragma unroll
  for (int r = 0; r < 4; ++r) {
    float s = (o[0][r] + o[1][r]) + (o[2][r] + o[3][r]);
    float s2 = (o[0][r] * o[0][r] + o[1][r] * o[1][r]) + (o[2][r] * o[2][r] + o[3][r] * o[3][r]);
#pragma unroll
    for (int off = 1; off <= 8; off <<= 1) {
      s += __shfl_xor(s, off);
      s2 += __shfl_xor(s2, off);
    }
    float mean = s * (1.0f / 64.0f);
    float var = s2 * (1.0f / 64.0f) - mean * mean;
    float rs = rsqrtf(var + EPSLN);
#pragma unroll
    for (int j = 0; j < 4; ++j)
      io[(size_t)(rowb + r) * 64 + j * 16 + c] = (o[j][r] - mean) * rs * gj[j] + bj[j];
  }
}

// MFMA: qt,kt,vt (bf16 out)
__global__ void __launch_bounds__(256)
k_qkvt_m(const float* __restrict__ xt, const unsigned short* __restrict__ wt,
         const float* __restrict__ bqt, const float* __restrict__ bkt,
         const float* __restrict__ bvt,
         unsigned short* __restrict__ qt, unsigned short* __restrict__ kt,
         unsigned short* __restrict__ vt) {
  __shared__ unsigned short Xs[64 * 72];
  __shared__ unsigned short Ws3[3 * 64 * 72];
  int tid = threadIdx.x;
  int n0 = blockIdx.x * 64;
  stage_f32(xt + (size_t)n0 * 64, Xs, 64 * 16, 64, 72, tid);
  stage_bf(wt + 8192, Ws3, 64 * 8, 64, 72, tid);
  stage_bf(wt + 12288, Ws3 + 4608, 64 * 8, 64, 72, tid);
  stage_bf(wt + 16384, Ws3 + 9216, 64 * 8, 64, 72, tid);
  __syncthreads();
  int lane = tid & 63, w = tid >> 6;
  int c = lane & 15, g = lane >> 4;
  f32x4 aq[4], ak[4], av[4];
#pragma unroll
  for (int j = 0; j < 4; ++j) {
#pragma unroll
    for (int r = 0; r < 4; ++r) { aq[j][r] = 0.f; ak[j][r] = 0.f; av[j][r] = 0.f; }
  }
  const unsigned short* xrow = Xs + (w * 16 + c) * 72 + g * 8;
#pragma unroll
  for (int kk = 0; kk < 2; ++kk) {
    bf16x8 af = *(const bf16x8*)(xrow + kk * 32);
#pragma unroll
    for (int j = 0; j < 4; ++j) {
      int boff = (j * 16 + c) * 72 + kk * 32 + g * 8;
      aq[j] = __builtin_amdgcn_mfma_f32_16x16x32_bf16(af, *(const bf16x8*)(Ws3 + boff), aq[j], 0, 0, 0);
      ak[j] = __builtin_amdgcn_mfma_f32_16x16x32_bf16(af, *(const bf16x8*)(Ws3 + 4608 + boff), ak[j], 0, 0, 0);
      av[j] = __builtin_amdgcn_mfma_f32_16x16x32_bf16(af, *(const bf16x8*)(Ws3 + 9216 + boff), av[j], 0, 0, 0);
    }
  }
  int rowb = n0 + w * 16 + 4 * g;
#pragma unroll
  for (int j = 0; j < 4; ++j) {
    int col = j * 16 + c;
    float bqj = bqt[col], bkj = bkt[col], bvj = bvt[col];
#pragma unroll
    for (int r = 0; r < 4; ++r) {
      size_t o = (size_t)(rowb + r) * 64 + col;
      qt[o] = f2bf(aq[j][r] + bqj);
      kt[o] = f2bf(ak[j][r] + bkj);
      vt[o] = f2bf(av[j][r] + bvj);
    }
  }
}

// K8: temporal attention via MFMA
#define VST 20
#define PST 40
__global__ void __launch_bounds__(256)
k_tattn(const unsigned short* __restrict__ qtb, const unsigned short* __restrict__ ktb,
        const unsigned short* __restrict__ vtb, float* __restrict__ attn) {
  int b = blockIdx.x >> 2, hh = blockIdx.x & 3;
  __shared__ unsigned short Qs[NFRM][16];
  __shared__ unsigned short Ks[NFRM][16];
  __shared__ unsigned short Vs[NFRM][VST];
  __shared__ unsigned short Ps[4][16][PST];
  int t = threadIdx.x;
  int wv = t >> 6, lane = t & 63;
  int g = lane >> 4, c = lane & 15;
  {
    size_t src = ((size_t)b * NFRM + t) * DD + hh * 16;
    const uint4* qsrc = (const uint4*)(qtb + src);
    const uint4* ksrc = (const uint4*)(ktb + src);
    const uint2* vsrc = (const uint2*)(vtb + src);
    ((uint4*)Qs[t])[0] = qsrc[0]; ((uint4*)Qs[t])[1] = qsrc[1];
    ((uint4*)Ks[t])[0] = ksrc[0]; ((uint4*)Ks[t])[1] = ksrc[1];
    uint2* vdst = (uint2*)Vs[t];
    vdst[0] = vsrc[0]; vdst[1] = vsrc[1]; vdst[2] = vsrc[2]; vdst[3] = vsrc[3];
  }
  __syncthreads();
  const bf16x8 zf = {0, 0, 0, 0, 0, 0, 0, 0};
  unsigned short (*P)[PST] = Ps[wv];
  for (int qt0 = wv; qt0 < 16; qt0 += 4) {
    bf16x8 qf = zf;
    if (g < 2) qf = *(const bf16x8*)&Qs[qt0 * 16 + c][g * 8];
    f32x4 O = {0.f, 0.f, 0.f, 0.f};
    float lacc[4] = {0.f, 0.f, 0.f, 0.f};
    for (int jp = 0; jp < 8; ++jp) {
#pragma unroll
      for (int half = 0; half < 2; ++half) {
        int jt = jp * 2 + half;
        bf16x8 kf = zf;
        if (g < 2) kf = *(const bf16x8*)&Ks[jt * 16 + c][g * 8];
        f32x4 S = __builtin_amdgcn_mfma_f32_16x16x32_bf16(qf, kf,
                    (f32x4){0.f, 0.f, 0.f, 0.f}, 0, 0, 0);
#pragma unroll
        for (int r = 0; r < 4; ++r) {
          float p = __expf(S[r] * SCL);
          lacc[r] += p;
          P[4 * g + r][half * 16 + c] = f2bf(p);
        }
      }
      bf16x8 pf = *(const bf16x8*)&P[c][g * 8];
      bf16x8 vf;
#pragma unroll
      for (int i = 0; i < 8; ++i) vf[i] = (short)Vs[jp * 32 + g * 8 + i][c];
      O = __builtin_amdgcn_mfma_f32_16x16x32_bf16(pf, vf, O, 0, 0, 0);
    }
#pragma unroll
    for (int r = 0; r < 4; ++r) {
      float s = lacc[r];
      s += __shfl_xor(s, 1); s += __shfl_xor(s, 2);
      s += __shfl_xor(s, 4); s += __shfl_xor(s, 8);
      lacc[r] = 1.0f / s;
    }
    size_t obase = ((size_t)b * NFRM + qt0 * 16) * DD + hh * 16;
#pragma unroll
    for (int r = 0; r < 4; ++r)
      attn[obase + (size_t)(4 * g + r) * DD + c] = O[r] * lacc[r];
  }
}

// MFMA: u = relu(xt @ W1 + b1), bf16 out [N][128]
__global__ void __launch_bounds__(256)
k_ffn1_m(const float* __restrict__ xt, const unsigned short* __restrict__ wt,
         const float* __restrict__ b1, unsigned short* __restrict__ u) {
  __shared__ unsigned short Xs[64 * 72];
  __shared__ unsigned short Ws[128 * 72];
  int tid = threadIdx.x;
  int n0 = blockIdx.x * 64;
  stage_f32(xt + (size_t)n0 * 64, Xs, 64 * 16, 64, 72, tid);
  stage_bf(wt + 20480, Ws, 128 * 8, 64, 72, tid);
  __syncthreads();
  int lane = tid & 63, w = tid >> 6;
  int c = lane & 15, g = lane >> 4;
  f32x4 acc[8];
#pragma unroll
  for (int j = 0; j < 8; ++j) { acc[j][0] = 0.f; acc[j][1] = 0.f; acc[j][2] = 0.f; acc[j][3] = 0.f; }
  const unsigned short* xrow = Xs + (w * 16 + c) * 72 + g * 8;
#pragma unroll
  for (int kk = 0; kk < 2; ++kk) {
    bf16x8 af = *(const bf16x8*)(xrow + kk * 32);
#pragma unroll
    for (int j = 0; j < 8; ++j)
      acc[j] = __builtin_amdgcn_mfma_f32_16x16x32_bf16(af,
                 *(const bf16x8*)(Ws + (j * 16 + c) * 72 + kk * 32 + g * 8), acc[j], 0, 0, 0);
  }
  int rowb = n0 + w * 16 + 4 * g;
#pragma unroll
  for (int j = 0; j < 8; ++j) {
    int col = j * 16 + c;
    float bb = b1[col];
#pragma unroll
    for (int r = 0; r < 4; ++r)
      u[(size_t)(rowb + r) * 128 + col] = f2bf(fmaxf(acc[j][r] + bb, 0.f));
  }
}

// MFMA: xt = LN(xt + u @ W2 + b2)
__global__ void __launch_bounds__(256)
k_ffn2_m(const unsigned short* __restrict__ u, const unsigned short* __restrict__ wt,
         const float* __restrict__ b2, const float* __restrict__ gam,
         const float* __restrict__ bet, float* __restrict__ xt) {
  __shared__ unsigned short Xs[64 * 136];
  __shared__ unsigned short Ws[64 * 136];
  int tid = threadIdx.x;
  int n0 = blockIdx.x * 64;
  stage_bf(u + (size_t)n0 * 128, Xs, 64 * 16, 128, 136, tid);
  stage_bf(wt + 28672, Ws, 64 * 16, 128, 136, tid);
  __syncthreads();
  int lane = tid & 63, w = tid >> 6;
  int c = lane & 15, g = lane >> 4;
  f32x4 acc[4];
#pragma unroll
  for (int j = 0; j < 4; ++j) { acc[j][0] = 0.f; acc[j][1] = 0.f; acc[j][2] = 0.f; acc[j][3] = 0.f; }
  const unsigned short* xrow = Xs + (w * 16 + c) * 136 + g * 8;
#pragma unroll
  for (int kk = 0; kk < 4; ++kk) {
    bf16x8 af = *(const bf16x8*)(xrow + kk * 32);
#pragma unroll
    for (int j = 0; j < 4; ++j)
      acc[j] = __builtin_amdgcn_mfma_f32_16x16x32_bf16(af,
                 *(const bf16x8*)(Ws + (j * 16 + c) * 136 + kk * 32 + g * 8), acc[j], 0, 0, 0);
  }
  int rowb = n0 + w * 16 + 4 * g;
  float o[4][4], gj[4], bj[4];
#pragma unroll
  for (int j = 0; j < 4; ++j) {
    int col = j * 16 + c;
    float bb = b2[col];
    gj[j] = gam[col]; bj[j] = bet[col];
#pragma unroll
    for (int r = 0; r < 4; ++r)
      o[j][r] = acc[j][r] + bb + xt[(size_t)(rowb + r) * 64 + col];
  }
#pragma unroll
  for (int r = 0; r < 4; ++r) {
    float s = (o[0][r] + o[1][r]) + (o[2][r] + o[3][r]);
    float s2 = (o[0][r] * o[0][r] + o[1][r] * o[1][r]) + (o[2][r] * o[2][r] + o[3][r] * o[3][r]);
#pragma unroll
    for (int off = 1; off <= 8; off <<= 1) {
      s += __shfl_xor(s, off);
      s2 += __shfl_xor(s2, off);
    }
    float mean = s * (1.0f / 64.0f);
    float var = s2 * (1.0f / 64.0f) - mean * mean;
    float rs = rsqrtf(var + EPSLN);
#pragma unroll
    for (int j = 0; j < 4; ++j)
      xt[(size_t)(rowb + r) * 64 + j * 16 + c] = (o[j][r] - mean) * rs * gj[j] + bj[j];
  }
}

// K12a: agg1 GEMM partials
__global__ void k_agg1a(const float* __restrict__ xt, const float* __restrict__ Wa1,
                        float* __restrict__ part) {
  __shared__ float ws_s[KROWS * DD];
  int kc = blockIdx.x >> 3, bt = blockIdx.x & 7;
  int t = threadIdx.x, wid = t >> 6, lane = t & 63;
  const float* wsrc = Wa1 + (size_t)kc * KROWS * DD;
  for (int idx = t; idx < KROWS * DD; idx += 256) ws_s[idx] = wsrc[idx];
  __syncthreads();
  for (int bb_ = 0; bb_ < 8; ++bb_) {
    int b = bt * 32 + wid * 8 + bb_;
    const float* xr = xt + (size_t)b * (NFRM * DD) + kc * KROWS;
    float acc = 0.f;
#pragma unroll 8
    for (int i = 0; i < KROWS; ++i) acc += xr[i] * ws_s[i * DD + lane];
    part[(size_t)kc * (BSZ * DD) + (size_t)b * DD + lane] = acc;
  }
}

__global__ void k_agg1red(const float* __restrict__ part, float* __restrict__ a1) {
  int g = blockIdx.x * 256 + threadIdx.x;
  float s = 0.f;
#pragma unroll 8
  for (int kc = 0; kc < KSP; ++kc) s += part[(size_t)kc * (BSZ * DD) + g];
  a1[g] = s;
}

// K13: head MLP
__global__ void k_head(const float* __restrict__ a1, const float* __restrict__ ba1,
                       const float* __restrict__ Wa2, const float* __restrict__ ba2,
                       const float* __restrict__ Wh1, const float* __restrict__ bh1,
                       const float* __restrict__ Wh2, const float* __restrict__ bh2,
                       float* __restrict__ out) {
  int b = blockIdx.x, t = threadIdx.x;
  __shared__ float s1[64], s2[32], s3[16];
  s1[t] = fmaxf(a1[b * DD + t] + ba1[t], 0.f);
  __syncthreads();
  if (t < 32) {
    float a = ba2[t];
#pragma unroll 8
    for (int j = 0; j < 64; ++j) a += s1[j] * Wa2[j * 32 + t];
    s2[t] = fmaxf(a, 0.f);
  }
  __syncthreads();
  if (t < 16) {
    float a = bh1[t];
#pragma unroll
    for (int j = 0; j < 32; ++j) a += s2[j] * Wh1[j * 16 + t];
    s3[t] = fmaxf(a, 0.f);
  }
  __syncthreads();
  if (t == 0) {
    float a = bh2[0];
#pragma unroll
    for (int j = 0; j < 16; ++j) a += s3[j] * Wh2[j];
    out[b] = 1.0f / (1.0f + expf(-a));
  }
}

extern "C" void kernel_launch(void* const* d_in, const int* in_sizes, int n_in,
                              void* d_out, int out_size, void* d_ws, size_t ws_size,
                              hipStream_t stream) {
  const float* x   = (const float*)d_in[0];
  const int*   ei  = (const int*)d_in[1];
  const float* Wi  = (const float*)d_in[2];
  const float* bi  = (const float*)d_in[3];
  const float* pe  = (const float*)d_in[4];
  const float* Wq  = (const float*)d_in[5];
  const float* Wk  = (const float*)d_in[6];
  const float* Wv  = (const float*)d_in[7];
  const float* bq  = (const float*)d_in[8];
  const float* bk  = (const float*)d_in[9];
  const float* bv  = (const float*)d_in[10];
  const float* Ws  = (const float*)d_in[11];
  const float* bs  = (const float*)d_in[12];
  const float* Wo  = (const float*)d_in[13];
  const float* bo  = (const float*)d_in[14];
  const float* gg  = (const float*)d_in[15];
  const float* gb  = (const float*)d_in[16];
  const float* Wqt = (const float*)d_in[17];
  const float* Wkt = (const float*)d_in[18];
  const float* Wvt = (const float*)d_in[19];
  const float* bqt = (const float*)d_in[20];
  const float* bkt = (const float*)d_in[21];
  const float* bvt = (const float*)d_in[22];
  const float* Wot = (const float*)d_in[23];
  const float* bot = (const float*)d_in[24];
  const float* l1g = (const float*)d_in[25];
  const float* l1b = (const float*)d_in[26];
  const float* W1  = (const float*)d_in[27];
  const float* b1  = (const float*)d_in[28];
  const float* W2  = (const float*)d_in[29];
  const float* b2  = (const float*)d_in[30];
  const float* l2g = (const float*)d_in[31];
  const float* l2b = (const float*)d_in[32];
  const float* Wa1 = (const float*)d_in[33];
  const float* ba1 = (const float*)d_in[34];
  const float* Wa2 = (const float*)d_in[35];
  const float* ba2 = (const float*)d_in[36];
  const float* Wh1 = (const float*)d_in[37];
  const float* bh1 = (const float*)d_in[38];
  const float* Wh2 = (const float*)d_in[39];
  const float* bh2 = (const float*)d_in[40];
  float* out = (float*)d_out;

  const size_t ND = (size_t)NN * DD;

  float* wsf    = (float*)d_ws;
  float* f_h    = wsf;                 // h / xt (fp32)
  float* f_q    = f_h  + ND;           // q fp32 -> qt/kt bf16
  float* f_k    = f_q  + ND;           // kv packed -> vt bf16
  float* f_v    = f_k  + ND;           // spare
  float* f_sk   = f_v  + ND;           // skip -> attn
  float* f_u    = f_sk + ND;           // gattn tmp fp32, then u bf16 [N][128]
  float* f_part = f_u  + 2 * ND;
  float* f_a1   = f_part + (size_t)KSP * BSZ * DD;
  int* i_srcs   = (int*)(f_a1 + BSZ * DD);  // [NE]
  int* i_rowptr = i_srcs + NE;              // [NN+1]
  int* i_hist   = i_rowptr + NN + 1;        // [256*256]
  int* i_btot   = i_hist + 65536;           // [256]
  int* i_bbase  = i_btot + 256;             // [256]
  int* i_pairs  = i_bbase + 256;            // [NE]
  unsigned short* wt = (unsigned short*)(i_pairs + NE);  // 53248 ushorts

  ushort2* f_kv = (ushort2*)f_k;
  float* f_tmp  = f_u;
  unsigned short* us_qt = (unsigned short*)f_q;
  unsigned short* us_kt = us_qt + ND;
  unsigned short* us_vt = (unsigned short*)f_k;
  unsigned short* us_u  = (unsigned short*)f_u;

  dim3 B(256);
  // 0. weight prep (bf16 transposed)
  k_wprep<<<dim3(208), B, 0, stream>>>(Wo, Wot, Wqt, Wkt, Wvt, W1, W2, Wq, Wk, Wv, Ws, wt);
  // 1. input proj + PE
  k_input<<<dim3(NN / (4 * RB)), B, 0, stream>>>(x, Wi, bi, pe, f_h);
  // 2. q, kv(bf16), skip  (MFMA)
  k_qkvs_m<<<dim3(NN / 64), B, 0, stream>>>(f_h, wt, bq, bk, bv, bs, f_q, f_kv, f_sk);
  // 3. bucketed CSR build
  k_hist <<<dim3(256), B, 0, stream>>>(ei, i_hist);
  k_hscan<<<dim3(256), B, 0, stream>>>(i_hist, i_btot);
  k_bscan<<<dim3(1),   B, 0, stream>>>(i_btot, i_bbase);
  k_passB<<<dim3(256), B, 0, stream>>>(ei, i_hist, i_bbase, i_pairs);
  k_passC<<<dim3(256), B, 0, stream>>>(i_pairs, i_bbase, i_btot, i_rowptr, i_srcs);
  // 4. graph attention + skip -> f_tmp; Wo matmul + residual LN -> f_h
  k_gattn<<<dim3(NN / 4), B, 0, stream>>>(f_q, f_kv, i_rowptr, i_srcs, f_sk, f_tmp);
  k_matln_m<<<dim3(NN / 64), B, 0, stream>>>(f_tmp, wt + 0, bo, gg, gb, f_h);
  // 5. temporal q,k,v (bf16, MFMA)
  k_qkvt_m<<<dim3(NN / 64), B, 0, stream>>>(f_h, wt, bqt, bkt, bvt, us_qt, us_kt, us_vt);
  // 6. temporal attention (MFMA) -> f_sk
  k_tattn<<<dim3(BSZ * HH), B, 0, stream>>>(us_qt, us_kt, us_vt, f_sk);
  // 7. attn@Wot + residual + LN1 -> f_h
  k_matln_m<<<dim3(NN / 64), B, 0, stream>>>(f_sk, wt + 4096, bot, l1g, l1b, f_h);
  // 8-9. FFN (MFMA) + LN2
  k_ffn1_m<<<dim3(NN / 64), B, 0, stream>>>(f_h, wt, b1, us_u);
  k_ffn2_m<<<dim3(NN / 64), B, 0, stream>>>(us_u, wt, b2, l2g, l2b, f_h);
  // 10. aggregation GEMM
  k_agg1a<<<dim3(KSP * 8), B, 0, stream>>>(f_h, Wa1, f_part);
  k_agg1red<<<dim3(BSZ * DD / 256), B, 0, stream>>>(f_part, f_a1);
  // 11. head MLP
  k_head<<<dim3(BSZ), dim3(64), 0, stream>>>(f_a1, ba1, Wa2, ba2, Wh1, bh1, Wh2, bh2, out);
}

// Round 8
// 273.315 us; speedup vs baseline: 4.2707x; 1.0471x over previous
//
#include <hip/hip_runtime.h>
#include <math.h>

#define NN 65536
#define SIN 24
#define DD 64
#define HH 4
#define HDIM 16
#define NFRM 256
#define NE 1048576
#define BSZ 256
#define EPSLN 1e-5f
#define SCL 0.25f
#define RB 8

#define KSP 128
#define KROWS 128

typedef __attribute__((ext_vector_type(8))) short bf16x8;
typedef __attribute__((ext_vector_type(4))) float f32x4;

__device__ __forceinline__ unsigned short f2bf(float f) {
  unsigned u = __float_as_uint(f);
  return (unsigned short)((u + 0x7FFFu + ((u >> 16) & 1u)) >> 16);
}
__device__ __forceinline__ float bf2f(unsigned short b) {
  return __uint_as_float(((unsigned)b) << 16);
}
__device__ __forceinline__ float bflo(unsigned u) {
  return __uint_as_float(u << 16);
}
__device__ __forceinline__ float bfhi(unsigned u) {
  return __uint_as_float(u & 0xFFFF0000u);
}

// stage fp32 [rows][DK] -> bf16 LDS [rows][ST]
__device__ __forceinline__ void stage_f32(const float* __restrict__ src,
                                          unsigned short* dst, int n4, int DK, int ST, int tid) {
  int dk4 = DK >> 2;
  for (int idx = tid; idx < n4; idx += 256) {
    int row = idx / dk4, c = (idx % dk4) * 4;
    float4 v = *(const float4*)(src + (size_t)row * DK + c);
    uint2 p;
    p.x = (unsigned)f2bf(v.x) | ((unsigned)f2bf(v.y) << 16);
    p.y = (unsigned)f2bf(v.z) | ((unsigned)f2bf(v.w) << 16);
    *(uint2*)(dst + row * ST + c) = p;
  }
}

// stage bf16 [rows][DK] -> LDS [rows][ST]
__device__ __forceinline__ void stage_bf(const unsigned short* __restrict__ src,
                                         unsigned short* dst, int n8, int DK, int ST, int tid) {
  int dk8 = DK >> 3;
  for (int idx = tid; idx < n8; idx += 256) {
    int row = idx / dk8, c = (idx % dk8) * 8;
    *(uint4*)(dst + row * ST + c) = *(const uint4*)(src + (size_t)row * DK + c);
  }
}

// K1: h = x @ Wi + bi + pe[n % NF]
__global__ void k_input(const float* __restrict__ x, const float* __restrict__ Wi,
                        const float* __restrict__ bi, const float* __restrict__ pe,
                        float* __restrict__ h) {
  int lane = threadIdx.x & 63;
  int wid = __builtin_amdgcn_readfirstlane(threadIdx.x >> 6);
  int n0 = (blockIdx.x * 4 + wid) * RB;
  float b = bi[lane];
  float acc[RB];
#pragma unroll
  for (int r = 0; r < RB; ++r) acc[r] = b + pe[((n0 + r) & (NFRM - 1)) * DD + lane];
  for (int s = 0; s < SIN; ++s) {
    float w = Wi[s * DD + lane];
#pragma unroll
    for (int r = 0; r < RB; ++r) acc[r] += x[(size_t)(n0 + r) * SIN + s] * w;
  }
#pragma unroll
  for (int r = 0; r < RB; ++r) h[(size_t)(n0 + r) * DD + lane] = acc[r];
}

// Weight prep: transpose all dense weights to bf16 Wt[Nout][Dk]
__global__ void k_wprep(const float* __restrict__ Wo, const float* __restrict__ Wot,
                        const float* __restrict__ Wqt, const float* __restrict__ Wkt,
                        const float* __restrict__ Wvt, const float* __restrict__ W1,
                        const float* __restrict__ W2, const float* __restrict__ Wq,
                        const float* __restrict__ Wk, const float* __restrict__ Wv,
                        const float* __restrict__ Wsk, unsigned short* __restrict__ wt) {
  int i = blockIdx.x * 256 + threadIdx.x;
  if (i >= 53248) return;
  float v;
  if (i < 4096)       { int t = i;         int j = t >> 6, d = t & 63; v = Wo[d * 64 + j]; }
  else if (i < 8192)  { int t = i - 4096;  int j = t >> 6, d = t & 63; v = Wot[d * 64 + j]; }
  else if (i < 12288) { int t = i - 8192;  int j = t >> 6, d = t & 63; v = Wqt[d * 64 + j]; }
  else if (i < 16384) { int t = i - 12288; int j = t >> 6, d = t & 63; v = Wkt[d * 64 + j]; }
  else if (i < 20480) { int t = i - 16384; int j = t >> 6, d = t & 63; v = Wvt[d * 64 + j]; }
  else if (i < 28672) { int t = i - 20480; int j = t >> 6, d = t & 63; v = W1[d * 128 + j]; }
  else if (i < 36864) { int t = i - 28672; int j = t >> 7, d = t & 127; v = W2[d * 64 + j]; }
  else if (i < 40960) { int t = i - 36864; int j = t >> 6, d = t & 63; v = Wq[(j >> 4) * 1024 + d * 16 + (j & 15)]; }
  else if (i < 45056) { int t = i - 40960; int j = t >> 6, d = t & 63; v = Wk[(j >> 4) * 1024 + d * 16 + (j & 15)]; }
  else if (i < 49152) { int t = i - 45056; int j = t >> 6, d = t & 63; v = Wv[(j >> 4) * 1024 + d * 16 + (j & 15)]; }
  else                { int t = i - 49152; int j = t >> 6, d = t & 63; v = Wsk[(j >> 4) * 1024 + d * 16 + (j & 15)]; }
  wt[i] = f2bf(v);
}

// K2 (MFMA): q fp32, kv packed bf16, sk fp32
__global__ void __launch_bounds__(256)
k_qkvs_m(const float* __restrict__ h, const unsigned short* __restrict__ wt,
         const float* __restrict__ bq, const float* __restrict__ bk,
         const float* __restrict__ bv, const float* __restrict__ bs,
         float* __restrict__ q, ushort2* __restrict__ kv, float* __restrict__ sk) {
  __shared__ unsigned short Xs[64 * 72];
  __shared__ unsigned short Ws4[4 * 64 * 72];
  int tid = threadIdx.x;
  int n0 = blockIdx.x * 64;
  stage_f32(h + (size_t)n0 * 64, Xs, 64 * 16, 64, 72, tid);
  stage_bf(wt + 36864, Ws4, 64 * 8, 64, 72, tid);
  stage_bf(wt + 40960, Ws4 + 4608, 64 * 8, 64, 72, tid);
  stage_bf(wt + 45056, Ws4 + 9216, 64 * 8, 64, 72, tid);
  stage_bf(wt + 49152, Ws4 + 13824, 64 * 8, 64, 72, tid);
  __syncthreads();
  int lane = tid & 63, w = tid >> 6;
  int c = lane & 15, g = lane >> 4;
  f32x4 aq[4], ak[4], av[4], as_[4];
#pragma unroll
  for (int j = 0; j < 4; ++j) {
#pragma unroll
    for (int r = 0; r < 4; ++r) { aq[j][r] = 0.f; ak[j][r] = 0.f; av[j][r] = 0.f; as_[j][r] = 0.f; }
  }
  const unsigned short* xrow = Xs + (w * 16 + c) * 72 + g * 8;
#pragma unroll
  for (int kk = 0; kk < 2; ++kk) {
    bf16x8 af = *(const bf16x8*)(xrow + kk * 32);
#pragma unroll
    for (int j = 0; j < 4; ++j) {
      int boff = (j * 16 + c) * 72 + kk * 32 + g * 8;
      aq[j] = __builtin_amdgcn_mfma_f32_16x16x32_bf16(af, *(const bf16x8*)(Ws4 + boff), aq[j], 0, 0, 0);
      ak[j] = __builtin_amdgcn_mfma_f32_16x16x32_bf16(af, *(const bf16x8*)(Ws4 + 4608 + boff), ak[j], 0, 0, 0);
      av[j] = __builtin_amdgcn_mfma_f32_16x16x32_bf16(af, *(const bf16x8*)(Ws4 + 9216 + boff), av[j], 0, 0, 0);
      as_[j] = __builtin_amdgcn_mfma_f32_16x16x32_bf16(af, *(const bf16x8*)(Ws4 + 13824 + boff), as_[j], 0, 0, 0);
    }
  }
  int rowb = n0 + w * 16 + 4 * g;
#pragma unroll
  for (int j = 0; j < 4; ++j) {
    int col = j * 16 + c;
    float bqj = bq[col], bkj = bk[col], bvj = bv[col], bsj = bs[col];
#pragma unroll
    for (int r = 0; r < 4; ++r) {
      size_t o = (size_t)(rowb + r) * 64 + col;
      q[o] = aq[j][r] + bqj;
      kv[o] = make_ushort2(f2bf(ak[j][r] + bkj), f2bf(av[j][r] + bvj));
      sk[o] = as_[j][r] + bsj;
    }
  }
}

// ---- Bucketed CSR build (bucket = dst >> 8) ----
__global__ void k_hist(const int* __restrict__ ei, int* __restrict__ hist) {
  __shared__ int h[256];
  int t = threadIdx.x;
  h[t] = 0;
  __syncthreads();
  int base = blockIdx.x * 4096;
#pragma unroll
  for (int r = 0; r < 16; ++r)
    atomicAdd(&h[ei[NE + base + r * 256 + t] >> 8], 1);
  __syncthreads();
  hist[t * 256 + blockIdx.x] = h[t];
}

__global__ void k_hscan(int* __restrict__ hist, int* __restrict__ btot) {
  __shared__ int s[256];
  int t = threadIdx.x, bkt = blockIdx.x;
  int v = hist[bkt * 256 + t];
  s[t] = v; __syncthreads();
  for (int off = 1; off < 256; off <<= 1) {
    int x = (t >= off) ? s[t - off] : 0;
    __syncthreads();
    s[t] += x;
    __syncthreads();
  }
  hist[bkt * 256 + t] = s[t] - v;
  if (t == 255) btot[bkt] = s[255];
}

__global__ void k_bscan(const int* __restrict__ btot, int* __restrict__ bbase) {
  __shared__ int s[256];
  int t = threadIdx.x;
  int v = btot[t];
  s[t] = v; __syncthreads();
  for (int off = 1; off < 256; off <<= 1) {
    int x = (t >= off) ? s[t - off] : 0;
    __syncthreads();
    s[t] += x;
    __syncthreads();
  }
  bbase[t] = s[t] - v;
}

__global__ void k_passB(const int* __restrict__ ei, const int* __restrict__ hist,
                        const int* __restrict__ bbase, int* __restrict__ pairs) {
  __shared__ int cur[256];
  int t = threadIdx.x;
  cur[t] = bbase[t] + hist[t * 256 + blockIdx.x];
  __syncthreads();
  int base = blockIdx.x * 4096;
#pragma unroll
  for (int r = 0; r < 16; ++r) {
    int e = base + r * 256 + t;
    int src = ei[e], dst = ei[NE + e];
    int pos = atomicAdd(&cur[dst >> 8], 1);
    pairs[pos] = ((dst & 255) << 16) | src;
  }
}

__global__ void k_passC(const int* __restrict__ pairs, const int* __restrict__ bbase,
                        const int* __restrict__ btot, int* __restrict__ rowptr,
                        int* __restrict__ srcs) {
  __shared__ int cnt[256];
  __shared__ int s[256];
  int t = threadIdx.x, bkt = blockIdx.x;
  cnt[t] = 0;
  __syncthreads();
  int base = bbase[bkt], n = btot[bkt];
  for (int i = t; i < n; i += 256) atomicAdd(&cnt[pairs[base + i] >> 16], 1);
  __syncthreads();
  int v = cnt[t];
  s[t] = v; __syncthreads();
  for (int off = 1; off < 256; off <<= 1) {
    int x = (t >= off) ? s[t - off] : 0;
    __syncthreads();
    s[t] += x;
    __syncthreads();
  }
  int rp = base + s[t] - v;
  rowptr[bkt * 256 + t] = rp;
  if (bkt == 0 && t == 0) rowptr[NN] = NE;
  __syncthreads();
  cnt[t] = rp;
  __syncthreads();
  for (int i = t; i < n; i += 256) {
    int p = pairs[base + i];
    int pos = atomicAdd(&cnt[p >> 16], 1);
    srcs[pos] = p & 0xFFFF;
  }
}

// Graph attention v2: wave per dst, lane = e*4 + h (16 edge slots x 4 heads).
// No max-subtraction (logits tiny; softmax shift-invariant). In-register dots,
// per-lane p*v accumulation, single LDS-transpose reduce per dst.
__global__ void __launch_bounds__(256)
k_gattn(const float* __restrict__ q, const unsigned* __restrict__ kv,
        const int* __restrict__ rowptr, const int* __restrict__ srcs,
        const float* __restrict__ sk, float* __restrict__ tmp) {
  __shared__ float red[4][64][20];
  int wid = threadIdx.x >> 6, lane = threadIdx.x & 63;
  int dst = (blockIdx.x << 2) + wid;
  int e = lane >> 2, h = lane & 3;
  float qv[16];
#pragma unroll
  for (int i = 0; i < 4; ++i)
    ((float4*)qv)[i] = *(const float4*)(q + (size_t)dst * 64 + h * 16 + i * 4);
  int beg = rowptr[dst], end = rowptr[dst + 1];
  float l = 0.f;
  float acc[16];
#pragma unroll
  for (int i = 0; i < 16; ++i) acc[i] = 0.f;
  for (int base = beg; base < end; base += 16) {
    int myidx = base + e;
    bool valid = myidx < end;
    int src = valid ? srcs[myidx] : 0;
    const uint4* kp = (const uint4*)(kv + (size_t)src * 64 + h * 16);
    uint4 ka = kp[0], kb = kp[1], kc_ = kp[2], kd = kp[3];
    float s;
    s  = bflo(ka.x) * qv[0]  + bflo(ka.y) * qv[1]  + bflo(ka.z) * qv[2]  + bflo(ka.w) * qv[3];
    s += bflo(kb.x) * qv[4]  + bflo(kb.y) * qv[5]  + bflo(kb.z) * qv[6]  + bflo(kb.w) * qv[7];
    s += bflo(kc_.x) * qv[8] + bflo(kc_.y) * qv[9] + bflo(kc_.z) * qv[10] + bflo(kc_.w) * qv[11];
    s += bflo(kd.x) * qv[12] + bflo(kd.y) * qv[13] + bflo(kd.z) * qv[14] + bflo(kd.w) * qv[15];
    float pex = valid ? __expf(s * SCL) : 0.f;
    l += pex;
    acc[0]  += pex * bfhi(ka.x);  acc[1]  += pex * bfhi(ka.y);
    acc[2]  += pex * bfhi(ka.z);  acc[3]  += pex * bfhi(ka.w);
    acc[4]  += pex * bfhi(kb.x);  acc[5]  += pex * bfhi(kb.y);
    acc[6]  += pex * bfhi(kb.z);  acc[7]  += pex * bfhi(kb.w);
    acc[8]  += pex * bfhi(kc_.x); acc[9]  += pex * bfhi(kc_.y);
    acc[10] += pex * bfhi(kc_.z); acc[11] += pex * bfhi(kc_.w);
    acc[12] += pex * bfhi(kd.x);  acc[13] += pex * bfhi(kd.y);
    acc[14] += pex * bfhi(kd.z);  acc[15] += pex * bfhi(kd.w);
  }
  // reduce l over the 16 e-lanes (e bits are lane bits 2..5)
  l += __shfl_xor(l, 4); l += __shfl_xor(l, 8);
  l += __shfl_xor(l, 16); l += __shfl_xor(l, 32);
  // LDS transpose-reduce of acc
  float* rw = &red[wid][lane][0];
#pragma unroll
  for (int i = 0; i < 4; ++i)
    *(float4*)(rw + 4 * i) = make_float4(acc[4 * i], acc[4 * i + 1], acc[4 * i + 2], acc[4 * i + 3]);
  int h2 = lane >> 4, d2 = lane & 15;
  float lsum = __shfl(l, h2);
  float ssum = 0.f;
#pragma unroll
  for (int ep = 0; ep < 16; ++ep) ssum += red[wid][ep * 4 + h2][d2];
  float aggv = (end > beg) ? ssum / lsum : 0.f;
  size_t o = (size_t)dst * 64 + lane;
  tmp[o] = aggv + sk[o];
}

// MFMA: io = LN(io + in1 @ W + bias)
__global__ void __launch_bounds__(256)
k_matln_m(const float* __restrict__ in1, const unsigned short* __restrict__ Wt,
          const float* __restrict__ bias, const float* __restrict__ gam,
          const float* __restrict__ bet, float* __restrict__ io) {
  __shared__ unsigned short Xs[64 * 72];
  __shared__ unsigned short Ws[64 * 72];
  int tid = threadIdx.x;
  int n0 = blockIdx.x * 64;
  stage_f32(in1 + (size_t)n0 * 64, Xs, 64 * 16, 64, 72, tid);
  stage_bf(Wt, Ws, 64 * 8, 64, 72, tid);
  __syncthreads();
  int lane = tid & 63, w = tid >> 6;
  int c = lane & 15, g = lane >> 4;
  f32x4 acc[4];
#pragma unroll
  for (int j = 0; j < 4; ++j) { acc[j][0] = 0.f; acc[j][1] = 0.f; acc[j][2] = 0.f; acc[j][3] = 0.f; }
  const unsigned short* xrow = Xs + (w * 16 + c) * 72 + g * 8;
#pragma unroll
  for (int kk = 0; kk < 2; ++kk) {
    bf16x8 af = *(const bf16x8*)(xrow + kk * 32);
#pragma unroll
    for (int j = 0; j < 4; ++j)
      acc[j] = __builtin_amdgcn_mfma_f32_16x16x32_bf16(af,
                 *(const bf16x8*)(Ws + (j * 16 + c) * 72 + kk * 32 + g * 8), acc[j], 0, 0, 0);
  }
  int rowb = n0 + w * 16 + 4 * g;
  float o[4][4], gj[4], bj[4];
#pragma unroll
  for (int j = 0; j < 4; ++j) {
    int col = j * 16 + c;
    float bb = bias[col];
    gj[j] = gam[col]; bj[j] = bet[col];
#pragma unroll
    for (int r = 0; r < 4; ++r)
      o[j][r] = acc[j][r] + bb + io[(size_t)(rowb + r) * 64 + col];
  }
#pragma unroll
  for (int r = 0; r < 4; ++r) {
    float s = (o[0][r] + o[1][r]) + (o[2][r] + o[3][r]);
    float s2 = (o[0][r] * o[0][r] + o[1][r] * o[1][r]) + (o[2][r] * o[2][r] + o[3][r] * o[3][r]);
#pragma unroll
    for (int off = 1; off <= 8; off <<= 1) {
      s += __shfl_xor(s, off);
      s2 += __shfl_xor(s2, off);
    }
    float mean = s * (1.0f / 64.0f);
    float var = s2 * (1.0f / 64.0f) - mean * mean;
    float rs = rsqrtf(var + EPSLN);
#pragma unroll
    for (int j = 0; j < 4; ++j)
      io[(size_t)(rowb + r) * 64 + j * 16 + c] = (o[j][r] - mean) * rs * gj[j] + bj[j];
  }
}

// MFMA: qt,kt,vt (bf16 out)
__global__ void __launch_bounds__(256)
k_qkvt_m(const float* __restrict__ xt, const unsigned short* __restrict__ wt,
         const float* __restrict__ bqt, const float* __restrict__ bkt,
         const float* __restrict__ bvt,
         unsigned short* __restrict__ qt, unsigned short* __restrict__ kt,
         unsigned short* __restrict__ vt) {
  __shared__ unsigned short Xs[64 * 72];
  __shared__ unsigned short Ws3[3 * 64 * 72];
  int tid = threadIdx.x;
  int n0 = blockIdx.x * 64;
  stage_f32(xt + (size_t)n0 * 64, Xs, 64 * 16, 64, 72, tid);
  stage_bf(wt + 8192, Ws3, 64 * 8, 64, 72, tid);
  stage_bf(wt + 12288, Ws3 + 4608, 64 * 8, 64, 72, tid);
  stage_bf(wt + 16384, Ws3 + 9216, 64 * 8, 64, 72, tid);
  __syncthreads();
  int lane = tid & 63, w = tid >> 6;
  int c = lane & 15, g = lane >> 4;
  f32x4 aq[4], ak[4], av[4];
#pragma unroll
  for (int j = 0; j < 4; ++j) {
#pragma unroll
    for (int r = 0; r < 4; ++r) { aq[j][r] = 0.f; ak[j][r] = 0.f; av[j][r] = 0.f; }
  }
  const unsigned short* xrow = Xs + (w * 16 + c) * 72 + g * 8;
#pragma unroll
  for (int kk = 0; kk < 2; ++kk) {
    bf16x8 af = *(const bf16x8*)(xrow + kk * 32);
#pragma unroll
    for (int j = 0; j < 4; ++j) {
      int boff = (j * 16 + c) * 72 + kk * 32 + g * 8;
      aq[j] = __builtin_amdgcn_mfma_f32_16x16x32_bf16(af, *(const bf16x8*)(Ws3 + boff), aq[j], 0, 0, 0);
      ak[j] = __builtin_amdgcn_mfma_f32_16x16x32_bf16(af, *(const bf16x8*)(Ws3 + 4608 + boff), ak[j], 0, 0, 0);
      av[j] = __builtin_amdgcn_mfma_f32_16x16x32_bf16(af, *(const bf16x8*)(Ws3 + 9216 + boff), av[j], 0, 0, 0);
    }
  }
  int rowb = n0 + w * 16 + 4 * g;
#pragma unroll
  for (int j = 0; j < 4; ++j) {
    int col = j * 16 + c;
    float bqj = bqt[col], bkj = bkt[col], bvj = bvt[col];
#pragma unroll
    for (int r = 0; r < 4; ++r) {
      size_t o = (size_t)(rowb + r) * 64 + col;
      qt[o] = f2bf(aq[j][r] + bqj);
      kt[o] = f2bf(ak[j][r] + bkj);
      vt[o] = f2bf(av[j][r] + bvj);
    }
  }
}

// K8: temporal attention via MFMA
#define VST 20
#define PST 40
__global__ void __launch_bounds__(256)
k_tattn(const unsigned short* __restrict__ qtb, const unsigned short* __restrict__ ktb,
        const unsigned short* __restrict__ vtb, float* __restrict__ attn) {
  int b = blockIdx.x >> 2, hh = blockIdx.x & 3;
  __shared__ unsigned short Qs[NFRM][16];
  __shared__ unsigned short Ks[NFRM][16];
  __shared__ unsigned short Vs[NFRM][VST];
  __shared__ unsigned short Ps[4][16][PST];
  int t = threadIdx.x;
  int wv = t >> 6, lane = t & 63;
  int g = lane >> 4, c = lane & 15;
  {
    size_t src = ((size_t)b * NFRM + t) * DD + hh * 16;
    const uint4* qsrc = (const uint4*)(qtb + src);
    const uint4* ksrc = (const uint4*)(ktb + src);
    const uint2* vsrc = (const uint2*)(vtb + src);
    ((uint4*)Qs[t])[0] = qsrc[0]; ((uint4*)Qs[t])[1] = qsrc[1];
    ((uint4*)Ks[t])[0] = ksrc[0]; ((uint4*)Ks[t])[1] = ksrc[1];
    uint2* vdst = (uint2*)Vs[t];
    vdst[0] = vsrc[0]; vdst[1] = vsrc[1]; vdst[2] = vsrc[2]; vdst[3] = vsrc[3];
  }
  __syncthreads();
  const bf16x8 zf = {0, 0, 0, 0, 0, 0, 0, 0};
  unsigned short (*P)[PST] = Ps[wv];
  for (int qt0 = wv; qt0 < 16; qt0 += 4) {
    bf16x8 qf = zf;
    if (g < 2) qf = *(const bf16x8*)&Qs[qt0 * 16 + c][g * 8];
    f32x4 O = {0.f, 0.f, 0.f, 0.f};
    float lacc[4] = {0.f, 0.f, 0.f, 0.f};
    for (int jp = 0; jp < 8; ++jp) {
#pragma unroll
      for (int half = 0; half < 2; ++half) {
        int jt = jp * 2 + half;
        bf16x8 kf = zf;
        if (g < 2) kf = *(const bf16x8*)&Ks[jt * 16 + c][g * 8];
        f32x4 S = __builtin_amdgcn_mfma_f32_16x16x32_bf16(qf, kf,
                    (f32x4){0.f, 0.f, 0.f, 0.f}, 0, 0, 0);
#pragma unroll
        for (int r = 0; r < 4; ++r) {
          float p = __expf(S[r] * SCL);
          lacc[r] += p;
          P[4 * g + r][half * 16 + c] = f2bf(p);
        }
      }
      bf16x8 pf = *(const bf16x8*)&P[c][g * 8];
      bf16x8 vf;
#pragma unroll
      for (int i = 0; i < 8; ++i) vf[i] = (short)Vs[jp * 32 + g * 8 + i][c];
      O = __builtin_amdgcn_mfma_f32_16x16x32_bf16(pf, vf, O, 0, 0, 0);
    }
#pragma unroll
    for (int r = 0; r < 4; ++r) {
      float s = lacc[r];
      s += __shfl_xor(s, 1); s += __shfl_xor(s, 2);
      s += __shfl_xor(s, 4); s += __shfl_xor(s, 8);
      lacc[r] = 1.0f / s;
    }
    size_t obase = ((size_t)b * NFRM + qt0 * 16) * DD + hh * 16;
#pragma unroll
    for (int r = 0; r < 4; ++r)
      attn[obase + (size_t)(4 * g + r) * DD + c] = O[r] * lacc[r];
  }
}

// MFMA: u = relu(xt @ W1 + b1), bf16 out [N][128]
__global__ void __launch_bounds__(256)
k_ffn1_m(const float* __restrict__ xt, const unsigned short* __restrict__ wt,
         const float* __restrict__ b1, unsigned short* __restrict__ u) {
  __shared__ unsigned short Xs[64 * 72];
  __shared__ unsigned short Ws[128 * 72];
  int tid = threadIdx.x;
  int n0 = blockIdx.x * 64;
  stage_f32(xt + (size_t)n0 * 64, Xs, 64 * 16, 64, 72, tid);
  stage_bf(wt + 20480, Ws, 128 * 8, 64, 72, tid);
  __syncthreads();
  int lane = tid & 63, w = tid >> 6;
  int c = lane & 15, g = lane >> 4;
  f32x4 acc[8];
#pragma unroll
  for (int j = 0; j < 8; ++j) { acc[j][0] = 0.f; acc[j][1] = 0.f; acc[j][2] = 0.f; acc[j][3] = 0.f; }
  const unsigned short* xrow = Xs + (w * 16 + c) * 72 + g * 8;
#pragma unroll
  for (int kk = 0; kk < 2; ++kk) {
    bf16x8 af = *(const bf16x8*)(xrow + kk * 32);
#pragma unroll
    for (int j = 0; j < 8; ++j)
      acc[j] = __builtin_amdgcn_mfma_f32_16x16x32_bf16(af,
                 *(const bf16x8*)(Ws + (j * 16 + c) * 72 + kk * 32 + g * 8), acc[j], 0, 0, 0);
  }
  int rowb = n0 + w * 16 + 4 * g;
#pragma unroll
  for (int j = 0; j < 8; ++j) {
    int col = j * 16 + c;
    float bb = b1[col];
#pragma unroll
    for (int r = 0; r < 4; ++r)
      u[(size_t)(rowb + r) * 128 + col] = f2bf(fmaxf(acc[j][r] + bb, 0.f));
  }
}

// MFMA: xt = LN(xt + u @ W2 + b2)
__global__ void __launch_bounds__(256)
k_ffn2_m(const unsigned short* __restrict__ u, const unsigned short* __restrict__ wt,
         const float* __restrict__ b2, const float* __restrict__ gam,
         const float* __restrict__ bet, float* __restrict__ xt) {
  __shared__ unsigned short Xs[64 * 136];
  __shared__ unsigned short Ws[64 * 136];
  int tid = threadIdx.x;
  int n0 = blockIdx.x * 64;
  stage_bf(u + (size_t)n0 * 128, Xs, 64 * 16, 128, 136, tid);
  stage_bf(wt + 28672, Ws, 64 * 16, 128, 136, tid);
  __syncthreads();
  int lane = tid & 63, w = tid >> 6;
  int c = lane & 15, g = lane >> 4;
  f32x4 acc[4];
#pragma unroll
  for (int j = 0; j < 4; ++j) { acc[j][0] = 0.f; acc[j][1] = 0.f; acc[j][2] = 0.f; acc[j][3] = 0.f; }
  const unsigned short* xrow = Xs + (w * 16 + c) * 136 + g * 8;
#pragma unroll
  for (int kk = 0; kk < 4; ++kk) {
    bf16x8 af = *(const bf16x8*)(xrow + kk * 32);
#pragma unroll
    for (int j = 0; j < 4; ++j)
      acc[j] = __builtin_amdgcn_mfma_f32_16x16x32_bf16(af,
                 *(const bf16x8*)(Ws + (j * 16 + c) * 136 + kk * 32 + g * 8), acc[j], 0, 0, 0);
  }
  int rowb = n0 + w * 16 + 4 * g;
  float o[4][4], gj[4], bj[4];
#pragma unroll
  for (int j = 0; j < 4; ++j) {
    int col = j * 16 + c;
    float bb = b2[col];
    gj[j] = gam[col]; bj[j] = bet[col];
#pragma unroll
    for (int r = 0; r < 4; ++r)
      o[j][r] = acc[j][r] + bb + xt[(size_t)(rowb + r) * 64 + col];
  }
#pragma unroll
  for (int r = 0; r < 4; ++r) {
    float s = (o[0][r] + o[1][r]) + (o[2][r] + o[3][r]);
    float s2 = (o[0][r] * o[0][r] + o[1][r] * o[1][r]) + (o[2][r] * o[2][r] + o[3][r] * o[3][r]);
#pragma unroll
    for (int off = 1; off <= 8; off <<= 1) {
      s += __shfl_xor(s, off);
      s2 += __shfl_xor(s2, off);
    }
    float mean = s * (1.0f / 64.0f);
    float var = s2 * (1.0f / 64.0f) - mean * mean;
    float rs = rsqrtf(var + EPSLN);
#pragma unroll
    for (int j = 0; j < 4; ++j)
      xt[(size_t)(rowb + r) * 64 + j * 16 + c] = (o[j][r] - mean) * rs * gj[j] + bj[j];
  }
}

// K12a: agg1 GEMM partials
__global__ void k_agg1a(const float* __restrict__ xt, const float* __restrict__ Wa1,
                        float* __restrict__ part) {
  __shared__ float ws_s[KROWS * DD];
  int kc = blockIdx.x >> 3, bt = blockIdx.x & 7;
  int t = threadIdx.x, wid = t >> 6, lane = t & 63;
  const float* wsrc = Wa1 + (size_t)kc * KROWS * DD;
  for (int idx = t; idx < KROWS * DD; idx += 256) ws_s[idx] = wsrc[idx];
  __syncthreads();
  for (int bb_ = 0; bb_ < 8; ++bb_) {
    int b = bt * 32 + wid * 8 + bb_;
    const float* xr = xt + (size_t)b * (NFRM * DD) + kc * KROWS;
    float acc = 0.f;
#pragma unroll 8
    for (int i = 0; i < KROWS; ++i) acc += xr[i] * ws_s[i * DD + lane];
    part[(size_t)kc * (BSZ * DD) + (size_t)b * DD + lane] = acc;
  }
}

__global__ void k_agg1red(const float* __restrict__ part, float* __restrict__ a1) {
  int g = blockIdx.x * 256 + threadIdx.x;
  float s = 0.f;
#pragma unroll 8
  for (int kc = 0; kc < KSP; ++kc) s += part[(size_t)kc * (BSZ * DD) + g];
  a1[g] = s;
}

// K13: head MLP
__global__ void k_head(const float* __restrict__ a1, const float* __restrict__ ba1,
                       const float* __restrict__ Wa2, const float* __restrict__ ba2,
                       const float* __restrict__ Wh1, const float* __restrict__ bh1,
                       const float* __restrict__ Wh2, const float* __restrict__ bh2,
                       float* __restrict__ out) {
  int b = blockIdx.x, t = threadIdx.x;
  __shared__ float s1[64], s2[32], s3[16];
  s1[t] = fmaxf(a1[b * DD + t] + ba1[t], 0.f);
  __syncthreads();
  if (t < 32) {
    float a = ba2[t];
#pragma unroll 8
    for (int j = 0; j < 64; ++j) a += s1[j] * Wa2[j * 32 + t];
    s2[t] = fmaxf(a, 0.f);
  }
  __syncthreads();
  if (t < 16) {
    float a = bh1[t];
#pragma unroll
    for (int j = 0; j < 32; ++j) a += s2[j] * Wh1[j * 16 + t];
    s3[t] = fmaxf(a, 0.f);
  }
  __syncthreads();
  if (t == 0) {
    float a = bh2[0];
#pragma unroll
    for (int j = 0; j < 16; ++j) a += s3[j] * Wh2[j];
    out[b] = 1.0f / (1.0f + expf(-a));
  }
}

extern "C" void kernel_launch(void* const* d_in, const int* in_sizes, int n_in,
                              void* d_out, int out_size, void* d_ws, size_t ws_size,
                              hipStream_t stream) {
  const float* x   = (const float*)d_in[0];
  const int*   ei  = (const int*)d_in[1];
  const float* Wi  = (const float*)d_in[2];
  const float* bi  = (const float*)d_in[3];
  const float* pe  = (const float*)d_in[4];
  const float* Wq  = (const float*)d_in[5];
  const float* Wk  = (const float*)d_in[6];
  const float* Wv  = (const float*)d_in[7];
  const float* bq  = (const float*)d_in[8];
  const float* bk  = (const float*)d_in[9];
  const float* bv  = (const float*)d_in[10];
  const float* Ws  = (const float*)d_in[11];
  const float* bs  = (const float*)d_in[12];
  const float* Wo  = (const float*)d_in[13];
  const float* bo  = (const float*)d_in[14];
  const float* gg  = (const float*)d_in[15];
  const float* gb  = (const float*)d_in[16];
  const float* Wqt = (const float*)d_in[17];
  const float* Wkt = (const float*)d_in[18];
  const float* Wvt = (const float*)d_in[19];
  const float* bqt = (const float*)d_in[20];
  const float* bkt = (const float*)d_in[21];
  const float* bvt = (const float*)d_in[22];
  const float* Wot = (const float*)d_in[23];
  const float* bot = (const float*)d_in[24];
  const float* l1g = (const float*)d_in[25];
  const float* l1b = (const float*)d_in[26];
  const float* W1  = (const float*)d_in[27];
  const float* b1  = (const float*)d_in[28];
  const float* W2  = (const float*)d_in[29];
  const float* b2  = (const float*)d_in[30];
  const float* l2g = (const float*)d_in[31];
  const float* l2b = (const float*)d_in[32];
  const float* Wa1 = (const float*)d_in[33];
  const float* ba1 = (const float*)d_in[34];
  const float* Wa2 = (const float*)d_in[35];
  const float* ba2 = (const float*)d_in[36];
  const float* Wh1 = (const float*)d_in[37];
  const float* bh1 = (const float*)d_in[38];
  const float* Wh2 = (const float*)d_in[39];
  const float* bh2 = (const float*)d_in[40];
  float* out = (float*)d_out;

  const size_t ND = (size_t)NN * DD;

  float* wsf    = (float*)d_ws;
  float* f_h    = wsf;
  float* f_q    = f_h  + ND;
  float* f_k    = f_q  + ND;
  float* f_v    = f_k  + ND;
  float* f_sk   = f_v  + ND;
  float* f_u    = f_sk + ND;
  float* f_part = f_u  + 2 * ND;
  float* f_a1   = f_part + (size_t)KSP * BSZ * DD;
  int* i_srcs   = (int*)(f_a1 + BSZ * DD);
  int* i_rowptr = i_srcs + NE;
  int* i_hist   = i_rowptr + NN + 1;
  int* i_btot   = i_hist + 65536;
  int* i_bbase  = i_btot + 256;
  int* i_pairs  = i_bbase + 256;
  unsigned short* wt = (unsigned short*)(i_pairs + NE);

  ushort2* f_kv = (ushort2*)f_k;
  float* f_tmp  = f_u;
  unsigned short* us_qt = (unsigned short*)f_q;
  unsigned short* us_kt = us_qt + ND;
  unsigned short* us_vt = (unsigned short*)f_k;
  unsigned short* us_u  = (unsigned short*)f_u;

  dim3 B(256);
  k_wprep<<<dim3(208), B, 0, stream>>>(Wo, Wot, Wqt, Wkt, Wvt, W1, W2, Wq, Wk, Wv, Ws, wt);
  k_input<<<dim3(NN / (4 * RB)), B, 0, stream>>>(x, Wi, bi, pe, f_h);
  k_qkvs_m<<<dim3(NN / 64), B, 0, stream>>>(f_h, wt, bq, bk, bv, bs, f_q, f_kv, f_sk);
  k_hist <<<dim3(256), B, 0, stream>>>(ei, i_hist);
  k_hscan<<<dim3(256), B, 0, stream>>>(i_hist, i_btot);
  k_bscan<<<dim3(1),   B, 0, stream>>>(i_btot, i_bbase);
  k_passB<<<dim3(256), B, 0, stream>>>(ei, i_hist, i_bbase, i_pairs);
  k_passC<<<dim3(256), B, 0, stream>>>(i_pairs, i_bbase, i_btot, i_rowptr, i_srcs);
  k_gattn<<<dim3(NN / 4), B, 0, stream>>>(f_q, (const unsigned*)f_kv, i_rowptr, i_srcs,
                                          f_sk, f_tmp);
  k_matln_m<<<dim3(NN / 64), B, 0, stream>>>(f_tmp, wt + 0, bo, gg, gb, f_h);
  k_qkvt_m<<<dim3(NN / 64), B, 0, stream>>>(f_h, wt, bqt, bkt, bvt, us_qt, us_kt, us_vt);
  k_tattn<<<dim3(BSZ * HH), B, 0, stream>>>(us_qt, us_kt, us_vt, f_sk);
  k_matln_m<<<dim3(NN / 64), B, 0, stream>>>(f_sk, wt + 4096, bot, l1g, l1b, f_h);
  k_ffn1_m<<<dim3(NN / 64), B, 0, stream>>>(f_h, wt, b1, us_u);
  k_ffn2_m<<<dim3(NN / 64), B, 0, stream>>>(us_u, wt, b2, l2g, l2b, f_h);
  k_agg1a<<<dim3(KSP * 8), B, 0, stream>>>(f_h, Wa1, f_part);
  k_agg1red<<<dim3(BSZ * DD / 256), B, 0, stream>>>(f_part, f_a1);
  k_head<<<dim3(BSZ), dim3(64), 0, stream>>>(f_a1, ba1, Wa2, ba2, Wh1, bh1, Wh2, bh2, out);
}